// Round 4
// baseline (6032.294 us; speedup 1.0000x reference)
//
#include <hip/hip_runtime.h>
#include <hip/hip_bf16.h>

typedef __hip_bfloat16 bf16;
typedef unsigned long long ull;
typedef __attribute__((ext_vector_type(8))) short s16x8;
typedef __attribute__((ext_vector_type(4))) float f32x4;

union FRG { ull u[2]; s16x8 v; };

#define B_      64
#define NMAX_   299
#define N_      300
#define D_      512
#define H_      512
#define NHEADS_ 8
#define NHID_   64
#define SCLD    304                  // padded leading dim for (n,m) score rows
#define SCSZ    (N_ * SCLD)          // 91,200 floats per batch
#define LDP     48                   // padded LDS row stride (bf16 elems) for mgemm

// ---------------------------------------------------------------- utilities

__device__ __forceinline__ float sigmoidf_(float x) { return 1.0f / (1.0f + expf(-x)); }

// ---------------------------------------------------------------- embedding

__global__ void embed_k(const int* __restrict__ tokens, const int* __restrict__ tok_lens,
                        const int* __restrict__ seq_lens, const float* __restrict__ emb,
                        bf16* __restrict__ out)
{
    const int n = blockIdx.x, b = blockIdx.y;
    const int d = threadIdx.x * 4;
    const int nc = seq_lens[b] - 1;
    float4 v;
    if (n < nc) {
        const int tl = tok_lens[b * NMAX_ + n];
        const int* tp = tokens + (b * NMAX_ + n) * 8;
        float4 acc = {0.f, 0.f, 0.f, 0.f};
        for (int t = 0; t < 8; ++t) {
            if (t < tl) {
                const float4 e = *(const float4*)(emb + (long)tp[t] * D_ + d);
                acc.x += e.x; acc.y += e.y; acc.z += e.z; acc.w += e.w;
            }
        }
        const float inv = 1.0f / (float)nc;
        v.x = acc.x * inv; v.y = acc.y * inv; v.z = acc.z * inv; v.w = acc.w * inv;
    } else {
        const int row = (n == nc) ? 2 : 0;
        v = *(const float4*)(emb + row * D_ + d);
    }
    bf16 o[4] = {__float2bfloat16(v.x), __float2bfloat16(v.y),
                 __float2bfloat16(v.z), __float2bfloat16(v.w)};
    *(uint2*)(out + ((long)b * N_ + n) * D_ + d) = *(uint2*)o;
}

// ------------------------------------------------------------------- cond

__global__ void cond_k(const float* __restrict__ adj, unsigned char* __restrict__ cond)
{
    __shared__ float T1[64][65];
    __shared__ float T2[64][65];
    const int b = blockIdx.z;
    const int n0 = blockIdx.x * 64, m0 = blockIdx.y * 64;
    const int jj = threadIdx.x & 63, i0 = threadIdx.x >> 6;
    for (int r = 0; r < 16; ++r) {
        const int i = i0 * 16 + r;
        const int n = n0 + i, m = m0 + jj;
        T1[i][jj] = (n < N_ && m < N_) ? adj[((long)b * N_ + n) * N_ + m] : 0.f;
        const int n2 = m0 + i, m2 = n0 + jj;
        T2[i][jj] = (n2 < N_ && m2 < N_) ? adj[((long)b * N_ + n2) * N_ + m2] : 0.f;
    }
    __syncthreads();
    for (int r = 0; r < 16; ++r) {
        const int i = i0 * 16 + r;
        const int n = n0 + i, m = m0 + jj;
        if (n < N_ && m < N_) {
            const float v = T1[i][jj] + T2[jj][i] + ((n == m) ? 1.f : 0.f);
            cond[((long)b * N_ + n) * N_ + m] = (v > 0.f) ? 1 : 0;
        }
    }
}

// -------------------------------------------------- weight prep (fp32->bf16)

__global__ void wgath_k(const float* __restrict__ W, bf16* __restrict__ out)
{   // (8,512,64) -> (512,512): out[h*64+o][d] = W[h][d][o]
    const int row = blockIdx.x;
    const int d = threadIdx.x;
    const int h = row >> 6, o = row & 63;
    out[row * 512 + d] = __float2bfloat16(W[((long)h * 512 + d) * 64 + o]);
}

__global__ void wtr_k(const float* __restrict__ W, bf16* __restrict__ out)
{   // (512,512) -> transposed: out[o][i] = W[i][o]
    const int o = blockIdx.x;
    const int i = threadIdx.x;
    out[o * 512 + i] = __float2bfloat16(W[(long)i * 512 + o]);
}

__global__ void f2b_k(const float* __restrict__ in, bf16* __restrict__ out, long n)
{
    for (long i = (long)blockIdx.x * 256 + threadIdx.x; i < n; i += (long)gridDim.x * 256)
        out[i] = __float2bfloat16(in[i]);
}

// ------------------------------------------------------- bf16 MFMA GEMM

template<int BM, int BN, bool OBF>
__global__ __launch_bounds__(256) void mgemm_k(
    const bf16* __restrict__ A, long sA, int lda,
    const bf16* __restrict__ Bm, long sB, int ldb,
    void* __restrict__ C, long sC, int ldc,
    int M, int N, int K)
{
    __shared__ short As[BM * LDP];
    __shared__ short Bs[BN * LDP];
    const int z = blockIdx.z;
    const bf16* Ab = A + (long)z * sA;
    const bf16* Bb = Bm + (long)z * sB;
    const int m0 = blockIdx.x * BM, n0 = blockIdx.y * BN;
    const int tid = threadIdx.x;
    const int lane = tid & 63;
    const int w = tid >> 6;
    const int wm = (w >> 1) * (BM / 2);
    const int wn = (w & 1) * (BN / 2);
    constexpr int MR = BM / 32;
    constexpr int NR = BN / 32;
    f32x4 acc[MR][NR] = {};

    const int srow = tid >> 2;
    const int sslot = (tid & 3) * 8;

    for (int k0 = 0; k0 < K; k0 += 32) {
        #pragma unroll
        for (int r = 0; r < BM / 64; ++r) {
            const int row = r * 64 + srow;
            uint4 v = {0u, 0u, 0u, 0u};
            if (m0 + row < M)
                v = *(const uint4*)(Ab + (long)(m0 + row) * lda + k0 + sslot);
            *(uint4*)&As[row * LDP + sslot] = v;
        }
        #pragma unroll
        for (int r = 0; r < BN / 64; ++r) {
            const int row = r * 64 + srow;
            uint4 v = {0u, 0u, 0u, 0u};
            if (n0 + row < N)
                v = *(const uint4*)(Bb + (long)(n0 + row) * ldb + k0 + sslot);
            *(uint4*)&Bs[row * LDP + sslot] = v;
        }
        __syncthreads();
        s16x8 aq[MR], bq[NR];
        #pragma unroll
        for (int i = 0; i < MR; ++i)
            aq[i] = *(const s16x8*)&As[(wm + i * 16 + (lane & 15)) * LDP + (lane >> 4) * 8];
        #pragma unroll
        for (int j = 0; j < NR; ++j)
            bq[j] = *(const s16x8*)&Bs[(wn + j * 16 + (lane & 15)) * LDP + (lane >> 4) * 8];
        #pragma unroll
        for (int i = 0; i < MR; ++i)
            #pragma unroll
            for (int j = 0; j < NR; ++j)
                acc[i][j] = __builtin_amdgcn_mfma_f32_16x16x32_bf16(aq[i], bq[j], acc[i][j], 0, 0, 0);
        __syncthreads();
    }

    #pragma unroll
    for (int i = 0; i < MR; ++i) {
        const int mrow = m0 + wm + i * 16 + (lane >> 4) * 4;
        #pragma unroll
        for (int j = 0; j < NR; ++j) {
            const int ncol = n0 + wn + j * 16 + (lane & 15);
            if (ncol < N) {
                #pragma unroll
                for (int e = 0; e < 4; ++e) {
                    const int mm = mrow + e;
                    if (mm < M) {
                        const long idx = (long)z * sC + (long)mm * ldc + ncol;
                        if (OBF) ((bf16*)C)[idx] = __float2bfloat16(acc[i][j][e]);
                        else     ((float*)C)[idx] = acc[i][j][e];
                    }
                }
            }
        }
    }
}

// ------------------------------------------------------- generic fp32 GEMM

template<bool BT, bool OBF, bool BBF = false>
__global__ __launch_bounds__(256) void gemm_k(
    const float* __restrict__ A, long sA, int lda,
    const float* __restrict__ B, long sB, int ldb,
    void* __restrict__ C, long sC, int ldc,
    int M, int N, int K)
{
    __shared__ alignas(16) float As[16][64];
    __shared__ alignas(16) float Bs[16][64];
    const int z = blockIdx.z;
    const float* Ab = A + (long)z * sA;
    const float* Bb = B + (long)z * sB;
    const int m0 = blockIdx.x * 64, n0 = blockIdx.y * 64;
    const int tid = threadIdx.x;
    const int tx = tid & 15, ty = tid >> 4;
    const int amm = tid >> 2, ak4 = (tid & 3) * 4;
    float acc[4][4] = {};

    for (int k0 = 0; k0 < K; k0 += 16) {
        {
            float4 v = {0.f, 0.f, 0.f, 0.f};
            const int row = m0 + amm;
            if (row < M) {
                if (k0 + ak4 + 3 < K) {
                    v = *(const float4*)(Ab + (long)row * lda + k0 + ak4);
                } else {
                    float* vp = (float*)&v;
                    for (int j = 0; j < 4; ++j)
                        if (k0 + ak4 + j < K) vp[j] = Ab[(long)row * lda + k0 + ak4 + j];
                }
            }
            As[ak4 + 0][amm] = v.x; As[ak4 + 1][amm] = v.y;
            As[ak4 + 2][amm] = v.z; As[ak4 + 3][amm] = v.w;
        }
        if (BT) {
            float4 v = {0.f, 0.f, 0.f, 0.f};
            const int row = n0 + amm;
            if (row < N) {
                if (k0 + ak4 + 3 < K) {
                    v = *(const float4*)(Bb + (long)row * ldb + k0 + ak4);
                } else {
                    float* vp = (float*)&v;
                    for (int j = 0; j < 4; ++j)
                        if (k0 + ak4 + j < K) vp[j] = Bb[(long)row * ldb + k0 + ak4 + j];
                }
            }
            Bs[ak4 + 0][amm] = v.x; Bs[ak4 + 1][amm] = v.y;
            Bs[ak4 + 2][amm] = v.z; Bs[ak4 + 3][amm] = v.w;
        } else {
            const int nn = tid & 63, kb = tid >> 6;
            #pragma unroll
            for (int r = 0; r < 4; ++r) {
                const int kk = kb * 4 + r;
                float v = 0.f;
                if (k0 + kk < K && n0 + nn < N) {
                    if (BBF) v = __bfloat162float(
                        ((const bf16*)B)[(long)z * sB + (long)(k0 + kk) * ldb + n0 + nn]);
                    else v = Bb[(long)(k0 + kk) * ldb + n0 + nn];
                }
                Bs[kk][nn] = v;
            }
        }
        __syncthreads();
        #pragma unroll
        for (int kk = 0; kk < 16; ++kk) {
            const float4 av = *(const float4*)&As[kk][ty * 4];
            const float4 bv = *(const float4*)&Bs[kk][tx * 4];
            const float* ap = (const float*)&av;
            const float* bp = (const float*)&bv;
            #pragma unroll
            for (int i = 0; i < 4; ++i)
                #pragma unroll
                for (int j = 0; j < 4; ++j)
                    acc[i][j] = fmaf(ap[i], bp[j], acc[i][j]);
        }
        __syncthreads();
    }
    for (int i = 0; i < 4; ++i) {
        const int m = m0 + ty * 4 + i;
        if (m >= M) break;
        for (int j = 0; j < 4; ++j) {
            const int nn = n0 + tx * 4 + j;
            if (nn < N) {
                const long idx = (long)z * sC + (long)m * ldc + nn;
                if (OBF) ((bf16*)C)[idx] = __float2bfloat16(acc[i][j]);
                else     ((float*)C)[idx] = acc[i][j];
            }
        }
    }
}

// ------------------------------------------------- softmaxes for GAT layer

__global__ void bsoft_k(const float* __restrict__ sc, float* __restrict__ mx, float* __restrict__ sm)
{
    const int idx = blockIdx.x * 256 + threadIdx.x;
    if (idx >= SCSZ) return;
    float m = -1e30f;
    for (int b = 0; b < B_; ++b) m = fmaxf(m, sc[(long)b * SCSZ + idx]);
    float s = 0.f;
    for (int b = 0; b < B_; ++b) s += expf(sc[(long)b * SCSZ + idx] - m);
    mx[idx] = m; sm[idx] = s;
}

__global__ __launch_bounds__(512) void colsoft_k(
    float* __restrict__ sc, const float* __restrict__ mx,
    const float* __restrict__ sm, const unsigned char* __restrict__ cond)
{
    __shared__ float red[8][64];
    const int ml = threadIdx.x & 63;
    const int ng = threadIdx.x >> 6;
    const int m = blockIdx.x * 64 + ml;
    const int b = blockIdx.y;
    float* scb = sc + (long)b * SCSZ;
    const unsigned char* cb = cond + (long)b * (N_ * N_);
    const bool act = m < N_;

    float vmax = -1e30f;
    for (int n = ng; n < N_; n += 8) {
        const int o = n * SCLD + m;
        if (act && cb[n * N_ + m]) {
            const float e = expf(scb[o] - mx[o]) / sm[o];
            scb[o] = e;
            vmax = fmaxf(vmax, e);
        }
    }
    red[ng][ml] = vmax;
    __syncthreads();
    vmax = red[0][ml];
    #pragma unroll
    for (int i = 1; i < 8; ++i) vmax = fmaxf(vmax, red[i][ml]);

    float ssum = 0.f;
    for (int n = ng; n < N_; n += 8) {
        const int o = n * SCLD + m;
        if (act && cb[n * N_ + m]) ssum += expf(scb[o] - vmax);
    }
    __syncthreads();
    red[ng][ml] = ssum;
    __syncthreads();
    ssum = 0.f;
    #pragma unroll
    for (int i = 0; i < 8; ++i) ssum += red[i][ml];
    const float inv = 1.0f / ssum;

    for (int n = ng; n < N_; n += 8) {
        const int o = n * SCLD + m;
        if (act) scb[o] = cb[n * N_ + m] ? expf(scb[o] - vmax) * inv : 0.f;
    }
}

__global__ void nsoft_k(const float* __restrict__ hp, bf16* __restrict__ out)
{
    const int f = blockIdx.x * 256 + threadIdx.x;
    const int b = blockIdx.y;
    const float* hb = hp + (long)b * (N_ * 512) + f;
    float vmax = -1e30f;
    for (int n = 0; n < N_; ++n) vmax = fmaxf(vmax, hb[n * 512]);
    float s = 0.f;
    for (int n = 0; n < N_; ++n) s += expf(hb[n * 512] - vmax);
    const float inv = 1.0f / s;
    bf16* ob = out + (long)b * (N_ * 512) + f;
    for (int n = 0; n < N_; ++n) ob[n * 512] = __float2bfloat16(expf(hb[n * 512] - vmax) * inv);
}

// ----------------------------------------------------------------- GRU prep

__global__ void xrev_k(const bf16* __restrict__ out2, const int* __restrict__ seq_lens,
                       bf16* __restrict__ xr)
{
    const int t = blockIdx.x, b = blockIdx.y;
    const int d = threadIdx.x * 4;
    int src = seq_lens[b] - 1 - t;
    if (src < 0) src = 0;
    *(uint2*)(xr + ((long)t * B_ + b) * 512 + d) =
        *(const uint2*)(out2 + ((long)b * N_ + src) * 512 + d);
}

__global__ void zero_k(float* __restrict__ p, long n)
{
    for (long i = (long)blockIdx.x * 256 + threadIdx.x; i < n; i += (long)gridDim.x * 256)
        p[i] = 0.f;
}

// ------------------------------------------------------ GRU recurrence (v2)
// 64 blocks x 256 thr: block = (dir, 16 u's, ALL 64 batches), 4 waves = 4
// batch-tiles of 16. m-tiles = gates (r,z,n) so all 3 gates of a (u,b) land
// in the SAME lane -> no cross-wave combine. Whh LDS-resident as hi/lo bf16
// (3 MFMA combos ~ fp32 matvec). h carried fp32 in registers; exchanged as
// hi/lo bf16 via relaxed agent atomics (L3-coherent). Barrier: 4 leaves x 8
// blocks per dir -> per-dir root.

__device__ __forceinline__ void dbar2(unsigned* __restrict__ gc, unsigned* __restrict__ root,
                                      int step) {
    __syncthreads();   // exec barrier + vmcnt drain of this block's h stores
    if (threadIdx.x == 0) {
        const unsigned old =
            __hip_atomic_fetch_add(gc, 1u, __ATOMIC_RELAXED, __HIP_MEMORY_SCOPE_AGENT);
        if (old == (unsigned)(step * 8 + 7))
            __hip_atomic_fetch_add(root, 1u, __ATOMIC_RELAXED, __HIP_MEMORY_SCOPE_AGENT);
        while (__hip_atomic_load(root, __ATOMIC_RELAXED, __HIP_MEMORY_SCOPE_AGENT)
               < (unsigned)((step + 1) * 4)) {
            __builtin_amdgcn_s_sleep(1);
        }
    }
    __syncthreads();
}

__global__ __launch_bounds__(256, 1) void gru_recur2(
    const bf16* __restrict__ gif, const bf16* __restrict__ gib,
    const float* __restrict__ Whh, const float* __restrict__ bih,
    const float* __restrict__ bhh, const int* __restrict__ seq_lens,
    float* __restrict__ hbuf_f, unsigned* __restrict__ bar,
    float* __restrict__ outf, float* __restrict__ outb,
    float* __restrict__ hfin)
{
    __shared__ short As[2][48 * 520];   // [hi/lo][row m = g*16+ul][k], pad 520
    const int tid = threadIdx.x;
    const int lane = tid & 63;
    const int w = tid >> 6;
    const int ml = lane & 15;
    const int ksl = lane >> 4;
    const int dir = blockIdx.x >> 5;
    const int blk = blockIdx.x & 31;
    const int u0 = blk * 16;
    const int grp = blk >> 3;
    unsigned* gc   = bar + (dir * 4 + grp) * 32;
    unsigned* root = bar + 512 + dir * 32;
    bf16* hb = (bf16*)hbuf_f;

    // one-time: Whh slab -> LDS hi/lo bf16
    {
        const float* Wb = Whh + (long)dir * (1536 * 512);
        for (int idx = tid; idx < 48 * 512; idx += 256) {
            const int row = idx >> 9, k = idx & 511;
            const int g = row >> 4, ul = row & 15;
            const float v = Wb[(long)(g * 512 + u0 + ul) * 512 + k];
            const bf16 hi = __float2bfloat16(v);
            const bf16 lo = __float2bfloat16(v - __bfloat162float(hi));
            As[0][row * 520 + k] = *(const short*)&hi;
            As[1][row * 520 + k] = *(const short*)&lo;
        }
    }

    const int bcol = w * 16 + ml;          // this lane's batch (C col = lane&15)
    const int ue = u0 + ksl * 4;           // this lane's 4 u's (C row = (lane>>4)*4+e)
    const bf16* gi = dir ? gib : gif;
    float cr[4], cz[4], cn[4], brr[4], bzz[4], bnn[4];
    #pragma unroll
    for (int e = 0; e < 4; ++e) {
        cr[e]  = bih[dir * 1536 + ue + e];
        cz[e]  = bih[dir * 1536 + 512 + ue + e];
        cn[e]  = bih[dir * 1536 + 1024 + ue + e];
        brr[e] = bhh[dir * 1536 + ue + e];
        bzz[e] = bhh[dir * 1536 + 512 + ue + e];
        bnn[e] = bhh[dir * 1536 + 1024 + ue + e];
    }
    const int sl = seq_lens[bcol];
    float hreg[4] = {0.f, 0.f, 0.f, 0.f};

    // init phase-0 h (both splits) at this lane's slots
    {
        const long z0 = (long)((dir * 2 + 0) * 2 + 0) * 32768 + bcol * 512 + u0 + ksl * 4;
        const long z1 = (long)((dir * 2 + 0) * 2 + 1) * 32768 + bcol * 512 + u0 + ksl * 4;
        __hip_atomic_store((ull*)(hb + z0), 0ull, __ATOMIC_RELAXED, __HIP_MEMORY_SCOPE_AGENT);
        __hip_atomic_store((ull*)(hb + z1), 0ull, __ATOMIC_RELAXED, __HIP_MEMORY_SCOPE_AGENT);
    }
    dbar2(gc, root, 0);

    for (int t = 0; t < N_; ++t) {
        const int rp = t & 1, wp = rp ^ 1;
        const bf16* rhi = hb + (long)((dir * 2 + rp) * 2 + 0) * 32768 + bcol * 512;
        const bf16* rlo = hb + (long)((dir * 2 + rp) * 2 + 1) * 32768 + bcol * 512;

        // issue ALL B-fragment loads up front (one L3 round-trip per step)
        ull bh_[32], bl_[32];
        #pragma unroll
        for (int ks = 0; ks < 16; ++ks) {
            const int o = ks * 32 + ksl * 8;
            bh_[ks * 2 + 0] = __hip_atomic_load((const ull*)(rhi + o),
                                  __ATOMIC_RELAXED, __HIP_MEMORY_SCOPE_AGENT);
            bh_[ks * 2 + 1] = __hip_atomic_load((const ull*)(rhi + o + 4),
                                  __ATOMIC_RELAXED, __HIP_MEMORY_SCOPE_AGENT);
            bl_[ks * 2 + 0] = __hip_atomic_load((const ull*)(rlo + o),
                                  __ATOMIC_RELAXED, __HIP_MEMORY_SCOPE_AGENT);
            bl_[ks * 2 + 1] = __hip_atomic_load((const ull*)(rlo + o + 4),
                                  __ATOMIC_RELAXED, __HIP_MEMORY_SCOPE_AGENT);
        }
        float gv[3][4];
        #pragma unroll
        for (int g = 0; g < 3; ++g)
            #pragma unroll
            for (int e = 0; e < 4; ++e)
                gv[g][e] = __bfloat162float(
                    gi[(long)t * 98304 + (g * 512 + ue + e) * 64 + bcol]);

        f32x4 acc[3] = {};
        #pragma unroll
        for (int ks = 0; ks < 16; ++ks) {
            FRG fh, fl;
            fh.u[0] = bh_[ks * 2]; fh.u[1] = bh_[ks * 2 + 1];
            fl.u[0] = bl_[ks * 2]; fl.u[1] = bl_[ks * 2 + 1];
            const int ko = ks * 32 + ksl * 8;
            const s16x8 a0h = *(const s16x8*)&As[0][(0 * 16 + ml) * 520 + ko];
            const s16x8 a1h = *(const s16x8*)&As[0][(1 * 16 + ml) * 520 + ko];
            const s16x8 a2h = *(const s16x8*)&As[0][(2 * 16 + ml) * 520 + ko];
            const s16x8 a0l = *(const s16x8*)&As[1][(0 * 16 + ml) * 520 + ko];
            const s16x8 a1l = *(const s16x8*)&As[1][(1 * 16 + ml) * 520 + ko];
            const s16x8 a2l = *(const s16x8*)&As[1][(2 * 16 + ml) * 520 + ko];
            acc[0] = __builtin_amdgcn_mfma_f32_16x16x32_bf16(a0h, fh.v, acc[0], 0, 0, 0);
            acc[1] = __builtin_amdgcn_mfma_f32_16x16x32_bf16(a1h, fh.v, acc[1], 0, 0, 0);
            acc[2] = __builtin_amdgcn_mfma_f32_16x16x32_bf16(a2h, fh.v, acc[2], 0, 0, 0);
            acc[0] = __builtin_amdgcn_mfma_f32_16x16x32_bf16(a0h, fl.v, acc[0], 0, 0, 0);
            acc[1] = __builtin_amdgcn_mfma_f32_16x16x32_bf16(a1h, fl.v, acc[1], 0, 0, 0);
            acc[2] = __builtin_amdgcn_mfma_f32_16x16x32_bf16(a2h, fl.v, acc[2], 0, 0, 0);
            acc[0] = __builtin_amdgcn_mfma_f32_16x16x32_bf16(a0l, fh.v, acc[0], 0, 0, 0);
            acc[1] = __builtin_amdgcn_mfma_f32_16x16x32_bf16(a1l, fh.v, acc[1], 0, 0, 0);
            acc[2] = __builtin_amdgcn_mfma_f32_16x16x32_bf16(a2l, fh.v, acc[2], 0, 0, 0);
        }

        ull phi = 0, plo = 0;
        const bool msk = t < sl;
        #pragma unroll
        for (int e = 0; e < 4; ++e) {
            const float rg = sigmoidf_(cr[e] + gv[0][e] + brr[e] + acc[0][e]);
            const float zg = sigmoidf_(cz[e] + gv[1][e] + bzz[e] + acc[1][e]);
            const float ng = tanhf(cn[e] + gv[2][e] + rg * (bnn[e] + acc[2][e]));
            const float hnew = (1.f - zg) * ng + zg * hreg[e];
            if (dir == 0) {
                outf[(long)t * 32768 + (ue + e) * 64 + bcol] = msk ? hnew : 0.f;
            } else if (msk) {
                outb[(long)(sl - 1 - t) * 32768 + (ue + e) * 64 + bcol] = hnew;
            }
            hreg[e] = msk ? hnew : hreg[e];
            const bf16 h_hi = __float2bfloat16(hreg[e]);
            const bf16 h_lo = __float2bfloat16(hreg[e] - __bfloat162float(h_hi));
            phi |= (ull)(*(const unsigned short*)&h_hi) << (16 * e);
            plo |= (ull)(*(const unsigned short*)&h_lo) << (16 * e);
        }
        const long wbh = (long)((dir * 2 + wp) * 2 + 0) * 32768 + bcol * 512 + u0 + ksl * 4;
        const long wbl = (long)((dir * 2 + wp) * 2 + 1) * 32768 + bcol * 512 + u0 + ksl * 4;
        __hip_atomic_store((ull*)(hb + wbh), phi, __ATOMIC_RELAXED, __HIP_MEMORY_SCOPE_AGENT);
        __hip_atomic_store((ull*)(hb + wbl), plo, __ATOMIC_RELAXED, __HIP_MEMORY_SCOPE_AGENT);
        if (t == N_ - 1) {
            #pragma unroll
            for (int e = 0; e < 4; ++e)
                hfin[dir * 32768 + (ue + e) * 64 + bcol] = hreg[e];
        }
        dbar2(gc, root, t + 1);
    }
}

// --------------------------------------------------------------- finalize

__global__ void final_k(const float* __restrict__ outf, const float* __restrict__ outb,
                        const float* __restrict__ hfin, const int* __restrict__ seq_lens,
                        float* __restrict__ dout)
{
    const long i = (long)blockIdx.x * 256 + threadIdx.x;
    const long NOUT = (long)N_ * B_ * 512;
    if (i < NOUT) {
        const int t = (int)(i >> 15);
        const int b = (int)((i >> 9) & 63);
        const int u = (int)(i & 511);
        const long src = (long)t * 32768 + u * 64 + b;
        dout[i] = (t < seq_lens[b]) ? outf[src] + outb[src] : 0.f;
    } else if (i < NOUT + 2 * B_ * 512) {
        const long j = i - NOUT;
        const int dir = (int)(j >> 15);
        const int b = (int)((j >> 9) & 63);
        const int u = (int)(j & 511);
        dout[i] = hfin[dir * 32768 + u * 64 + b];
    }
}

__global__ void fail_zero_k(float* __restrict__ dout, long n)
{
    for (long i = (long)blockIdx.x * 256 + threadIdx.x; i < n; i += (long)gridDim.x * 256)
        dout[i] = 0.f;
}

// ----------------------------------------------------------------- launch

extern "C" void kernel_launch(void* const* d_in, const int* in_sizes, int n_in,
                              void* d_out, int out_size, void* d_ws, size_t ws_size,
                              hipStream_t stream)
{
    const int*   tokens   = (const int*)d_in[0];
    const int*   tok_lens = (const int*)d_in[1];
    const int*   seq_lens = (const int*)d_in[2];
    const float* adj      = (const float*)d_in[3];
    const float* emb      = (const float*)d_in[4];
    const float* Wq       = (const float*)d_in[5];
    const float* Wk       = (const float*)d_in[6];
    const float* Wq_o     = (const float*)d_in[7];
    const float* Wk_o     = (const float*)d_in[8];
    const float* gWih     = (const float*)d_in[9];
    const float* gWhh     = (const float*)d_in[10];
    const float* gbih     = (const float*)d_in[11];
    const float* gbhh     = (const float*)d_in[12];
    float* out = (float*)d_out;

    const long SZ = (long)B_ * N_ * 512;   // 9,830,400 elements
    float* F1 = (float*)d_ws;              // q1   -> outf
    float* F2 = F1 + SZ;                   // k1   -> outb
    float* F3 = F2 + SZ;                   // hp1  -> hp2
    bf16* b0 = (bf16*)(F3 + SZ);           // embx -> out2
    bf16* b1 = b0 + SZ;                    // x1   -> x_rev
    bf16* b2 = b1 + SZ;                    // q2   -> wih(bf16)
    bf16* b3 = b2 + SZ;                    // k2
    float* sc   = (float*)(b3 + SZ);
    float* mx   = sc + (long)B_ * SCSZ;
    float* smv  = mx + SCSZ;
    unsigned char* cond = (unsigned char*)(smv + SCSZ);
    bf16* gif = (bf16*)(cond + (long)B_ * N_ * N_);
    bf16* gib = gif + (long)N_ * 1536 * B_;
    float* hbuf = (float*)(gib + (long)N_ * 1536 * B_);   // 512 KB: bf16 hi/lo x 2 par x 2 dir
    unsigned* bar = (unsigned*)(hbuf + 131072);
    float* hfin = (float*)(bar + 2048);                   // 2 x 512 x 64 fp32 final h
    const size_t needed = (size_t)((char*)(hfin + 2 * 512 * 64) - (char*)d_ws);
    if (ws_size < needed) {
        fail_zero_k<<<4096, 256, 0, stream>>>(out, out_size);
        return;
    }
    bf16* wq1  = (bf16*)sc;
    bf16* wk1  = wq1 + 512 * 512;
    bf16* w2q  = (bf16*)sc;
    bf16* w2k  = w2q + 512 * 512;
    bf16* wihb = b2;

    // 1. layer-1 weight prep, embedding (bf16), cond
    wgath_k<<<512, 512, 0, stream>>>(Wq, wq1);
    wgath_k<<<512, 512, 0, stream>>>(Wk, wk1);
    embed_k<<<dim3(N_, B_), 128, 0, stream>>>(tokens, tok_lens, seq_lens, emb, b0);
    cond_k<<<dim3(5, 5, B_), 256, 0, stream>>>(adj, cond);

    // 2. layer-1 projections via MFMA (fp32 out): q1 -> F1, k1 -> F2
    mgemm_k<128, 128, false><<<dim3(150, 4, 1), 256, 0, stream>>>(
        b0, 0, 512, wq1, 0, 512, F1, 0, 512, B_ * N_, 512, 512);
    mgemm_k<128, 128, false><<<dim3(150, 4, 1), 256, 0, stream>>>(
        b0, 0, 512, wk1, 0, 512, F2, 0, 512, B_ * N_, 512, 512);

    // 3. per-head attention (fp32 SIMT: K=64)
    for (int h = 0; h < NHEADS_; ++h) {
        gemm_k<true, false><<<dim3(5, 5, B_), 256, 0, stream>>>(
            F1 + h * 64, (long)N_ * 512, 512,
            F2 + h * 64, (long)N_ * 512, 512,
            sc, SCSZ, SCLD, N_, N_, 64);
        bsoft_k<<<(SCSZ + 255) / 256, 256, 0, stream>>>(sc, mx, smv);
        colsoft_k<<<dim3(5, B_), 512, 0, stream>>>(sc, mx, smv, cond);
        gemm_k<false, false><<<dim3(5, 1, B_), 256, 0, stream>>>(
            sc, SCSZ, SCLD,
            F2 + h * 64, (long)N_ * 512, 512,
            F3 + h * 64, (long)N_ * 512, 512, N_, 64, N_);
    }
    nsoft_k<<<dim3(2, B_), 256, 0, stream>>>(F3, b1);               // x1 (bf16)

    // 4. layer-2 via MFMA: q2/k2 (bf16 out), scores2
    wtr_k<<<512, 512, 0, stream>>>(Wq_o, w2q);
    wtr_k<<<512, 512, 0, stream>>>(Wk_o, w2k);
    mgemm_k<128, 128, true><<<dim3(150, 4, 1), 256, 0, stream>>>(
        b1, 0, 512, w2q, 0, 512, b2, 0, 512, B_ * N_, 512, 512);
    mgemm_k<128, 128, true><<<dim3(150, 4, 1), 256, 0, stream>>>(
        b1, 0, 512, w2k, 0, 512, b3, 0, 512, B_ * N_, 512, 512);
    mgemm_k<64, 64, false><<<dim3(5, 5, B_), 256, 0, stream>>>(
        b2, (long)N_ * 512, 512, b3, (long)N_ * 512, 512,
        sc, SCSZ, SCLD, N_, N_, 512);
    f2b_k<<<6144, 256, 0, stream>>>(gWih, wihb, (long)2 * 1536 * 512);
    bsoft_k<<<(SCSZ + 255) / 256, 256, 0, stream>>>(sc, mx, smv);
    colsoft_k<<<dim3(5, B_), 512, 0, stream>>>(sc, mx, smv, cond);
    gemm_k<false, false, true><<<dim3(5, 8, B_), 256, 0, stream>>>(
        sc, SCSZ, SCLD, (const float*)(const void*)b3, (long)N_ * 512, 512,
        F3, (long)N_ * 512, 512, N_, 512, N_);
    nsoft_k<<<dim3(2, B_), 256, 0, stream>>>(F3, b0);                // out2 (bf16)

    // 5. GRU input GEMMs via MFMA (bf16 out, layout (t, j, b))
    xrev_k<<<dim3(N_, B_), 128, 0, stream>>>(b0, seq_lens, b1);
    zero_k<<<1, 256, 0, stream>>>((float*)bar, 2048);
    mgemm_k<64, 64, true><<<dim3(24, 1, N_), 256, 0, stream>>>(
        wihb, 0, 512, b0, 512, (long)N_ * 512, gif, 1536 * 64, 64, 1536, 64, 512);
    mgemm_k<64, 64, true><<<dim3(24, 1, N_), 256, 0, stream>>>(
        wihb + 1536 * 512, 0, 512, b1, (long)B_ * 512, 512, gib, 1536 * 64, 64, 1536, 64, 512);

    // 6. recurrence (MFMA, 64 blocks, fence-free per-dir sync) + finalize
    gru_recur2<<<64, 256, 0, stream>>>(gif, gib, gWhh, gbih, gbhh, seq_lens,
                                       hbuf, bar, F1, F2, hfin);
    final_k<<<38656, 256, 0, stream>>>(F1, F2, hfin, seq_lens, out);
}

// Round 5
// 5085.343 us; speedup vs baseline: 1.1862x; 1.1862x over previous
//
#include <hip/hip_runtime.h>
#include <hip/hip_bf16.h>

typedef __hip_bfloat16 bf16;
typedef unsigned long long ull;
typedef __attribute__((ext_vector_type(8))) short s16x8;
typedef __attribute__((ext_vector_type(4))) float f32x4;

union FRG { ull u[2]; s16x8 v; };

#define B_      64
#define NMAX_   299
#define N_      300
#define D_      512
#define H_      512
#define NHEADS_ 8
#define NHID_   64
#define SCLD    304                  // padded leading dim for (n,m) score rows
#define SCSZ    (N_ * SCLD)          // 91,200 floats per batch
#define LDP     48                   // padded LDS row stride (bf16 elems) for mgemm
#define WPAD    536                  // Whh LDS k-stride (shorts): 16B-aligned, 16 bank groups

// ---------------------------------------------------------------- utilities

__device__ __forceinline__ float sigmoidf_(float x) { return 1.0f / (1.0f + expf(-x)); }

// ---------------------------------------------------------------- embedding

__global__ void embed_k(const int* __restrict__ tokens, const int* __restrict__ tok_lens,
                        const int* __restrict__ seq_lens, const float* __restrict__ emb,
                        bf16* __restrict__ out)
{
    const int n = blockIdx.x, b = blockIdx.y;
    const int d = threadIdx.x * 4;
    const int nc = seq_lens[b] - 1;
    float4 v;
    if (n < nc) {
        const int tl = tok_lens[b * NMAX_ + n];
        const int* tp = tokens + (b * NMAX_ + n) * 8;
        float4 acc = {0.f, 0.f, 0.f, 0.f};
        for (int t = 0; t < 8; ++t) {
            if (t < tl) {
                const float4 e = *(const float4*)(emb + (long)tp[t] * D_ + d);
                acc.x += e.x; acc.y += e.y; acc.z += e.z; acc.w += e.w;
            }
        }
        const float inv = 1.0f / (float)nc;
        v.x = acc.x * inv; v.y = acc.y * inv; v.z = acc.z * inv; v.w = acc.w * inv;
    } else {
        const int row = (n == nc) ? 2 : 0;
        v = *(const float4*)(emb + row * D_ + d);
    }
    bf16 o[4] = {__float2bfloat16(v.x), __float2bfloat16(v.y),
                 __float2bfloat16(v.z), __float2bfloat16(v.w)};
    *(uint2*)(out + ((long)b * N_ + n) * D_ + d) = *(uint2*)o;
}

// ------------------------------------------------------------------- cond

__global__ void cond_k(const float* __restrict__ adj, unsigned char* __restrict__ cond)
{
    __shared__ float T1[64][65];
    __shared__ float T2[64][65];
    const int b = blockIdx.z;
    const int n0 = blockIdx.x * 64, m0 = blockIdx.y * 64;
    const int jj = threadIdx.x & 63, i0 = threadIdx.x >> 6;
    for (int r = 0; r < 16; ++r) {
        const int i = i0 * 16 + r;
        const int n = n0 + i, m = m0 + jj;
        T1[i][jj] = (n < N_ && m < N_) ? adj[((long)b * N_ + n) * N_ + m] : 0.f;
        const int n2 = m0 + i, m2 = n0 + jj;
        T2[i][jj] = (n2 < N_ && m2 < N_) ? adj[((long)b * N_ + n2) * N_ + m2] : 0.f;
    }
    __syncthreads();
    for (int r = 0; r < 16; ++r) {
        const int i = i0 * 16 + r;
        const int n = n0 + i, m = m0 + jj;
        if (n < N_ && m < N_) {
            const float v = T1[i][jj] + T2[jj][i] + ((n == m) ? 1.f : 0.f);
            cond[((long)b * N_ + n) * N_ + m] = (v > 0.f) ? 1 : 0;
        }
    }
}

// -------------------------------------------------- weight prep (fp32->bf16)

__global__ void wgath_k(const float* __restrict__ W, bf16* __restrict__ out)
{   // (8,512,64) -> (512,512): out[h*64+o][d] = W[h][d][o]
    const int row = blockIdx.x;
    const int d = threadIdx.x;
    const int h = row >> 6, o = row & 63;
    out[row * 512 + d] = __float2bfloat16(W[((long)h * 512 + d) * 64 + o]);
}

__global__ void wtr_k(const float* __restrict__ W, bf16* __restrict__ out)
{   // (512,512) -> transposed: out[o][i] = W[i][o]
    const int o = blockIdx.x;
    const int i = threadIdx.x;
    out[o * 512 + i] = __float2bfloat16(W[(long)i * 512 + o]);
}

__global__ void f2b_k(const float* __restrict__ in, bf16* __restrict__ out, long n)
{
    for (long i = (long)blockIdx.x * 256 + threadIdx.x; i < n; i += (long)gridDim.x * 256)
        out[i] = __float2bfloat16(in[i]);
}

// ------------------------------------------------------- bf16 MFMA GEMM

template<int BM, int BN, bool OBF>
__global__ __launch_bounds__(256) void mgemm_k(
    const bf16* __restrict__ A, long sA, int lda,
    const bf16* __restrict__ Bm, long sB, int ldb,
    void* __restrict__ C, long sC, int ldc,
    int M, int N, int K)
{
    __shared__ short As[BM * LDP];
    __shared__ short Bs[BN * LDP];
    const int z = blockIdx.z;
    const bf16* Ab = A + (long)z * sA;
    const bf16* Bb = Bm + (long)z * sB;
    const int m0 = blockIdx.x * BM, n0 = blockIdx.y * BN;
    const int tid = threadIdx.x;
    const int lane = tid & 63;
    const int w = tid >> 6;
    const int wm = (w >> 1) * (BM / 2);
    const int wn = (w & 1) * (BN / 2);
    constexpr int MR = BM / 32;
    constexpr int NR = BN / 32;
    f32x4 acc[MR][NR] = {};

    const int srow = tid >> 2;
    const int sslot = (tid & 3) * 8;

    for (int k0 = 0; k0 < K; k0 += 32) {
        #pragma unroll
        for (int r = 0; r < BM / 64; ++r) {
            const int row = r * 64 + srow;
            uint4 v = {0u, 0u, 0u, 0u};
            if (m0 + row < M)
                v = *(const uint4*)(Ab + (long)(m0 + row) * lda + k0 + sslot);
            *(uint4*)&As[row * LDP + sslot] = v;
        }
        #pragma unroll
        for (int r = 0; r < BN / 64; ++r) {
            const int row = r * 64 + srow;
            uint4 v = {0u, 0u, 0u, 0u};
            if (n0 + row < N)
                v = *(const uint4*)(Bb + (long)(n0 + row) * ldb + k0 + sslot);
            *(uint4*)&Bs[row * LDP + sslot] = v;
        }
        __syncthreads();
        s16x8 aq[MR], bq[NR];
        #pragma unroll
        for (int i = 0; i < MR; ++i)
            aq[i] = *(const s16x8*)&As[(wm + i * 16 + (lane & 15)) * LDP + (lane >> 4) * 8];
        #pragma unroll
        for (int j = 0; j < NR; ++j)
            bq[j] = *(const s16x8*)&Bs[(wn + j * 16 + (lane & 15)) * LDP + (lane >> 4) * 8];
        #pragma unroll
        for (int i = 0; i < MR; ++i)
            #pragma unroll
            for (int j = 0; j < NR; ++j)
                acc[i][j] = __builtin_amdgcn_mfma_f32_16x16x32_bf16(aq[i], bq[j], acc[i][j], 0, 0, 0);
        __syncthreads();
    }

    #pragma unroll
    for (int i = 0; i < MR; ++i) {
        const int mrow = m0 + wm + i * 16 + (lane >> 4) * 4;
        #pragma unroll
        for (int j = 0; j < NR; ++j) {
            const int ncol = n0 + wn + j * 16 + (lane & 15);
            if (ncol < N) {
                #pragma unroll
                for (int e = 0; e < 4; ++e) {
                    const int mm = mrow + e;
                    if (mm < M) {
                        const long idx = (long)z * sC + (long)mm * ldc + ncol;
                        if (OBF) ((bf16*)C)[idx] = __float2bfloat16(acc[i][j][e]);
                        else     ((float*)C)[idx] = acc[i][j][e];
                    }
                }
            }
        }
    }
}

// ------------------------------------------------------- generic fp32 GEMM

template<bool BT, bool OBF, bool BBF = false>
__global__ __launch_bounds__(256) void gemm_k(
    const float* __restrict__ A, long sA, int lda,
    const float* __restrict__ B, long sB, int ldb,
    void* __restrict__ C, long sC, int ldc,
    int M, int N, int K)
{
    __shared__ alignas(16) float As[16][64];
    __shared__ alignas(16) float Bs[16][64];
    const int z = blockIdx.z;
    const float* Ab = A + (long)z * sA;
    const float* Bb = B + (long)z * sB;
    const int m0 = blockIdx.x * 64, n0 = blockIdx.y * 64;
    const int tid = threadIdx.x;
    const int tx = tid & 15, ty = tid >> 4;
    const int amm = tid >> 2, ak4 = (tid & 3) * 4;
    float acc[4][4] = {};

    for (int k0 = 0; k0 < K; k0 += 16) {
        {
            float4 v = {0.f, 0.f, 0.f, 0.f};
            const int row = m0 + amm;
            if (row < M) {
                if (k0 + ak4 + 3 < K) {
                    v = *(const float4*)(Ab + (long)row * lda + k0 + ak4);
                } else {
                    float* vp = (float*)&v;
                    for (int j = 0; j < 4; ++j)
                        if (k0 + ak4 + j < K) vp[j] = Ab[(long)row * lda + k0 + ak4 + j];
                }
            }
            As[ak4 + 0][amm] = v.x; As[ak4 + 1][amm] = v.y;
            As[ak4 + 2][amm] = v.z; As[ak4 + 3][amm] = v.w;
        }
        if (BT) {
            float4 v = {0.f, 0.f, 0.f, 0.f};
            const int row = n0 + amm;
            if (row < N) {
                if (k0 + ak4 + 3 < K) {
                    v = *(const float4*)(Bb + (long)row * ldb + k0 + ak4);
                } else {
                    float* vp = (float*)&v;
                    for (int j = 0; j < 4; ++j)
                        if (k0 + ak4 + j < K) vp[j] = Bb[(long)row * ldb + k0 + ak4 + j];
                }
            }
            Bs[ak4 + 0][amm] = v.x; Bs[ak4 + 1][amm] = v.y;
            Bs[ak4 + 2][amm] = v.z; Bs[ak4 + 3][amm] = v.w;
        } else {
            const int nn = tid & 63, kb = tid >> 6;
            #pragma unroll
            for (int r = 0; r < 4; ++r) {
                const int kk = kb * 4 + r;
                float v = 0.f;
                if (k0 + kk < K && n0 + nn < N) {
                    if (BBF) v = __bfloat162float(
                        ((const bf16*)B)[(long)z * sB + (long)(k0 + kk) * ldb + n0 + nn]);
                    else v = Bb[(long)(k0 + kk) * ldb + n0 + nn];
                }
                Bs[kk][nn] = v;
            }
        }
        __syncthreads();
        #pragma unroll
        for (int kk = 0; kk < 16; ++kk) {
            const float4 av = *(const float4*)&As[kk][ty * 4];
            const float4 bv = *(const float4*)&Bs[kk][tx * 4];
            const float* ap = (const float*)&av;
            const float* bp = (const float*)&bv;
            #pragma unroll
            for (int i = 0; i < 4; ++i)
                #pragma unroll
                for (int j = 0; j < 4; ++j)
                    acc[i][j] = fmaf(ap[i], bp[j], acc[i][j]);
        }
        __syncthreads();
    }
    for (int i = 0; i < 4; ++i) {
        const int m = m0 + ty * 4 + i;
        if (m >= M) break;
        for (int j = 0; j < 4; ++j) {
            const int nn = n0 + tx * 4 + j;
            if (nn < N) {
                const long idx = (long)z * sC + (long)m * ldc + nn;
                if (OBF) ((bf16*)C)[idx] = __float2bfloat16(acc[i][j]);
                else     ((float*)C)[idx] = acc[i][j];
            }
        }
    }
}

// ------------------------------------------------- softmaxes for GAT layer

__global__ void bsoft_k(const float* __restrict__ sc, float* __restrict__ mx, float* __restrict__ sm)
{
    const int idx = blockIdx.x * 256 + threadIdx.x;
    if (idx >= SCSZ) return;
    float m = -1e30f;
    for (int b = 0; b < B_; ++b) m = fmaxf(m, sc[(long)b * SCSZ + idx]);
    float s = 0.f;
    for (int b = 0; b < B_; ++b) s += expf(sc[(long)b * SCSZ + idx] - m);
    mx[idx] = m; sm[idx] = s;
}

__global__ __launch_bounds__(512) void colsoft_k(
    float* __restrict__ sc, const float* __restrict__ mx,
    const float* __restrict__ sm, const unsigned char* __restrict__ cond)
{
    __shared__ float red[8][64];
    const int ml = threadIdx.x & 63;
    const int ng = threadIdx.x >> 6;
    const int m = blockIdx.x * 64 + ml;
    const int b = blockIdx.y;
    float* scb = sc + (long)b * SCSZ;
    const unsigned char* cb = cond + (long)b * (N_ * N_);
    const bool act = m < N_;

    float vmax = -1e30f;
    for (int n = ng; n < N_; n += 8) {
        const int o = n * SCLD + m;
        if (act && cb[n * N_ + m]) {
            const float e = expf(scb[o] - mx[o]) / sm[o];
            scb[o] = e;
            vmax = fmaxf(vmax, e);
        }
    }
    red[ng][ml] = vmax;
    __syncthreads();
    vmax = red[0][ml];
    #pragma unroll
    for (int i = 1; i < 8; ++i) vmax = fmaxf(vmax, red[i][ml]);

    float ssum = 0.f;
    for (int n = ng; n < N_; n += 8) {
        const int o = n * SCLD + m;
        if (act && cb[n * N_ + m]) ssum += expf(scb[o] - vmax);
    }
    __syncthreads();
    red[ng][ml] = ssum;
    __syncthreads();
    ssum = 0.f;
    #pragma unroll
    for (int i = 0; i < 8; ++i) ssum += red[i][ml];
    const float inv = 1.0f / ssum;

    for (int n = ng; n < N_; n += 8) {
        const int o = n * SCLD + m;
        if (act) scb[o] = cb[n * N_ + m] ? expf(scb[o] - vmax) * inv : 0.f;
    }
}

__global__ void nsoft_k(const float* __restrict__ hp, bf16* __restrict__ out)
{
    const int f = blockIdx.x * 256 + threadIdx.x;
    const int b = blockIdx.y;
    const float* hb = hp + (long)b * (N_ * 512) + f;
    float vmax = -1e30f;
    for (int n = 0; n < N_; ++n) vmax = fmaxf(vmax, hb[n * 512]);
    float s = 0.f;
    for (int n = 0; n < N_; ++n) s += expf(hb[n * 512] - vmax);
    const float inv = 1.0f / s;
    bf16* ob = out + (long)b * (N_ * 512) + f;
    for (int n = 0; n < N_; ++n) ob[n * 512] = __float2bfloat16(expf(hb[n * 512] - vmax) * inv);
}

// ----------------------------------------------------------------- GRU prep

__global__ void xrev_k(const bf16* __restrict__ out2, const int* __restrict__ seq_lens,
                       bf16* __restrict__ xr)
{
    const int t = blockIdx.x, b = blockIdx.y;
    const int d = threadIdx.x * 4;
    int src = seq_lens[b] - 1 - t;
    if (src < 0) src = 0;
    *(uint2*)(xr + ((long)t * B_ + b) * 512 + d) =
        *(const uint2*)(out2 + ((long)b * N_ + src) * 512 + d);
}

__global__ void zero_k(float* __restrict__ p, long n)
{
    for (long i = (long)blockIdx.x * 256 + threadIdx.x; i < n; i += (long)gridDim.x * 256)
        p[i] = 0.f;
}

// ------------------------------------------------------ GRU recurrence (v3)
// v1's proven 256-block shape (dir, 8u-slab, 32b-half) + v2's proven MFMA
// matvec. 128 thr = 2 waves, each wave = one 16-batch C-tile. Whh hi/lo bf16
// LDS-resident (mirror rows: A row m>=8 reads m-8, so C rows 8-15 duplicate
// 0-7 -> all lanes fully uniform, dup stores benign). h exchanged hi/lo bf16
// via relaxed agent atomics; h carried fp32 in regs. out-writes DEFERRED past
// the barrier-notify (drain overlaps next step's wait). Barrier: v1's
// 16-leaf x 8 tree per dir.

__device__ __forceinline__ void dbar(unsigned* __restrict__ gc, unsigned* __restrict__ root,
                                     int step) {
    __syncthreads();   // exec barrier + vmcnt drain of this block's stores
    if (threadIdx.x == 0) {
        const unsigned old =
            __hip_atomic_fetch_add(gc, 1u, __ATOMIC_RELAXED, __HIP_MEMORY_SCOPE_AGENT);
        if (old == (unsigned)(step * 8 + 7))
            __hip_atomic_fetch_add(root, 1u, __ATOMIC_RELAXED, __HIP_MEMORY_SCOPE_AGENT);
        while (__hip_atomic_load(root, __ATOMIC_RELAXED, __HIP_MEMORY_SCOPE_AGENT)
               < (unsigned)((step + 1) * 16)) {
            __builtin_amdgcn_s_sleep(1);
        }
    }
    __syncthreads();
}

__global__ __launch_bounds__(128, 1) void gru_recur3(
    const bf16* __restrict__ gif, const bf16* __restrict__ gib,
    const float* __restrict__ Whh, const float* __restrict__ bih,
    const float* __restrict__ bhh, const int* __restrict__ seq_lens,
    float* __restrict__ hbuf_f, unsigned* __restrict__ bar,
    float* __restrict__ outf, float* __restrict__ outb,
    float* __restrict__ hfin)
{
    __shared__ short wlds[2 * 3 * 8 * WPAD];   // [hilo][gate][ul][WPAD] ~50 KB
    __shared__ float padl[8192];               // +32 KB -> ~83 KB: force 1 block/CU
    const int tid = threadIdx.x;               // 0..127
    const int lane = tid & 63;
    const int w = tid >> 6;                    // 16-batch tile
    const int ml = lane & 15;
    const int ksl = lane >> 4;                 // 0..3
    const int dir = blockIdx.x >> 7;
    const int bl  = blockIdx.x & 127;
    const int ub  = (bl >> 1) * 8;             // u-slab base (8 u's)
    const int bh  = bl & 1;                    // batch half
    const int grp = bl >> 3;
    unsigned* gc   = bar + (dir * 16 + grp) * 32;
    unsigned* root = bar + 1024 + dir * 32;
    bf16* hb = (bf16*)hbuf_f;

    if (seq_lens[0] == -12345) padl[tid] = 1.f;   // keep padl allocated

    // one-time: Whh slab -> LDS hi/lo bf16 (rows: gate g, local u 0..7)
    {
        const float* Wb = Whh + (long)dir * (1536 * 512);
        for (int idx = tid; idx < 3 * 8 * 512; idx += 128) {
            const int row = idx >> 9;          // 0..23
            const int k = idx & 511;
            const int g = row >> 3, ul = row & 7;
            const float v = Wb[(long)(g * 512 + ub + ul) * 512 + k];
            const bf16 hi = __float2bfloat16(v);
            const bf16 lo = __float2bfloat16(v - __bfloat162float(hi));
            wlds[(0 * 24 + g * 8 + ul) * WPAD + k] = *(const short*)&hi;
            wlds[(1 * 24 + g * 8 + ul) * WPAD + k] = *(const short*)&lo;
        }
    }

    const int bcol = bh * 32 + w * 16 + ml;    // this lane's batch (C col)
    const int ue   = ub + (ksl & 1) * 4;       // this lane's u-quad (mirror: ksl&1)
    const bf16* gi = dir ? gib : gif;
    float cr[4], cz[4], cn[4], brr[4], bzz[4], bnn[4];
    #pragma unroll
    for (int e = 0; e < 4; ++e) {
        cr[e]  = bih[dir * 1536 + ue + e];
        cz[e]  = bih[dir * 1536 + 512 + ue + e];
        cn[e]  = bih[dir * 1536 + 1024 + ue + e];
        brr[e] = bhh[dir * 1536 + ue + e];
        bzz[e] = bhh[dir * 1536 + 512 + ue + e];
        bnn[e] = bhh[dir * 1536 + 1024 + ue + e];
    }
    const int sl = seq_lens[bcol];
    float hreg[4] = {0.f, 0.f, 0.f, 0.f};
    float owv[4] = {0.f, 0.f, 0.f, 0.f};       // deferred out values

    // init phase-0 h (hi & lo planes) — duplicate stores from ksl>=2 benign
    {
        const long z0 = (long)((dir * 2 + 0) * 2 + 0) * 32768 + bcol * 512 + ue;
        const long z1 = (long)((dir * 2 + 0) * 2 + 1) * 32768 + bcol * 512 + ue;
        __hip_atomic_store((ull*)(hb + z0), 0ull, __ATOMIC_RELAXED, __HIP_MEMORY_SCOPE_AGENT);
        __hip_atomic_store((ull*)(hb + z1), 0ull, __ATOMIC_RELAXED, __HIP_MEMORY_SCOPE_AGENT);
    }
    dbar(gc, root, 0);

    for (int t = 0; t < N_; ++t) {
        const int rp = t & 1, wp = rp ^ 1;
        const bf16* rhi = hb + (long)((dir * 2 + rp) * 2 + 0) * 32768 + bcol * 512;
        const bf16* rlo = hb + (long)((dir * 2 + rp) * 2 + 1) * 32768 + bcol * 512;

        // 1. issue ALL h-fragment loads first (critical path)
        ull bhv[32], blv[32];
        #pragma unroll
        for (int ks = 0; ks < 16; ++ks) {
            const int o = ks * 32 + ksl * 8;
            bhv[ks * 2 + 0] = __hip_atomic_load((const ull*)(rhi + o),
                                  __ATOMIC_RELAXED, __HIP_MEMORY_SCOPE_AGENT);
            bhv[ks * 2 + 1] = __hip_atomic_load((const ull*)(rhi + o + 4),
                                  __ATOMIC_RELAXED, __HIP_MEMORY_SCOPE_AGENT);
            blv[ks * 2 + 0] = __hip_atomic_load((const ull*)(rlo + o),
                                  __ATOMIC_RELAXED, __HIP_MEMORY_SCOPE_AGENT);
            blv[ks * 2 + 1] = __hip_atomic_load((const ull*)(rlo + o + 4),
                                  __ATOMIC_RELAXED, __HIP_MEMORY_SCOPE_AGENT);
        }

        // 2. deferred out-writes of step t-1 (drain overlaps this step's work)
        if (t > 0) {
            const int tp = t - 1;
            if (dir == 0) {
                #pragma unroll
                for (int e = 0; e < 4; ++e)
                    outf[(long)tp * 32768 + (ue + e) * 64 + bcol] = owv[e];
            } else if (tp < sl) {
                #pragma unroll
                for (int e = 0; e < 4; ++e)
                    outb[(long)(sl - 1 - tp) * 32768 + (ue + e) * 64 + bcol] = owv[e];
            }
        }

        // 3. gi for this step (consumed in epilogue)
        float gv[3][4];
        #pragma unroll
        for (int g = 0; g < 3; ++g)
            #pragma unroll
            for (int e = 0; e < 4; ++e)
                gv[g][e] = __bfloat162float(
                    gi[(long)t * 98304 + (g * 512 + ue + e) * 64 + bcol]);

        // 4. MFMA matvec: 3 gate-tiles x 16 k-chunks x 3 hi/lo combos
        f32x4 acc[3] = {};
        #pragma unroll
        for (int ks = 0; ks < 16; ++ks) {
            FRG fh, fl;
            fh.u[0] = bhv[ks * 2]; fh.u[1] = bhv[ks * 2 + 1];
            fl.u[0] = blv[ks * 2]; fl.u[1] = blv[ks * 2 + 1];
            const int ko = ks * 32 + ksl * 8;
            const int mr = ml & 7;             // mirror row
            const s16x8 a0h = *(const s16x8*)&wlds[(0 * 24 + 0 * 8 + mr) * WPAD + ko];
            const s16x8 a1h = *(const s16x8*)&wlds[(0 * 24 + 1 * 8 + mr) * WPAD + ko];
            const s16x8 a2h = *(const s16x8*)&wlds[(0 * 24 + 2 * 8 + mr) * WPAD + ko];
            const s16x8 a0l = *(const s16x8*)&wlds[(1 * 24 + 0 * 8 + mr) * WPAD + ko];
            const s16x8 a1l = *(const s16x8*)&wlds[(1 * 24 + 1 * 8 + mr) * WPAD + ko];
            const s16x8 a2l = *(const s16x8*)&wlds[(1 * 24 + 2 * 8 + mr) * WPAD + ko];
            acc[0] = __builtin_amdgcn_mfma_f32_16x16x32_bf16(a0h, fh.v, acc[0], 0, 0, 0);
            acc[1] = __builtin_amdgcn_mfma_f32_16x16x32_bf16(a1h, fh.v, acc[1], 0, 0, 0);
            acc[2] = __builtin_amdgcn_mfma_f32_16x16x32_bf16(a2h, fh.v, acc[2], 0, 0, 0);
            acc[0] = __builtin_amdgcn_mfma_f32_16x16x32_bf16(a0h, fl.v, acc[0], 0, 0, 0);
            acc[1] = __builtin_amdgcn_mfma_f32_16x16x32_bf16(a1h, fl.v, acc[1], 0, 0, 0);
            acc[2] = __builtin_amdgcn_mfma_f32_16x16x32_bf16(a2h, fl.v, acc[2], 0, 0, 0);
            acc[0] = __builtin_amdgcn_mfma_f32_16x16x32_bf16(a0l, fh.v, acc[0], 0, 0, 0);
            acc[1] = __builtin_amdgcn_mfma_f32_16x16x32_bf16(a1l, fh.v, acc[1], 0, 0, 0);
            acc[2] = __builtin_amdgcn_mfma_f32_16x16x32_bf16(a2l, fh.v, acc[2], 0, 0, 0);
        }

        // 5. gate nonlinearity + h update (uniform across lanes; dups consistent)
        ull phi = 0, plo = 0;
        const bool msk = t < sl;
        #pragma unroll
        for (int e = 0; e < 4; ++e) {
            const float rg = sigmoidf_(cr[e] + gv[0][e] + brr[e] + acc[0][e]);
            const float zg = sigmoidf_(cz[e] + gv[1][e] + bzz[e] + acc[1][e]);
            const float ng = tanhf(cn[e] + gv[2][e] + rg * (bnn[e] + acc[2][e]));
            const float hnew = (1.f - zg) * ng + zg * hreg[e];
            owv[e] = (dir == 0) ? (msk ? hnew : 0.f) : hnew;
            hreg[e] = msk ? hnew : hreg[e];
            const bf16 h_hi = __float2bfloat16(hreg[e]);
            const bf16 h_lo = __float2bfloat16(hreg[e] - __bfloat162float(h_hi));
            phi |= (ull)(*(const unsigned short*)&h_hi) << (16 * e);
            plo |= (ull)(*(const unsigned short*)&h_lo) << (16 * e);
        }
        const long wbh = (long)((dir * 2 + wp) * 2 + 0) * 32768 + bcol * 512 + ue;
        const long wbl = (long)((dir * 2 + wp) * 2 + 1) * 32768 + bcol * 512 + ue;
        __hip_atomic_store((ull*)(hb + wbh), phi, __ATOMIC_RELAXED, __HIP_MEMORY_SCOPE_AGENT);
        __hip_atomic_store((ull*)(hb + wbl), plo, __ATOMIC_RELAXED, __HIP_MEMORY_SCOPE_AGENT);

        dbar(gc, root, t + 1);
    }

    // final deferred out-write (t = N_-1) + final hidden state
    {
        const int tp = N_ - 1;
        if (dir == 0) {
            #pragma unroll
            for (int e = 0; e < 4; ++e)
                outf[(long)tp * 32768 + (ue + e) * 64 + bcol] = owv[e];
        } else if (tp < sl) {
            #pragma unroll
            for (int e = 0; e < 4; ++e)
                outb[(long)(sl - 1 - tp) * 32768 + (ue + e) * 64 + bcol] = owv[e];
        }
        #pragma unroll
        for (int e = 0; e < 4; ++e)
            hfin[dir * 32768 + (ue + e) * 64 + bcol] = hreg[e];
    }
}

// --------------------------------------------------------------- finalize

__global__ void final_k(const float* __restrict__ outf, const float* __restrict__ outb,
                        const float* __restrict__ hfin, const int* __restrict__ seq_lens,
                        float* __restrict__ dout)
{
    const long i = (long)blockIdx.x * 256 + threadIdx.x;
    const long NOUT = (long)N_ * B_ * 512;
    if (i < NOUT) {
        const int t = (int)(i >> 15);
        const int b = (int)((i >> 9) & 63);
        const int u = (int)(i & 511);
        const long src = (long)t * 32768 + u * 64 + b;
        dout[i] = (t < seq_lens[b]) ? outf[src] + outb[src] : 0.f;
    } else if (i < NOUT + 2 * B_ * 512) {
        const long j = i - NOUT;
        const int dir = (int)(j >> 15);
        const int b = (int)((j >> 9) & 63);
        const int u = (int)(j & 511);
        dout[i] = hfin[dir * 32768 + u * 64 + b];
    }
}

__global__ void fail_zero_k(float* __restrict__ dout, long n)
{
    for (long i = (long)blockIdx.x * 256 + threadIdx.x; i < n; i += (long)gridDim.x * 256)
        dout[i] = 0.f;
}

// ----------------------------------------------------------------- launch

extern "C" void kernel_launch(void* const* d_in, const int* in_sizes, int n_in,
                              void* d_out, int out_size, void* d_ws, size_t ws_size,
                              hipStream_t stream)
{
    const int*   tokens   = (const int*)d_in[0];
    const int*   tok_lens = (const int*)d_in[1];
    const int*   seq_lens = (const int*)d_in[2];
    const float* adj      = (const float*)d_in[3];
    const float* emb      = (const float*)d_in[4];
    const float* Wq       = (const float*)d_in[5];
    const float* Wk       = (const float*)d_in[6];
    const float* Wq_o     = (const float*)d_in[7];
    const float* Wk_o     = (const float*)d_in[8];
    const float* gWih     = (const float*)d_in[9];
    const float* gWhh     = (const float*)d_in[10];
    const float* gbih     = (const float*)d_in[11];
    const float* gbhh     = (const float*)d_in[12];
    float* out = (float*)d_out;

    const long SZ = (long)B_ * N_ * 512;   // 9,830,400 elements
    float* F1 = (float*)d_ws;              // q1   -> outf
    float* F2 = F1 + SZ;                   // k1   -> outb
    float* F3 = F2 + SZ;                   // hp1  -> hp2
    bf16* b0 = (bf16*)(F3 + SZ);           // embx -> out2
    bf16* b1 = b0 + SZ;                    // x1   -> x_rev
    bf16* b2 = b1 + SZ;                    // q2   -> wih(bf16)
    bf16* b3 = b2 + SZ;                    // k2
    float* sc   = (float*)(b3 + SZ);
    float* mx   = sc + (long)B_ * SCSZ;
    float* smv  = mx + SCSZ;
    unsigned char* cond = (unsigned char*)(smv + SCSZ);
    bf16* gif = (bf16*)(cond + (long)B_ * N_ * N_);
    bf16* gib = gif + (long)N_ * 1536 * B_;
    float* hbuf = (float*)(gib + (long)N_ * 1536 * B_);   // 512 KB bf16 hi/lo x 2ph x 2dir
    unsigned* bar = (unsigned*)(hbuf + 131072);
    float* hfin = (float*)(bar + 2048);                   // 2 x 512 x 64 fp32 final h
    const size_t needed = (size_t)((char*)(hfin + 2 * 512 * 64) - (char*)d_ws);
    if (ws_size < needed) {
        fail_zero_k<<<4096, 256, 0, stream>>>(out, out_size);
        return;
    }
    bf16* wq1  = (bf16*)sc;
    bf16* wk1  = wq1 + 512 * 512;
    bf16* w2q  = (bf16*)sc;
    bf16* w2k  = w2q + 512 * 512;
    bf16* wihb = b2;

    // 1. layer-1 weight prep, embedding (bf16), cond
    wgath_k<<<512, 512, 0, stream>>>(Wq, wq1);
    wgath_k<<<512, 512, 0, stream>>>(Wk, wk1);
    embed_k<<<dim3(N_, B_), 128, 0, stream>>>(tokens, tok_lens, seq_lens, emb, b0);
    cond_k<<<dim3(5, 5, B_), 256, 0, stream>>>(adj, cond);

    // 2. layer-1 projections via MFMA (fp32 out): q1 -> F1, k1 -> F2
    mgemm_k<128, 128, false><<<dim3(150, 4, 1), 256, 0, stream>>>(
        b0, 0, 512, wq1, 0, 512, F1, 0, 512, B_ * N_, 512, 512);
    mgemm_k<128, 128, false><<<dim3(150, 4, 1), 256, 0, stream>>>(
        b0, 0, 512, wk1, 0, 512, F2, 0, 512, B_ * N_, 512, 512);

    // 3. per-head attention (fp32 SIMT: K=64)
    for (int h = 0; h < NHEADS_; ++h) {
        gemm_k<true, false><<<dim3(5, 5, B_), 256, 0, stream>>>(
            F1 + h * 64, (long)N_ * 512, 512,
            F2 + h * 64, (long)N_ * 512, 512,
            sc, SCSZ, SCLD, N_, N_, 64);
        bsoft_k<<<(SCSZ + 255) / 256, 256, 0, stream>>>(sc, mx, smv);
        colsoft_k<<<dim3(5, B_), 512, 0, stream>>>(sc, mx, smv, cond);
        gemm_k<false, false><<<dim3(5, 1, B_), 256, 0, stream>>>(
            sc, SCSZ, SCLD,
            F2 + h * 64, (long)N_ * 512, 512,
            F3 + h * 64, (long)N_ * 512, 512, N_, 64, N_);
    }
    nsoft_k<<<dim3(2, B_), 256, 0, stream>>>(F3, b1);               // x1 (bf16)

    // 4. layer-2 via MFMA: q2/k2 (bf16 out), scores2
    wtr_k<<<512, 512, 0, stream>>>(Wq_o, w2q);
    wtr_k<<<512, 512, 0, stream>>>(Wk_o, w2k);
    mgemm_k<128, 128, true><<<dim3(150, 4, 1), 256, 0, stream>>>(
        b1, 0, 512, w2q, 0, 512, b2, 0, 512, B_ * N_, 512, 512);
    mgemm_k<128, 128, true><<<dim3(150, 4, 1), 256, 0, stream>>>(
        b1, 0, 512, w2k, 0, 512, b3, 0, 512, B_ * N_, 512, 512);
    mgemm_k<64, 64, false><<<dim3(5, 5, B_), 256, 0, stream>>>(
        b2, (long)N_ * 512, 512, b3, (long)N_ * 512, 512,
        sc, SCSZ, SCLD, N_, N_, 512);
    f2b_k<<<6144, 256, 0, stream>>>(gWih, wihb, (long)2 * 1536 * 512);
    bsoft_k<<<(SCSZ + 255) / 256, 256, 0, stream>>>(sc, mx, smv);
    colsoft_k<<<dim3(5, B_), 512, 0, stream>>>(sc, mx, smv, cond);
    gemm_k<false, false, true><<<dim3(5, 8, B_), 256, 0, stream>>>(
        sc, SCSZ, SCLD, (const float*)(const void*)b3, (long)N_ * 512, 512,
        F3, (long)N_ * 512, 512, N_, 512, N_);
    nsoft_k<<<dim3(2, B_), 256, 0, stream>>>(F3, b0);                // out2 (bf16)

    // 5. GRU input GEMMs via MFMA (bf16 out, layout (t, j, b))
    xrev_k<<<dim3(N_, B_), 128, 0, stream>>>(b0, seq_lens, b1);
    zero_k<<<1, 256, 0, stream>>>((float*)bar, 2048);
    mgemm_k<64, 64, true><<<dim3(24, 1, N_), 256, 0, stream>>>(
        wihb, 0, 512, b0, 512, (long)N_ * 512, gif, 1536 * 64, 64, 1536, 64, 512);
    mgemm_k<64, 64, true><<<dim3(24, 1, N_), 256, 0, stream>>>(
        wihb + 1536 * 512, 0, 512, b1, (long)B_ * 512, 512, gib, 1536 * 64, 64, 1536, 64, 512);

    // 6. recurrence (256 blocks, MFMA matvec, deferred outs) + finalize
    gru_recur3<<<256, 128, 0, stream>>>(gif, gib, gWhh, gbih, gbhh, seq_lens,
                                        hbuf, bar, F1, F2, hfin);
    final_k<<<38656, 256, 0, stream>>>(F1, F2, hfin, seq_lens, out);
}

// Round 6
// 4294.708 us; speedup vs baseline: 1.4046x; 1.1841x over previous
//
#include <hip/hip_runtime.h>
#include <hip/hip_bf16.h>

typedef __hip_bfloat16 bf16;
typedef unsigned long long ull;
typedef __attribute__((ext_vector_type(8))) short s16x8;
typedef __attribute__((ext_vector_type(4))) float f32x4;

union FRG { ull u[2]; s16x8 v; };

#define B_      64
#define NMAX_   299
#define N_      300
#define D_      512
#define H_      512
#define NHEADS_ 8
#define NHID_   64
#define SCLD    304                  // padded leading dim for (n,m) score rows
#define SCSZ    (N_ * SCLD)          // 91,200 floats per batch
#define LDP     48                   // padded LDS row stride (bf16 elems) for mgemm
#define WPAD    536                  // Whh LDS k-stride (shorts)
#define HP      520                  // h LDS row stride (shorts): 2-way bank alias only

// ---------------------------------------------------------------- utilities

__device__ __forceinline__ float sigmoidf_(float x) { return 1.0f / (1.0f + expf(-x)); }

// ---------------------------------------------------------------- embedding

__global__ void embed_k(const int* __restrict__ tokens, const int* __restrict__ tok_lens,
                        const int* __restrict__ seq_lens, const float* __restrict__ emb,
                        bf16* __restrict__ out)
{
    const int n = blockIdx.x, b = blockIdx.y;
    const int d = threadIdx.x * 4;
    const int nc = seq_lens[b] - 1;
    float4 v;
    if (n < nc) {
        const int tl = tok_lens[b * NMAX_ + n];
        const int* tp = tokens + (b * NMAX_ + n) * 8;
        float4 acc = {0.f, 0.f, 0.f, 0.f};
        for (int t = 0; t < 8; ++t) {
            if (t < tl) {
                const float4 e = *(const float4*)(emb + (long)tp[t] * D_ + d);
                acc.x += e.x; acc.y += e.y; acc.z += e.z; acc.w += e.w;
            }
        }
        const float inv = 1.0f / (float)nc;
        v.x = acc.x * inv; v.y = acc.y * inv; v.z = acc.z * inv; v.w = acc.w * inv;
    } else {
        const int row = (n == nc) ? 2 : 0;
        v = *(const float4*)(emb + row * D_ + d);
    }
    bf16 o[4] = {__float2bfloat16(v.x), __float2bfloat16(v.y),
                 __float2bfloat16(v.z), __float2bfloat16(v.w)};
    *(uint2*)(out + ((long)b * N_ + n) * D_ + d) = *(uint2*)o;
}

// ------------------------------------------------------------------- cond

__global__ void cond_k(const float* __restrict__ adj, unsigned char* __restrict__ cond)
{
    __shared__ float T1[64][65];
    __shared__ float T2[64][65];
    const int b = blockIdx.z;
    const int n0 = blockIdx.x * 64, m0 = blockIdx.y * 64;
    const int jj = threadIdx.x & 63, i0 = threadIdx.x >> 6;
    for (int r = 0; r < 16; ++r) {
        const int i = i0 * 16 + r;
        const int n = n0 + i, m = m0 + jj;
        T1[i][jj] = (n < N_ && m < N_) ? adj[((long)b * N_ + n) * N_ + m] : 0.f;
        const int n2 = m0 + i, m2 = n0 + jj;
        T2[i][jj] = (n2 < N_ && m2 < N_) ? adj[((long)b * N_ + n2) * N_ + m2] : 0.f;
    }
    __syncthreads();
    for (int r = 0; r < 16; ++r) {
        const int i = i0 * 16 + r;
        const int n = n0 + i, m = m0 + jj;
        if (n < N_ && m < N_) {
            const float v = T1[i][jj] + T2[jj][i] + ((n == m) ? 1.f : 0.f);
            cond[((long)b * N_ + n) * N_ + m] = (v > 0.f) ? 1 : 0;
        }
    }
}

// -------------------------------------------------- weight prep (fp32->bf16)

__global__ void wgath_k(const float* __restrict__ W, bf16* __restrict__ out)
{   // (8,512,64) -> (512,512): out[h*64+o][d] = W[h][d][o]
    const int row = blockIdx.x;
    const int d = threadIdx.x;
    const int h = row >> 6, o = row & 63;
    out[row * 512 + d] = __float2bfloat16(W[((long)h * 512 + d) * 64 + o]);
}

__global__ void wtr_k(const float* __restrict__ W, bf16* __restrict__ out)
{   // (512,512) -> transposed: out[o][i] = W[i][o]
    const int o = blockIdx.x;
    const int i = threadIdx.x;
    out[o * 512 + i] = __float2bfloat16(W[(long)i * 512 + o]);
}

__global__ void f2b_k(const float* __restrict__ in, bf16* __restrict__ out, long n)
{
    for (long i = (long)blockIdx.x * 256 + threadIdx.x; i < n; i += (long)gridDim.x * 256)
        out[i] = __float2bfloat16(in[i]);
}

// ------------------------------------------------------- bf16 MFMA GEMM

template<int BM, int BN, bool OBF>
__global__ __launch_bounds__(256) void mgemm_k(
    const bf16* __restrict__ A, long sA, int lda,
    const bf16* __restrict__ Bm, long sB, int ldb,
    void* __restrict__ C, long sC, int ldc,
    int M, int N, int K)
{
    __shared__ short As[BM * LDP];
    __shared__ short Bs[BN * LDP];
    const int z = blockIdx.z;
    const bf16* Ab = A + (long)z * sA;
    const bf16* Bb = Bm + (long)z * sB;
    const int m0 = blockIdx.x * BM, n0 = blockIdx.y * BN;
    const int tid = threadIdx.x;
    const int lane = tid & 63;
    const int w = tid >> 6;
    const int wm = (w >> 1) * (BM / 2);
    const int wn = (w & 1) * (BN / 2);
    constexpr int MR = BM / 32;
    constexpr int NR = BN / 32;
    f32x4 acc[MR][NR] = {};

    const int srow = tid >> 2;
    const int sslot = (tid & 3) * 8;

    for (int k0 = 0; k0 < K; k0 += 32) {
        #pragma unroll
        for (int r = 0; r < BM / 64; ++r) {
            const int row = r * 64 + srow;
            uint4 v = {0u, 0u, 0u, 0u};
            if (m0 + row < M)
                v = *(const uint4*)(Ab + (long)(m0 + row) * lda + k0 + sslot);
            *(uint4*)&As[row * LDP + sslot] = v;
        }
        #pragma unroll
        for (int r = 0; r < BN / 64; ++r) {
            const int row = r * 64 + srow;
            uint4 v = {0u, 0u, 0u, 0u};
            if (n0 + row < N)
                v = *(const uint4*)(Bb + (long)(n0 + row) * ldb + k0 + sslot);
            *(uint4*)&Bs[row * LDP + sslot] = v;
        }
        __syncthreads();
        s16x8 aq[MR], bq[NR];
        #pragma unroll
        for (int i = 0; i < MR; ++i)
            aq[i] = *(const s16x8*)&As[(wm + i * 16 + (lane & 15)) * LDP + (lane >> 4) * 8];
        #pragma unroll
        for (int j = 0; j < NR; ++j)
            bq[j] = *(const s16x8*)&Bs[(wn + j * 16 + (lane & 15)) * LDP + (lane >> 4) * 8];
        #pragma unroll
        for (int i = 0; i < MR; ++i)
            #pragma unroll
            for (int j = 0; j < NR; ++j)
                acc[i][j] = __builtin_amdgcn_mfma_f32_16x16x32_bf16(aq[i], bq[j], acc[i][j], 0, 0, 0);
        __syncthreads();
    }

    #pragma unroll
    for (int i = 0; i < MR; ++i) {
        const int mrow = m0 + wm + i * 16 + (lane >> 4) * 4;
        #pragma unroll
        for (int j = 0; j < NR; ++j) {
            const int ncol = n0 + wn + j * 16 + (lane & 15);
            if (ncol < N) {
                #pragma unroll
                for (int e = 0; e < 4; ++e) {
                    const int mm = mrow + e;
                    if (mm < M) {
                        const long idx = (long)z * sC + (long)mm * ldc + ncol;
                        if (OBF) ((bf16*)C)[idx] = __float2bfloat16(acc[i][j][e]);
                        else     ((float*)C)[idx] = acc[i][j][e];
                    }
                }
            }
        }
    }
}

// ------------------------------------------------------- generic fp32 GEMM

template<bool BT, bool OBF, bool BBF = false>
__global__ __launch_bounds__(256) void gemm_k(
    const float* __restrict__ A, long sA, int lda,
    const float* __restrict__ B, long sB, int ldb,
    void* __restrict__ C, long sC, int ldc,
    int M, int N, int K)
{
    __shared__ alignas(16) float As[16][64];
    __shared__ alignas(16) float Bs[16][64];
    const int z = blockIdx.z;
    const float* Ab = A + (long)z * sA;
    const float* Bb = B + (long)z * sB;
    const int m0 = blockIdx.x * 64, n0 = blockIdx.y * 64;
    const int tid = threadIdx.x;
    const int tx = tid & 15, ty = tid >> 4;
    const int amm = tid >> 2, ak4 = (tid & 3) * 4;
    float acc[4][4] = {};

    for (int k0 = 0; k0 < K; k0 += 16) {
        {
            float4 v = {0.f, 0.f, 0.f, 0.f};
            const int row = m0 + amm;
            if (row < M) {
                if (k0 + ak4 + 3 < K) {
                    v = *(const float4*)(Ab + (long)row * lda + k0 + ak4);
                } else {
                    float* vp = (float*)&v;
                    for (int j = 0; j < 4; ++j)
                        if (k0 + ak4 + j < K) vp[j] = Ab[(long)row * lda + k0 + ak4 + j];
                }
            }
            As[ak4 + 0][amm] = v.x; As[ak4 + 1][amm] = v.y;
            As[ak4 + 2][amm] = v.z; As[ak4 + 3][amm] = v.w;
        }
        if (BT) {
            float4 v = {0.f, 0.f, 0.f, 0.f};
            const int row = n0 + amm;
            if (row < N) {
                if (k0 + ak4 + 3 < K) {
                    v = *(const float4*)(Bb + (long)row * ldb + k0 + ak4);
                } else {
                    float* vp = (float*)&v;
                    for (int j = 0; j < 4; ++j)
                        if (k0 + ak4 + j < K) vp[j] = Bb[(long)row * ldb + k0 + ak4 + j];
                }
            }
            Bs[ak4 + 0][amm] = v.x; Bs[ak4 + 1][amm] = v.y;
            Bs[ak4 + 2][amm] = v.z; Bs[ak4 + 3][amm] = v.w;
        } else {
            const int nn = tid & 63, kb = tid >> 6;
            #pragma unroll
            for (int r = 0; r < 4; ++r) {
                const int kk = kb * 4 + r;
                float v = 0.f;
                if (k0 + kk < K && n0 + nn < N) {
                    if (BBF) v = __bfloat162float(
                        ((const bf16*)B)[(long)z * sB + (long)(k0 + kk) * ldb + n0 + nn]);
                    else v = Bb[(long)(k0 + kk) * ldb + n0 + nn];
                }
                Bs[kk][nn] = v;
            }
        }
        __syncthreads();
        #pragma unroll
        for (int kk = 0; kk < 16; ++kk) {
            const float4 av = *(const float4*)&As[kk][ty * 4];
            const float4 bv = *(const float4*)&Bs[kk][tx * 4];
            const float* ap = (const float*)&av;
            const float* bp = (const float*)&bv;
            #pragma unroll
            for (int i = 0; i < 4; ++i)
                #pragma unroll
                for (int j = 0; j < 4; ++j)
                    acc[i][j] = fmaf(ap[i], bp[j], acc[i][j]);
        }
        __syncthreads();
    }
    for (int i = 0; i < 4; ++i) {
        const int m = m0 + ty * 4 + i;
        if (m >= M) break;
        for (int j = 0; j < 4; ++j) {
            const int nn = n0 + tx * 4 + j;
            if (nn < N) {
                const long idx = (long)z * sC + (long)m * ldc + nn;
                if (OBF) ((bf16*)C)[idx] = __float2bfloat16(acc[i][j]);
                else     ((float*)C)[idx] = acc[i][j];
            }
        }
    }
}

// ------------------------------------------------- softmaxes for GAT layer

__global__ void bsoft_k(const float* __restrict__ sc, float* __restrict__ mx, float* __restrict__ sm)
{
    const int idx = blockIdx.x * 256 + threadIdx.x;
    if (idx >= SCSZ) return;
    float m = -1e30f;
    for (int b = 0; b < B_; ++b) m = fmaxf(m, sc[(long)b * SCSZ + idx]);
    float s = 0.f;
    for (int b = 0; b < B_; ++b) s += expf(sc[(long)b * SCSZ + idx] - m);
    mx[idx] = m; sm[idx] = s;
}

__global__ __launch_bounds__(512) void colsoft_k(
    float* __restrict__ sc, const float* __restrict__ mx,
    const float* __restrict__ sm, const unsigned char* __restrict__ cond)
{
    __shared__ float red[8][64];
    const int ml = threadIdx.x & 63;
    const int ng = threadIdx.x >> 6;
    const int m = blockIdx.x * 64 + ml;
    const int b = blockIdx.y;
    float* scb = sc + (long)b * SCSZ;
    const unsigned char* cb = cond + (long)b * (N_ * N_);
    const bool act = m < N_;

    float vmax = -1e30f;
    for (int n = ng; n < N_; n += 8) {
        const int o = n * SCLD + m;
        if (act && cb[n * N_ + m]) {
            const float e = expf(scb[o] - mx[o]) / sm[o];
            scb[o] = e;
            vmax = fmaxf(vmax, e);
        }
    }
    red[ng][ml] = vmax;
    __syncthreads();
    vmax = red[0][ml];
    #pragma unroll
    for (int i = 1; i < 8; ++i) vmax = fmaxf(vmax, red[i][ml]);

    float ssum = 0.f;
    for (int n = ng; n < N_; n += 8) {
        const int o = n * SCLD + m;
        if (act && cb[n * N_ + m]) ssum += expf(scb[o] - vmax);
    }
    __syncthreads();
    red[ng][ml] = ssum;
    __syncthreads();
    ssum = 0.f;
    #pragma unroll
    for (int i = 0; i < 8; ++i) ssum += red[i][ml];
    const float inv = 1.0f / ssum;

    for (int n = ng; n < N_; n += 8) {
        const int o = n * SCLD + m;
        if (act) scb[o] = cb[n * N_ + m] ? expf(scb[o] - vmax) * inv : 0.f;
    }
}

__global__ void nsoft_k(const float* __restrict__ hp, bf16* __restrict__ out)
{
    const int f = blockIdx.x * 256 + threadIdx.x;
    const int b = blockIdx.y;
    const float* hb = hp + (long)b * (N_ * 512) + f;
    float vmax = -1e30f;
    for (int n = 0; n < N_; ++n) vmax = fmaxf(vmax, hb[n * 512]);
    float s = 0.f;
    for (int n = 0; n < N_; ++n) s += expf(hb[n * 512] - vmax);
    const float inv = 1.0f / s;
    bf16* ob = out + (long)b * (N_ * 512) + f;
    for (int n = 0; n < N_; ++n) ob[n * 512] = __float2bfloat16(expf(hb[n * 512] - vmax) * inv);
}

// ----------------------------------------------------------------- GRU prep

__global__ void xrev_k(const bf16* __restrict__ out2, const int* __restrict__ seq_lens,
                       bf16* __restrict__ xr)
{
    const int t = blockIdx.x, b = blockIdx.y;
    const int d = threadIdx.x * 4;
    int src = seq_lens[b] - 1 - t;
    if (src < 0) src = 0;
    *(uint2*)(xr + ((long)t * B_ + b) * 512 + d) =
        *(const uint2*)(out2 + ((long)b * N_ + src) * 512 + d);
}

__global__ void zero_k(float* __restrict__ p, long n)
{
    for (long i = (long)blockIdx.x * 256 + threadIdx.x; i < n; i += (long)gridDim.x * 256)
        p[i] = 0.f;
}

// ------------------------------------------------------ GRU recurrence (v4)
// = v3 + coalesced h-exchange. h global layout [plane][b][u] (u contiguous,
// producer ull stores unchanged). Consumers read their 32-batch half
// COALESCED (adjacent threads adjacent ull within a row), all 64 ull issued
// up-front, staged into LDS [plane][b_local][HP] (row stride 1040B -> 2-way
// bank alias = free), MFMA B-fragments via ds_read_b128. Barrier narrowed to
// 4 independent 64-block groups (dir x batch-half): 8 leaves x 8 -> root.
// Mirror lanes (ksl>=2) hold duplicate C rows: their gi loads + all global
// stores predicated off (halves gi read + h/out write traffic).

__device__ __forceinline__ void dbar4(unsigned* __restrict__ gc, unsigned* __restrict__ root,
                                      int step) {
    __syncthreads();   // exec barrier + vmcnt drain of this block's stores
    if (threadIdx.x == 0) {
        const unsigned old =
            __hip_atomic_fetch_add(gc, 1u, __ATOMIC_RELAXED, __HIP_MEMORY_SCOPE_AGENT);
        if (old == (unsigned)(step * 8 + 7))
            __hip_atomic_fetch_add(root, 1u, __ATOMIC_RELAXED, __HIP_MEMORY_SCOPE_AGENT);
        while (__hip_atomic_load(root, __ATOMIC_RELAXED, __HIP_MEMORY_SCOPE_AGENT)
               < (unsigned)((step + 1) * 8)) {
            __builtin_amdgcn_s_sleep(1);
        }
    }
    __syncthreads();
}

__global__ __launch_bounds__(128, 1) void gru_recur4(
    const bf16* __restrict__ gif, const bf16* __restrict__ gib,
    const float* __restrict__ Whh, const float* __restrict__ bih,
    const float* __restrict__ bhh, const int* __restrict__ seq_lens,
    float* __restrict__ hbuf_f, unsigned* __restrict__ bar,
    float* __restrict__ outf, float* __restrict__ outb,
    float* __restrict__ hfin)
{
    __shared__ short wlds[2 * 3 * 8 * WPAD];   // ~50 KB Whh hi/lo
    __shared__ short hlds[2 * 32 * HP];        // ~65 KB h hi/lo staging
    const int tid = threadIdx.x;               // 0..127
    const int lane = tid & 63;
    const int w = tid >> 6;                    // 16-batch tile
    const int ml = lane & 15;
    const int ksl = lane >> 4;                 // 0..3
    const int dir = blockIdx.x >> 7;
    const int bl  = blockIdx.x & 127;
    const int ub  = (bl >> 1) * 8;             // u-slab base (8 u's)
    const int bh  = bl & 1;                    // batch half
    const int g4  = dir * 2 + bh;              // barrier group (64 blocks)
    unsigned* gc   = bar + (g4 * 8 + ((bl >> 1) >> 3)) * 32;
    unsigned* root = bar + 1024 + g4 * 32;
    bf16* hb = (bf16*)hbuf_f;

    // one-time: Whh slab -> LDS hi/lo bf16 (rows: gate g, local u 0..7)
    {
        const float* Wb = Whh + (long)dir * (1536 * 512);
        for (int idx = tid; idx < 3 * 8 * 512; idx += 128) {
            const int row = idx >> 9;          // 0..23
            const int k = idx & 511;
            const int g = row >> 3, ul = row & 7;
            const float v = Wb[(long)(g * 512 + ub + ul) * 512 + k];
            const bf16 hi = __float2bfloat16(v);
            const bf16 lo = __float2bfloat16(v - __bfloat162float(hi));
            wlds[(0 * 24 + g * 8 + ul) * WPAD + k] = *(const short*)&hi;
            wlds[(1 * 24 + g * 8 + ul) * WPAD + k] = *(const short*)&lo;
        }
    }

    const int bcol = bh * 32 + w * 16 + ml;    // this lane's batch (C col)
    const int ue   = ub + (ksl & 1) * 4;       // this lane's u-quad (mirror)
    const bool owner = (ksl < 2);              // non-duplicate C rows
    const bf16* gi = dir ? gib : gif;
    float cr[4], cz[4], cn[4], brr[4], bzz[4], bnn[4];
    #pragma unroll
    for (int e = 0; e < 4; ++e) {
        cr[e]  = bih[dir * 1536 + ue + e];
        cz[e]  = bih[dir * 1536 + 512 + ue + e];
        cn[e]  = bih[dir * 1536 + 1024 + ue + e];
        brr[e] = bhh[dir * 1536 + ue + e];
        bzz[e] = bhh[dir * 1536 + 512 + ue + e];
        bnn[e] = bhh[dir * 1536 + 1024 + ue + e];
    }
    const int sl = seq_lens[bcol];
    float hreg[4] = {0.f, 0.f, 0.f, 0.f};
    float owv[4] = {0.f, 0.f, 0.f, 0.f};       // deferred out values

    // init phase-0 h (hi & lo planes), one writer per (u,b)
    if (owner) {
        const long z0 = (long)((dir * 2 + 0) * 2 + 0) * 32768 + bcol * 512 + ue;
        const long z1 = (long)((dir * 2 + 0) * 2 + 1) * 32768 + bcol * 512 + ue;
        __hip_atomic_store((ull*)(hb + z0), 0ull, __ATOMIC_RELAXED, __HIP_MEMORY_SCOPE_AGENT);
        __hip_atomic_store((ull*)(hb + z1), 0ull, __ATOMIC_RELAXED, __HIP_MEMORY_SCOPE_AGENT);
    }
    dbar4(gc, root, 0);

    for (int t = 0; t < N_; ++t) {
        const int rp = t & 1, wp = rp ^ 1;
        const ull* hu0 = (const ull*)hb + (long)((dir * 2 + rp) * 2 + 0) * 8192 + bh * 4096;
        const ull* hu1 = (const ull*)hb + (long)((dir * 2 + rp) * 2 + 1) * 8192 + bh * 4096;

        // 1. issue ALL coalesced staging loads (adjacent tid -> adjacent ull)
        ull r0[32], r1[32];
        #pragma unroll
        for (int i = 0; i < 32; ++i)
            r0[i] = __hip_atomic_load(hu0 + i * 128 + tid,
                                      __ATOMIC_RELAXED, __HIP_MEMORY_SCOPE_AGENT);
        #pragma unroll
        for (int i = 0; i < 32; ++i)
            r1[i] = __hip_atomic_load(hu1 + i * 128 + tid,
                                      __ATOMIC_RELAXED, __HIP_MEMORY_SCOPE_AGENT);

        // 2. deferred out-writes of step t-1 (overlap with load latency)
        if (t > 0 && owner) {
            const int tp = t - 1;
            if (dir == 0) {
                #pragma unroll
                for (int e = 0; e < 4; ++e)
                    outf[(long)tp * 32768 + (ue + e) * 64 + bcol] = owv[e];
            } else if (tp < sl) {
                #pragma unroll
                for (int e = 0; e < 4; ++e)
                    outb[(long)(sl - 1 - tp) * 32768 + (ue + e) * 64 + bcol] = owv[e];
            }
        }

        // 3. gi for this step (only owner lanes consume it)
        float gv[3][4];
        if (owner) {
            #pragma unroll
            for (int g = 0; g < 3; ++g)
                #pragma unroll
                for (int e = 0; e < 4; ++e)
                    gv[g][e] = __bfloat162float(
                        gi[(long)t * 98304 + (g * 512 + ue + e) * 64 + bcol]);
        }

        // 4. stage h into LDS [plane][b_local][HP] (transpose by addressing)
        #pragma unroll
        for (int i = 0; i < 32; ++i) {
            const int q = i * 128 + tid;       // 0..4095
            const int bl_ = q >> 7, uo = q & 127;
            *(ull*)&hlds[bl_ * HP + uo * 4] = r0[i];
        }
        #pragma unroll
        for (int i = 0; i < 32; ++i) {
            const int q = i * 128 + tid;
            const int bl_ = q >> 7, uo = q & 127;
            *(ull*)&hlds[32 * HP + bl_ * HP + uo * 4] = r1[i];
        }
        __syncthreads();

        // 5. MFMA matvec: 3 gate-tiles x 16 k-chunks x 3 hi/lo combos
        const int brow = (w * 16 + ml) * HP;   // this lane's batch row in LDS
        f32x4 acc[3] = {};
        #pragma unroll
        for (int ks = 0; ks < 16; ++ks) {
            const int u0 = ks * 32 + ksl * 8;
            const s16x8 fh = *(const s16x8*)&hlds[brow + u0];
            const s16x8 fl = *(const s16x8*)&hlds[32 * HP + brow + u0];
            const int mr = ml & 7;             // mirror row
            const s16x8 a0h = *(const s16x8*)&wlds[(0 * 24 + 0 * 8 + mr) * WPAD + u0];
            const s16x8 a1h = *(const s16x8*)&wlds[(0 * 24 + 1 * 8 + mr) * WPAD + u0];
            const s16x8 a2h = *(const s16x8*)&wlds[(0 * 24 + 2 * 8 + mr) * WPAD + u0];
            const s16x8 a0l = *(const s16x8*)&wlds[(1 * 24 + 0 * 8 + mr) * WPAD + u0];
            const s16x8 a1l = *(const s16x8*)&wlds[(1 * 24 + 1 * 8 + mr) * WPAD + u0];
            const s16x8 a2l = *(const s16x8*)&wlds[(1 * 24 + 2 * 8 + mr) * WPAD + u0];
            acc[0] = __builtin_amdgcn_mfma_f32_16x16x32_bf16(a0h, fh, acc[0], 0, 0, 0);
            acc[1] = __builtin_amdgcn_mfma_f32_16x16x32_bf16(a1h, fh, acc[1], 0, 0, 0);
            acc[2] = __builtin_amdgcn_mfma_f32_16x16x32_bf16(a2h, fh, acc[2], 0, 0, 0);
            acc[0] = __builtin_amdgcn_mfma_f32_16x16x32_bf16(a0h, fl, acc[0], 0, 0, 0);
            acc[1] = __builtin_amdgcn_mfma_f32_16x16x32_bf16(a1h, fl, acc[1], 0, 0, 0);
            acc[2] = __builtin_amdgcn_mfma_f32_16x16x32_bf16(a2h, fl, acc[2], 0, 0, 0);
            acc[0] = __builtin_amdgcn_mfma_f32_16x16x32_bf16(a0l, fh, acc[0], 0, 0, 0);
            acc[1] = __builtin_amdgcn_mfma_f32_16x16x32_bf16(a1l, fh, acc[1], 0, 0, 0);
            acc[2] = __builtin_amdgcn_mfma_f32_16x16x32_bf16(a2l, fh, acc[2], 0, 0, 0);
        }

        // 6. gate nonlinearity + h update + h store (owner lanes only)
        if (owner) {
            ull phi = 0, plo = 0;
            const bool msk = t < sl;
            #pragma unroll
            for (int e = 0; e < 4; ++e) {
                const float rg = sigmoidf_(cr[e] + gv[0][e] + brr[e] + acc[0][e]);
                const float zg = sigmoidf_(cz[e] + gv[1][e] + bzz[e] + acc[1][e]);
                const float ng = tanhf(cn[e] + gv[2][e] + rg * (bnn[e] + acc[2][e]));
                const float hnew = (1.f - zg) * ng + zg * hreg[e];
                owv[e] = (dir == 0) ? (msk ? hnew : 0.f) : hnew;
                hreg[e] = msk ? hnew : hreg[e];
                const bf16 h_hi = __float2bfloat16(hreg[e]);
                const bf16 h_lo = __float2bfloat16(hreg[e] - __bfloat162float(h_hi));
                phi |= (ull)(*(const unsigned short*)&h_hi) << (16 * e);
                plo |= (ull)(*(const unsigned short*)&h_lo) << (16 * e);
            }
            const long wbh = (long)((dir * 2 + wp) * 2 + 0) * 32768 + bcol * 512 + ue;
            const long wbl = (long)((dir * 2 + wp) * 2 + 1) * 32768 + bcol * 512 + ue;
            __hip_atomic_store((ull*)(hb + wbh), phi, __ATOMIC_RELAXED, __HIP_MEMORY_SCOPE_AGENT);
            __hip_atomic_store((ull*)(hb + wbl), plo, __ATOMIC_RELAXED, __HIP_MEMORY_SCOPE_AGENT);
        }

        dbar4(gc, root, t + 1);
    }

    // final deferred out-write (t = N_-1) + final hidden state
    if (owner) {
        const int tp = N_ - 1;
        if (dir == 0) {
            #pragma unroll
            for (int e = 0; e < 4; ++e)
                outf[(long)tp * 32768 + (ue + e) * 64 + bcol] = owv[e];
        } else if (tp < sl) {
            #pragma unroll
            for (int e = 0; e < 4; ++e)
                outb[(long)(sl - 1 - tp) * 32768 + (ue + e) * 64 + bcol] = owv[e];
        }
        #pragma unroll
        for (int e = 0; e < 4; ++e)
            hfin[dir * 32768 + (ue + e) * 64 + bcol] = hreg[e];
    }
}

// --------------------------------------------------------------- finalize

__global__ void final_k(const float* __restrict__ outf, const float* __restrict__ outb,
                        const float* __restrict__ hfin, const int* __restrict__ seq_lens,
                        float* __restrict__ dout)
{
    const long i = (long)blockIdx.x * 256 + threadIdx.x;
    const long NOUT = (long)N_ * B_ * 512;
    if (i < NOUT) {
        const int t = (int)(i >> 15);
        const int b = (int)((i >> 9) & 63);
        const int u = (int)(i & 511);
        const long src = (long)t * 32768 + u * 64 + b;
        dout[i] = (t < seq_lens[b]) ? outf[src] + outb[src] : 0.f;
    } else if (i < NOUT + 2 * B_ * 512) {
        const long j = i - NOUT;
        const int dir = (int)(j >> 15);
        const int b = (int)((j >> 9) & 63);
        const int u = (int)(j & 511);
        dout[i] = hfin[dir * 32768 + u * 64 + b];
    }
}

__global__ void fail_zero_k(float* __restrict__ dout, long n)
{
    for (long i = (long)blockIdx.x * 256 + threadIdx.x; i < n; i += (long)gridDim.x * 256)
        dout[i] = 0.f;
}

// ----------------------------------------------------------------- launch

extern "C" void kernel_launch(void* const* d_in, const int* in_sizes, int n_in,
                              void* d_out, int out_size, void* d_ws, size_t ws_size,
                              hipStream_t stream)
{
    const int*   tokens   = (const int*)d_in[0];
    const int*   tok_lens = (const int*)d_in[1];
    const int*   seq_lens = (const int*)d_in[2];
    const float* adj      = (const float*)d_in[3];
    const float* emb      = (const float*)d_in[4];
    const float* Wq       = (const float*)d_in[5];
    const float* Wk       = (const float*)d_in[6];
    const float* Wq_o     = (const float*)d_in[7];
    const float* Wk_o     = (const float*)d_in[8];
    const float* gWih     = (const float*)d_in[9];
    const float* gWhh     = (const float*)d_in[10];
    const float* gbih     = (const float*)d_in[11];
    const float* gbhh     = (const float*)d_in[12];
    float* out = (float*)d_out;

    const long SZ = (long)B_ * N_ * 512;   // 9,830,400 elements
    float* F1 = (float*)d_ws;              // q1   -> outf
    float* F2 = F1 + SZ;                   // k1   -> outb
    float* F3 = F2 + SZ;                   // hp1  -> hp2
    bf16* b0 = (bf16*)(F3 + SZ);           // embx -> out2
    bf16* b1 = b0 + SZ;                    // x1   -> x_rev
    bf16* b2 = b1 + SZ;                    // q2   -> wih(bf16)
    bf16* b3 = b2 + SZ;                    // k2
    float* sc   = (float*)(b3 + SZ);
    float* mx   = sc + (long)B_ * SCSZ;
    float* smv  = mx + SCSZ;
    unsigned char* cond = (unsigned char*)(smv + SCSZ);
    bf16* gif = (bf16*)(cond + (long)B_ * N_ * N_);
    bf16* gib = gif + (long)N_ * 1536 * B_;
    float* hbuf = (float*)(gib + (long)N_ * 1536 * B_);   // 512 KB bf16 hi/lo x 2ph x 2dir
    unsigned* bar = (unsigned*)(hbuf + 131072);
    float* hfin = (float*)(bar + 2048);                   // 2 x 512 x 64 fp32 final h
    const size_t needed = (size_t)((char*)(hfin + 2 * 512 * 64) - (char*)d_ws);
    if (ws_size < needed) {
        fail_zero_k<<<4096, 256, 0, stream>>>(out, out_size);
        return;
    }
    bf16* wq1  = (bf16*)sc;
    bf16* wk1  = wq1 + 512 * 512;
    bf16* w2q  = (bf16*)sc;
    bf16* w2k  = w2q + 512 * 512;
    bf16* wihb = b2;

    // 1. layer-1 weight prep, embedding (bf16), cond
    wgath_k<<<512, 512, 0, stream>>>(Wq, wq1);
    wgath_k<<<512, 512, 0, stream>>>(Wk, wk1);
    embed_k<<<dim3(N_, B_), 128, 0, stream>>>(tokens, tok_lens, seq_lens, emb, b0);
    cond_k<<<dim3(5, 5, B_), 256, 0, stream>>>(adj, cond);

    // 2. layer-1 projections via MFMA (fp32 out): q1 -> F1, k1 -> F2
    mgemm_k<128, 128, false><<<dim3(150, 4, 1), 256, 0, stream>>>(
        b0, 0, 512, wq1, 0, 512, F1, 0, 512, B_ * N_, 512, 512);
    mgemm_k<128, 128, false><<<dim3(150, 4, 1), 256, 0, stream>>>(
        b0, 0, 512, wk1, 0, 512, F2, 0, 512, B_ * N_, 512, 512);

    // 3. per-head attention (fp32 SIMT: K=64)
    for (int h = 0; h < NHEADS_; ++h) {
        gemm_k<true, false><<<dim3(5, 5, B_), 256, 0, stream>>>(
            F1 + h * 64, (long)N_ * 512, 512,
            F2 + h * 64, (long)N_ * 512, 512,
            sc, SCSZ, SCLD, N_, N_, 64);
        bsoft_k<<<(SCSZ + 255) / 256, 256, 0, stream>>>(sc, mx, smv);
        colsoft_k<<<dim3(5, B_), 512, 0, stream>>>(sc, mx, smv, cond);
        gemm_k<false, false><<<dim3(5, 1, B_), 256, 0, stream>>>(
            sc, SCSZ, SCLD,
            F2 + h * 64, (long)N_ * 512, 512,
            F3 + h * 64, (long)N_ * 512, 512, N_, 64, N_);
    }
    nsoft_k<<<dim3(2, B_), 256, 0, stream>>>(F3, b1);               // x1 (bf16)

    // 4. layer-2 via MFMA: q2/k2 (bf16 out), scores2
    wtr_k<<<512, 512, 0, stream>>>(Wq_o, w2q);
    wtr_k<<<512, 512, 0, stream>>>(Wk_o, w2k);
    mgemm_k<128, 128, true><<<dim3(150, 4, 1), 256, 0, stream>>>(
        b1, 0, 512, w2q, 0, 512, b2, 0, 512, B_ * N_, 512, 512);
    mgemm_k<128, 128, true><<<dim3(150, 4, 1), 256, 0, stream>>>(
        b1, 0, 512, w2k, 0, 512, b3, 0, 512, B_ * N_, 512, 512);
    mgemm_k<64, 64, false><<<dim3(5, 5, B_), 256, 0, stream>>>(
        b2, (long)N_ * 512, 512, b3, (long)N_ * 512, 512,
        sc, SCSZ, SCLD, N_, N_, 512);
    f2b_k<<<6144, 256, 0, stream>>>(gWih, wihb, (long)2 * 1536 * 512);
    bsoft_k<<<(SCSZ + 255) / 256, 256, 0, stream>>>(sc, mx, smv);
    colsoft_k<<<dim3(5, B_), 512, 0, stream>>>(sc, mx, smv, cond);
    gemm_k<false, false, true><<<dim3(5, 8, B_), 256, 0, stream>>>(
        sc, SCSZ, SCLD, (const float*)(const void*)b3, (long)N_ * 512, 512,
        F3, (long)N_ * 512, 512, N_, 512, N_);
    nsoft_k<<<dim3(2, B_), 256, 0, stream>>>(F3, b0);                // out2 (bf16)

    // 5. GRU input GEMMs via MFMA (bf16 out, layout (t, j, b))
    xrev_k<<<dim3(N_, B_), 128, 0, stream>>>(b0, seq_lens, b1);
    zero_k<<<1, 256, 0, stream>>>((float*)bar, 2048);
    mgemm_k<64, 64, true><<<dim3(24, 1, N_), 256, 0, stream>>>(
        wihb, 0, 512, b0, 512, (long)N_ * 512, gif, 1536 * 64, 64, 1536, 64, 512);
    mgemm_k<64, 64, true><<<dim3(24, 1, N_), 256, 0, stream>>>(
        wihb + 1536 * 512, 0, 512, b1, (long)B_ * 512, 512, gib, 1536 * 64, 64, 1536, 64, 512);

    // 6. recurrence (256 blocks, coalesced LDS-staged exchange) + finalize
    gru_recur4<<<256, 128, 0, stream>>>(gif, gib, gWhh, gbih, gbhh, seq_lens,
                                        hbuf, bar, F1, F2, hfin);
    final_k<<<38656, 256, 0, stream>>>(F1, F2, hfin, seq_lens, out);
}

// Round 9
// 3848.673 us; speedup vs baseline: 1.5674x; 1.1159x over previous
//
#include <hip/hip_runtime.h>
#include <hip/hip_bf16.h>

typedef __hip_bfloat16 bf16;
typedef unsigned long long ull;
typedef __attribute__((ext_vector_type(8))) short s16x8;
typedef __attribute__((ext_vector_type(4))) float f32x4;

#define B_      64
#define NMAX_   299
#define N_      300
#define D_      512
#define H_      512
#define NHEADS_ 8
#define NHID_   64
#define SCLD    304                  // padded leading dim for (n,m) score rows
#define SCSZ    (N_ * SCLD)          // 91,200 floats per batch
#define LDP     48                   // padded LDS row stride (bf16 elems) for mgemm
#define WPAD    536                  // Whh LDS k-stride (shorts)
#define HP      520                  // h LDS row stride (shorts)
#define AK      320                  // padded K (=m) for att/kT MFMA operands

// ---------------------------------------------------------------- utilities

__device__ __forceinline__ float sigmoidf_(float x) { return 1.0f / (1.0f + expf(-x)); }

// ---------------------------------------------------------------- embedding

__global__ void embed_k(const int* __restrict__ tokens, const int* __restrict__ tok_lens,
                        const int* __restrict__ seq_lens, const float* __restrict__ emb,
                        bf16* __restrict__ out)
{
    const int n = blockIdx.x, b = blockIdx.y;
    const int d = threadIdx.x * 4;
    const int nc = seq_lens[b] - 1;
    float4 v;
    if (n < nc) {
        const int tl = tok_lens[b * NMAX_ + n];
        const int* tp = tokens + (b * NMAX_ + n) * 8;
        float4 acc = {0.f, 0.f, 0.f, 0.f};
        for (int t = 0; t < 8; ++t) {
            if (t < tl) {
                const float4 e = *(const float4*)(emb + (long)tp[t] * D_ + d);
                acc.x += e.x; acc.y += e.y; acc.z += e.z; acc.w += e.w;
            }
        }
        const float inv = 1.0f / (float)nc;
        v.x = acc.x * inv; v.y = acc.y * inv; v.z = acc.z * inv; v.w = acc.w * inv;
    } else {
        const int row = (n == nc) ? 2 : 0;
        v = *(const float4*)(emb + row * D_ + d);
    }
    bf16 o[4] = {__float2bfloat16(v.x), __float2bfloat16(v.y),
                 __float2bfloat16(v.z), __float2bfloat16(v.w)};
    *(uint2*)(out + ((long)b * N_ + n) * D_ + d) = *(uint2*)o;
}

// ------------------------------------------------------------------- cond

__global__ void cond_k(const float* __restrict__ adj, unsigned char* __restrict__ cond)
{
    __shared__ float T1[64][65];
    __shared__ float T2[64][65];
    const int b = blockIdx.z;
    const int n0 = blockIdx.x * 64, m0 = blockIdx.y * 64;
    const int jj = threadIdx.x & 63, i0 = threadIdx.x >> 6;
    for (int r = 0; r < 16; ++r) {
        const int i = i0 * 16 + r;
        const int n = n0 + i, m = m0 + jj;
        T1[i][jj] = (n < N_ && m < N_) ? adj[((long)b * N_ + n) * N_ + m] : 0.f;
        const int n2 = m0 + i, m2 = n0 + jj;
        T2[i][jj] = (n2 < N_ && m2 < N_) ? adj[((long)b * N_ + n2) * N_ + m2] : 0.f;
    }
    __syncthreads();
    for (int r = 0; r < 16; ++r) {
        const int i = i0 * 16 + r;
        const int n = n0 + i, m = m0 + jj;
        if (n < N_ && m < N_) {
            const float v = T1[i][jj] + T2[jj][i] + ((n == m) ? 1.f : 0.f);
            cond[((long)b * N_ + n) * N_ + m] = (v > 0.f) ? 1 : 0;
        }
    }
}

// -------------------------------------------------- weight prep (fp32->bf16)

__global__ void wgath_k(const float* __restrict__ W, bf16* __restrict__ out)
{   // (8,512,64) -> (512,512): out[h*64+o][d] = W[h][d][o]
    const int row = blockIdx.x;
    const int d = threadIdx.x;
    const int h = row >> 6, o = row & 63;
    out[row * 512 + d] = __float2bfloat16(W[((long)h * 512 + d) * 64 + o]);
}

__global__ void wtr_k(const float* __restrict__ W, bf16* __restrict__ out)
{   // (512,512) -> transposed: out[o][i] = W[i][o]
    const int o = blockIdx.x;
    const int i = threadIdx.x;
    out[o * 512 + i] = __float2bfloat16(W[(long)i * 512 + o]);
}

__global__ void f2b_k(const float* __restrict__ in, bf16* __restrict__ out, long n)
{
    for (long i = (long)blockIdx.x * 256 + threadIdx.x; i < n; i += (long)gridDim.x * 256)
        out[i] = __float2bfloat16(in[i]);
}

// ---------------------------------------------- bf16 tile transpose (+pad)
// in: [b][300][512] -> out: [b][512][AK], out[f][m] = in[m][f]; m>=300 -> 0

__global__ void tbf_k(const bf16* __restrict__ in, bf16* __restrict__ out)
{
    __shared__ short T[64][65];
    const int b = blockIdx.z;
    const int m0 = blockIdx.x * 64, f0 = blockIdx.y * 64;
    const int jj = threadIdx.x & 63, i0 = threadIdx.x >> 6;
    for (int r = 0; r < 16; ++r) {
        const int i = i0 * 16 + r;
        const int m = m0 + i, f = f0 + jj;
        short v = 0;
        if (m < N_) v = *(const short*)&in[((long)b * N_ + m) * 512 + f];
        T[i][jj] = v;
    }
    __syncthreads();
    for (int r = 0; r < 16; ++r) {
        const int i = i0 * 16 + r;
        const int f = f0 + i, m = m0 + jj;
        ((short*)out)[((long)b * 512 + f) * AK + m] = T[jj][i];
    }
}

// ------------------------------------------------------- bf16 MFMA GEMM
// C[m][n] = sum_k A[m][k] * B[n][k]   (B transposed, row-major [N][K]).

template<int BM, int BN, bool OBF>
__global__ __launch_bounds__(256) void mgemm_k(
    const bf16* __restrict__ A, long sA, int lda,
    const bf16* __restrict__ Bm, long sB, int ldb,
    void* __restrict__ C, long sC, int ldc,
    int M, int N, int K)
{
    __shared__ short As[BM * LDP];
    __shared__ short Bs[BN * LDP];
    const int z = blockIdx.z;
    const bf16* Ab = A + (long)z * sA;
    const bf16* Bb = Bm + (long)z * sB;
    const int m0 = blockIdx.x * BM, n0 = blockIdx.y * BN;
    const int tid = threadIdx.x;
    const int lane = tid & 63;
    const int w = tid >> 6;
    const int wm = (w >> 1) * (BM / 2);
    const int wn = (w & 1) * (BN / 2);
    constexpr int MR = BM / 32;
    constexpr int NR = BN / 32;
    f32x4 acc[MR][NR] = {};

    const int srow = tid >> 2;
    const int sslot = (tid & 3) * 8;

    for (int k0 = 0; k0 < K; k0 += 32) {
        #pragma unroll
        for (int r = 0; r < BM / 64; ++r) {
            const int row = r * 64 + srow;
            uint4 v = {0u, 0u, 0u, 0u};
            if (m0 + row < M)
                v = *(const uint4*)(Ab + (long)(m0 + row) * lda + k0 + sslot);
            *(uint4*)&As[row * LDP + sslot] = v;
        }
        #pragma unroll
        for (int r = 0; r < BN / 64; ++r) {
            const int row = r * 64 + srow;
            uint4 v = {0u, 0u, 0u, 0u};
            if (n0 + row < N)
                v = *(const uint4*)(Bb + (long)(n0 + row) * ldb + k0 + sslot);
            *(uint4*)&Bs[row * LDP + sslot] = v;
        }
        __syncthreads();
        s16x8 aq[MR], bq[NR];
        #pragma unroll
        for (int i = 0; i < MR; ++i)
            aq[i] = *(const s16x8*)&As[(wm + i * 16 + (lane & 15)) * LDP + (lane >> 4) * 8];
        #pragma unroll
        for (int j = 0; j < NR; ++j)
            bq[j] = *(const s16x8*)&Bs[(wn + j * 16 + (lane & 15)) * LDP + (lane >> 4) * 8];
        #pragma unroll
        for (int i = 0; i < MR; ++i)
            #pragma unroll
            for (int j = 0; j < NR; ++j)
                acc[i][j] = __builtin_amdgcn_mfma_f32_16x16x32_bf16(aq[i], bq[j], acc[i][j], 0, 0, 0);
        __syncthreads();
    }

    #pragma unroll
    for (int i = 0; i < MR; ++i) {
        const int mrow = m0 + wm + i * 16 + (lane >> 4) * 4;
        #pragma unroll
        for (int j = 0; j < NR; ++j) {
            const int ncol = n0 + wn + j * 16 + (lane & 15);
            if (ncol < N) {
                #pragma unroll
                for (int e = 0; e < 4; ++e) {
                    const int mm = mrow + e;
                    if (mm < M) {
                        const long idx = (long)z * sC + (long)mm * ldc + ncol;
                        if (OBF) ((bf16*)C)[idx] = __float2bfloat16(acc[i][j][e]);
                        else     ((float*)C)[idx] = acc[i][j][e];
                    }
                }
            }
        }
    }
}

// ------------------------------------------------- softmaxes for GAT layer

__global__ void bsoft_k(const float* __restrict__ sc, float* __restrict__ mx, float* __restrict__ sm)
{
    const int idx = blockIdx.x * 256 + threadIdx.x;
    if (idx >= SCSZ) return;
    float m = -1e30f;
    for (int b = 0; b < B_; ++b) m = fmaxf(m, sc[(long)b * SCSZ + idx]);
    float s = 0.f;
    for (int b = 0; b < B_; ++b) s += expf(sc[(long)b * SCSZ + idx] - m);
    mx[idx] = m; sm[idx] = s;
}

// column softmax; final pass emits bf16 att probs [b][n][AK] (pad m zeroed)
__global__ __launch_bounds__(512) void colsoft_k(
    float* __restrict__ sc, const float* __restrict__ mx,
    const float* __restrict__ sm, const unsigned char* __restrict__ cond,
    bf16* __restrict__ abf)
{
    __shared__ float red[8][64];
    const int ml = threadIdx.x & 63;
    const int ng = threadIdx.x >> 6;
    const int m = blockIdx.x * 64 + ml;        // 0..319
    const int b = blockIdx.y;
    float* scb = sc + (long)b * SCSZ;
    const unsigned char* cb = cond + (long)b * (N_ * N_);
    const bool act = m < N_;

    float vmax = -1e30f;
    for (int n = ng; n < N_; n += 8) {
        const int o = n * SCLD + m;
        if (act && cb[n * N_ + m]) {
            const float e = expf(scb[o] - mx[o]) / sm[o];
            scb[o] = e;
            vmax = fmaxf(vmax, e);
        }
    }
    red[ng][ml] = vmax;
    __syncthreads();
    vmax = red[0][ml];
    #pragma unroll
    for (int i = 1; i < 8; ++i) vmax = fmaxf(vmax, red[i][ml]);

    float ssum = 0.f;
    for (int n = ng; n < N_; n += 8) {
        const int o = n * SCLD + m;
        if (act && cb[n * N_ + m]) ssum += expf(scb[o] - vmax);
    }
    __syncthreads();
    red[ng][ml] = ssum;
    __syncthreads();
    ssum = 0.f;
    #pragma unroll
    for (int i = 0; i < 8; ++i) ssum += red[i][ml];
    const float inv = 1.0f / ssum;

    for (int n = ng; n < N_; n += 8) {
        const int o = n * SCLD + m;
        const float v = (act && cb[n * N_ + m]) ? expf(scb[o] - vmax) * inv : 0.f;
        abf[(long)b * (N_ * AK) + n * AK + m] = __float2bfloat16(v);
    }
}

__global__ void nsoft_k(const float* __restrict__ hp, bf16* __restrict__ out)
{
    const int f = blockIdx.x * 256 + threadIdx.x;
    const int b = blockIdx.y;
    const float* hb = hp + (long)b * (N_ * 512) + f;
    float vmax = -1e30f;
    for (int n = 0; n < N_; ++n) vmax = fmaxf(vmax, hb[n * 512]);
    float s = 0.f;
    for (int n = 0; n < N_; ++n) s += expf(hb[n * 512] - vmax);
    const float inv = 1.0f / s;
    bf16* ob = out + (long)b * (N_ * 512) + f;
    for (int n = 0; n < N_; ++n) ob[n * 512] = __float2bfloat16(expf(hb[n * 512] - vmax) * inv);
}

// ----------------------------------------------------------------- GRU prep

__global__ void xrev_k(const bf16* __restrict__ out2, const int* __restrict__ seq_lens,
                       bf16* __restrict__ xr)
{
    const int t = blockIdx.x, b = blockIdx.y;
    const int d = threadIdx.x * 4;
    int src = seq_lens[b] - 1 - t;
    if (src < 0) src = 0;
    *(uint2*)(xr + ((long)t * B_ + b) * 512 + d) =
        *(const uint2*)(out2 + ((long)b * N_ + src) * 512 + d);
}

__global__ void zero_k(float* __restrict__ p, long n)
{
    for (long i = (long)blockIdx.x * 256 + threadIdx.x; i < n; i += (long)gridDim.x * 256)
        p[i] = 0.f;
}

// ------------------------------------------------------ GRU recurrence (v4)
// (unchanged — 2.02 ms, exchange/barrier latency-bound)

__device__ __forceinline__ void dbar4(unsigned* __restrict__ gc, unsigned* __restrict__ root,
                                      int step) {
    __syncthreads();
    if (threadIdx.x == 0) {
        const unsigned old =
            __hip_atomic_fetch_add(gc, 1u, __ATOMIC_RELAXED, __HIP_MEMORY_SCOPE_AGENT);
        if (old == (unsigned)(step * 8 + 7))
            __hip_atomic_fetch_add(root, 1u, __ATOMIC_RELAXED, __HIP_MEMORY_SCOPE_AGENT);
        while (__hip_atomic_load(root, __ATOMIC_RELAXED, __HIP_MEMORY_SCOPE_AGENT)
               < (unsigned)((step + 1) * 8)) {
            __builtin_amdgcn_s_sleep(1);
        }
    }
    __syncthreads();
}

__global__ __launch_bounds__(128, 1) void gru_recur4(
    const bf16* __restrict__ gif, const bf16* __restrict__ gib,
    const float* __restrict__ Whh, const float* __restrict__ bih,
    const float* __restrict__ bhh, const int* __restrict__ seq_lens,
    float* __restrict__ hbuf_f, unsigned* __restrict__ bar,
    float* __restrict__ outf, float* __restrict__ outb,
    float* __restrict__ hfin)
{
    __shared__ short wlds[2 * 3 * 8 * WPAD];
    __shared__ short hlds[2 * 32 * HP];
    const int tid = threadIdx.x;
    const int lane = tid & 63;
    const int w = tid >> 6;
    const int ml = lane & 15;
    const int ksl = lane >> 4;
    const int dir = blockIdx.x >> 7;
    const int bl  = blockIdx.x & 127;
    const int ub  = (bl >> 1) * 8;
    const int bh  = bl & 1;
    const int g4  = dir * 2 + bh;
    unsigned* gc   = bar + (g4 * 8 + ((bl >> 1) >> 3)) * 32;
    unsigned* root = bar + 1024 + g4 * 32;
    bf16* hb = (bf16*)hbuf_f;

    {
        const float* Wb = Whh + (long)dir * (1536 * 512);
        for (int idx = tid; idx < 3 * 8 * 512; idx += 128) {
            const int row = idx >> 9;
            const int k = idx & 511;
            const int g = row >> 3, ul = row & 7;
            const float v = Wb[(long)(g * 512 + ub + ul) * 512 + k];
            const bf16 hi = __float2bfloat16(v);
            const bf16 lo = __float2bfloat16(v - __bfloat162float(hi));
            wlds[(0 * 24 + g * 8 + ul) * WPAD + k] = *(const short*)&hi;
            wlds[(1 * 24 + g * 8 + ul) * WPAD + k] = *(const short*)&lo;
        }
    }

    const int bcol = bh * 32 + w * 16 + ml;
    const int ue   = ub + (ksl & 1) * 4;
    const bool owner = (ksl < 2);
    const bf16* gi = dir ? gib : gif;
    float cr[4], cz[4], cn[4], brr[4], bzz[4], bnn[4];
    #pragma unroll
    for (int e = 0; e < 4; ++e) {
        cr[e]  = bih[dir * 1536 + ue + e];
        cz[e]  = bih[dir * 1536 + 512 + ue + e];
        cn[e]  = bih[dir * 1536 + 1024 + ue + e];
        brr[e] = bhh[dir * 1536 + ue + e];
        bzz[e] = bhh[dir * 1536 + 512 + ue + e];
        bnn[e] = bhh[dir * 1536 + 1024 + ue + e];
    }
    const int sl = seq_lens[bcol];
    float hreg[4] = {0.f, 0.f, 0.f, 0.f};
    float owv[4] = {0.f, 0.f, 0.f, 0.f};

    if (owner) {
        const long z0 = (long)((dir * 2 + 0) * 2 + 0) * 32768 + bcol * 512 + ue;
        const long z1 = (long)((dir * 2 + 0) * 2 + 1) * 32768 + bcol * 512 + ue;
        __hip_atomic_store((ull*)(hb + z0), 0ull, __ATOMIC_RELAXED, __HIP_MEMORY_SCOPE_AGENT);
        __hip_atomic_store((ull*)(hb + z1), 0ull, __ATOMIC_RELAXED, __HIP_MEMORY_SCOPE_AGENT);
    }
    dbar4(gc, root, 0);

    for (int t = 0; t < N_; ++t) {
        const int rp = t & 1, wp = rp ^ 1;
        const ull* hu0 = (const ull*)hb + (long)((dir * 2 + rp) * 2 + 0) * 8192 + bh * 4096;
        const ull* hu1 = (const ull*)hb + (long)((dir * 2 + rp) * 2 + 1) * 8192 + bh * 4096;

        ull r0[32], r1[32];
        #pragma unroll
        for (int i = 0; i < 32; ++i)
            r0[i] = __hip_atomic_load(hu0 + i * 128 + tid,
                                      __ATOMIC_RELAXED, __HIP_MEMORY_SCOPE_AGENT);
        #pragma unroll
        for (int i = 0; i < 32; ++i)
            r1[i] = __hip_atomic_load(hu1 + i * 128 + tid,
                                      __ATOMIC_RELAXED, __HIP_MEMORY_SCOPE_AGENT);

        if (t > 0 && owner) {
            const int tp = t - 1;
            if (dir == 0) {
                #pragma unroll
                for (int e = 0; e < 4; ++e)
                    outf[(long)tp * 32768 + (ue + e) * 64 + bcol] = owv[e];
            } else if (tp < sl) {
                #pragma unroll
                for (int e = 0; e < 4; ++e)
                    outb[(long)(sl - 1 - tp) * 32768 + (ue + e) * 64 + bcol] = owv[e];
            }
        }

        float gv[3][4];
        if (owner) {
            #pragma unroll
            for (int g = 0; g < 3; ++g)
                #pragma unroll
                for (int e = 0; e < 4; ++e)
                    gv[g][e] = __bfloat162float(
                        gi[(long)t * 98304 + (g * 512 + ue + e) * 64 + bcol]);
        }

        #pragma unroll
        for (int i = 0; i < 32; ++i) {
            const int q = i * 128 + tid;
            const int bl_ = q >> 7, uo = q & 127;
            *(ull*)&hlds[bl_ * HP + uo * 4] = r0[i];
        }
        #pragma unroll
        for (int i = 0; i < 32; ++i) {
            const int q = i * 128 + tid;
            const int bl_ = q >> 7, uo = q & 127;
            *(ull*)&hlds[32 * HP + bl_ * HP + uo * 4] = r1[i];
        }
        __syncthreads();

        const int brow = (w * 16 + ml) * HP;
        f32x4 acc[3] = {};
        #pragma unroll
        for (int ks = 0; ks < 16; ++ks) {
            const int u0 = ks * 32 + ksl * 8;
            const s16x8 fh = *(const s16x8*)&hlds[brow + u0];
            const s16x8 fl = *(const s16x8*)&hlds[32 * HP + brow + u0];
            const int mr = ml & 7;
            const s16x8 a0h = *(const s16x8*)&wlds[(0 * 24 + 0 * 8 + mr) * WPAD + u0];
            const s16x8 a1h = *(const s16x8*)&wlds[(0 * 24 + 1 * 8 + mr) * WPAD + u0];
            const s16x8 a2h = *(const s16x8*)&wlds[(0 * 24 + 2 * 8 + mr) * WPAD + u0];
            const s16x8 a0l = *(const s16x8*)&wlds[(1 * 24 + 0 * 8 + mr) * WPAD + u0];
            const s16x8 a1l = *(const s16x8*)&wlds[(1 * 24 + 1 * 8 + mr) * WPAD + u0];
            const s16x8 a2l = *(const s16x8*)&wlds[(1 * 24 + 2 * 8 + mr) * WPAD + u0];
            acc[0] = __builtin_amdgcn_mfma_f32_16x16x32_bf16(a0h, fh, acc[0], 0, 0, 0);
            acc[1] = __builtin_amdgcn_mfma_f32_16x16x32_bf16(a1h, fh, acc[1], 0, 0, 0);
            acc[2] = __builtin_amdgcn_mfma_f32_16x16x32_bf16(a2h, fh, acc[2], 0, 0, 0);
            acc[0] = __builtin_amdgcn_mfma_f32_16x16x32_bf16(a0h, fl, acc[0], 0, 0, 0);
            acc[1] = __builtin_amdgcn_mfma_f32_16x16x32_bf16(a1h, fl, acc[1], 0, 0, 0);
            acc[2] = __builtin_amdgcn_mfma_f32_16x16x32_bf16(a2h, fl, acc[2], 0, 0, 0);
            acc[0] = __builtin_amdgcn_mfma_f32_16x16x32_bf16(a0l, fh, acc[0], 0, 0, 0);
            acc[1] = __builtin_amdgcn_mfma_f32_16x16x32_bf16(a1l, fh, acc[1], 0, 0, 0);
            acc[2] = __builtin_amdgcn_mfma_f32_16x16x32_bf16(a2l, fh, acc[2], 0, 0, 0);
        }

        if (owner) {
            ull phi = 0, plo = 0;
            const bool msk = t < sl;
            #pragma unroll
            for (int e = 0; e < 4; ++e) {
                const float rg = sigmoidf_(cr[e] + gv[0][e] + brr[e] + acc[0][e]);
                const float zg = sigmoidf_(cz[e] + gv[1][e] + bzz[e] + acc[1][e]);
                const float ng = tanhf(cn[e] + gv[2][e] + rg * (bnn[e] + acc[2][e]));
                const float hnew = (1.f - zg) * ng + zg * hreg[e];
                owv[e] = (dir == 0) ? (msk ? hnew : 0.f) : hnew;
                hreg[e] = msk ? hnew : hreg[e];
                const bf16 h_hi = __float2bfloat16(hreg[e]);
                const bf16 h_lo = __float2bfloat16(hreg[e] - __bfloat162float(h_hi));
                phi |= (ull)(*(const unsigned short*)&h_hi) << (16 * e);
                plo |= (ull)(*(const unsigned short*)&h_lo) << (16 * e);
            }
            const long wbh = (long)((dir * 2 + wp) * 2 + 0) * 32768 + bcol * 512 + ue;
            const long wbl = (long)((dir * 2 + wp) * 2 + 1) * 32768 + bcol * 512 + ue;
            __hip_atomic_store((ull*)(hb + wbh), phi, __ATOMIC_RELAXED, __HIP_MEMORY_SCOPE_AGENT);
            __hip_atomic_store((ull*)(hb + wbl), plo, __ATOMIC_RELAXED, __HIP_MEMORY_SCOPE_AGENT);
        }

        dbar4(gc, root, t + 1);
    }

    if (owner) {
        const int tp = N_ - 1;
        if (dir == 0) {
            #pragma unroll
            for (int e = 0; e < 4; ++e)
                outf[(long)tp * 32768 + (ue + e) * 64 + bcol] = owv[e];
        } else if (tp < sl) {
            #pragma unroll
            for (int e = 0; e < 4; ++e)
                outb[(long)(sl - 1 - tp) * 32768 + (ue + e) * 64 + bcol] = owv[e];
        }
        #pragma unroll
        for (int e = 0; e < 4; ++e)
            hfin[dir * 32768 + (ue + e) * 64 + bcol] = hreg[e];
    }
}

// --------------------------------------------------------------- finalize

__global__ void final_k(const float* __restrict__ outf, const float* __restrict__ outb,
                        const float* __restrict__ hfin, const int* __restrict__ seq_lens,
                        float* __restrict__ dout)
{
    const long i = (long)blockIdx.x * 256 + threadIdx.x;
    const long NOUT = (long)N_ * B_ * 512;
    if (i < NOUT) {
        const int t = (int)(i >> 15);
        const int b = (int)((i >> 9) & 63);
        const int u = (int)(i & 511);
        const long src = (long)t * 32768 + u * 64 + b;
        dout[i] = (t < seq_lens[b]) ? outf[src] + outb[src] : 0.f;
    } else if (i < NOUT + 2 * B_ * 512) {
        const long j = i - NOUT;
        const int dir = (int)(j >> 15);
        const int b = (int)((j >> 9) & 63);
        const int u = (int)(j & 511);
        dout[i] = hfin[dir * 32768 + u * 64 + b];
    }
}

__global__ void fail_zero_k(float* __restrict__ dout, long n)
{
    for (long i = (long)blockIdx.x * 256 + threadIdx.x; i < n; i += (long)gridDim.x * 256)
        dout[i] = 0.f;
}

// ----------------------------------------------------------------- launch

extern "C" void kernel_launch(void* const* d_in, const int* in_sizes, int n_in,
                              void* d_out, int out_size, void* d_ws, size_t ws_size,
                              hipStream_t stream)
{
    const int*   tokens   = (const int*)d_in[0];
    const int*   tok_lens = (const int*)d_in[1];
    const int*   seq_lens = (const int*)d_in[2];
    const float* adj      = (const float*)d_in[3];
    const float* emb      = (const float*)d_in[4];
    const float* Wq       = (const float*)d_in[5];
    const float* Wk       = (const float*)d_in[6];
    const float* Wq_o     = (const float*)d_in[7];
    const float* Wk_o     = (const float*)d_in[8];
    const float* gWih     = (const float*)d_in[9];
    const float* gWhh     = (const float*)d_in[10];
    const float* gbih     = (const float*)d_in[11];
    const float* gbhh     = (const float*)d_in[12];
    float* out = (float*)d_out;

    const long SZ = (long)B_ * N_ * 512;   // 9,830,400 elements
    float* F1 = (float*)d_ws;              // kT scratch -> outf
    float* F2 = F1 + SZ;                   // att_bf     -> outb
    float* F3 = F2 + SZ;                   // hp1 / hp2 (fp32)
    bf16* b0 = (bf16*)(F3 + SZ);           // embx -> out2
    bf16* b1 = b0 + SZ;                    // x1   -> x_rev
    bf16* b2 = b1 + SZ;                    // q1b  -> q2 -> wih(bf16)
    bf16* b3 = b2 + SZ;                    // k1b  -> k2
    float* sc   = (float*)(b3 + SZ);
    float* mx   = sc + (long)B_ * SCSZ;
    float* smv  = mx + SCSZ;
    unsigned char* cond = (unsigned char*)(smv + SCSZ);
    bf16* gif = (bf16*)(cond + (long)B_ * N_ * N_);
    bf16* gib = gif + (long)N_ * 1536 * B_;
    float* hbuf = (float*)(gib + (long)N_ * 1536 * B_);
    unsigned* bar = (unsigned*)(hbuf + 131072);
    float* hfin = (float*)(bar + 2048);
    const size_t needed = (size_t)((char*)(hfin + 2 * 512 * 64) - (char*)d_ws);
    if (ws_size < needed) {
        fail_zero_k<<<4096, 256, 0, stream>>>(out, out_size);
        return;
    }
    bf16* wq1  = (bf16*)sc;                // dead-region transients
    bf16* wk1  = wq1 + 512 * 512;
    bf16* w2q  = (bf16*)sc;
    bf16* w2k  = w2q + 512 * 512;
    bf16* wihb = b2;
    bf16* kT   = (bf16*)F1;                // [b][512][AK] transposed keys
    bf16* abf  = (bf16*)F2;                // [b][N][AK] bf16 att probs

    // 1. layer-1 weight prep, embedding (bf16), cond
    wgath_k<<<512, 512, 0, stream>>>(Wq, wq1);
    wgath_k<<<512, 512, 0, stream>>>(Wk, wk1);
    embed_k<<<dim3(N_, B_), 128, 0, stream>>>(tokens, tok_lens, seq_lens, emb, b0);
    cond_k<<<dim3(5, 5, B_), 256, 0, stream>>>(adj, cond);

    // 2. layer-1 projections via MFMA (bf16 out): q1 -> b2, k1 -> b3; k1^T
    mgemm_k<128, 128, true><<<dim3(150, 4, 1), 256, 0, stream>>>(
        b0, 0, 512, wq1, 0, 512, b2, 0, 512, B_ * N_, 512, 512);
    mgemm_k<128, 128, true><<<dim3(150, 4, 1), 256, 0, stream>>>(
        b0, 0, 512, wk1, 0, 512, b3, 0, 512, B_ * N_, 512, 512);
    tbf_k<<<dim3(5, 8, B_), 256, 0, stream>>>(b3, kT);

    // 3. per-head attention (all MFMA)
    for (int h = 0; h < NHEADS_; ++h) {
        mgemm_k<64, 64, false><<<dim3(5, 5, B_), 256, 0, stream>>>(    // scores1
            b2 + h * 64, (long)N_ * 512, 512,
            b3 + h * 64, (long)N_ * 512, 512,
            sc, SCSZ, SCLD, N_, N_, 64);
        bsoft_k<<<(SCSZ + 255) / 256, 256, 0, stream>>>(sc, mx, smv);
        colsoft_k<<<dim3(5, B_), 512, 0, stream>>>(sc, mx, smv, cond, abf);
        mgemm_k<64, 64, false><<<dim3(5, 1, B_), 256, 0, stream>>>(    // hp1
            abf, (long)N_ * AK, AK,
            kT + (long)h * 64 * AK, (long)512 * AK, AK,
            F3 + h * 64, (long)N_ * 512, 512, N_, 64, AK);
    }
    nsoft_k<<<dim3(2, B_), 256, 0, stream>>>(F3, b1);                  // x1 (bf16)

    // 4. layer-2 via MFMA: q2/k2 (bf16), k2^T, scores2, hp2
    wtr_k<<<512, 512, 0, stream>>>(Wq_o, w2q);
    wtr_k<<<512, 512, 0, stream>>>(Wk_o, w2k);
    mgemm_k<128, 128, true><<<dim3(150, 4, 1), 256, 0, stream>>>(
        b1, 0, 512, w2q, 0, 512, b2, 0, 512, B_ * N_, 512, 512);
    mgemm_k<128, 128, true><<<dim3(150, 4, 1), 256, 0, stream>>>(
        b1, 0, 512, w2k, 0, 512, b3, 0, 512, B_ * N_, 512, 512);
    tbf_k<<<dim3(5, 8, B_), 256, 0, stream>>>(b3, kT);
    mgemm_k<64, 64, false><<<dim3(5, 5, B_), 256, 0, stream>>>(        // scores2
        b2, (long)N_ * 512, 512, b3, (long)N_ * 512, 512,
        sc, SCSZ, SCLD, N_, N_, 512);
    f2b_k<<<6144, 256, 0, stream>>>(gWih, wihb, (long)2 * 1536 * 512); // q2 dead
    bsoft_k<<<(SCSZ + 255) / 256, 256, 0, stream>>>(sc, mx, smv);
    colsoft_k<<<dim3(5, B_), 512, 0, stream>>>(sc, mx, smv, cond, abf);
    mgemm_k<64, 64, false><<<dim3(5, 8, B_), 256, 0, stream>>>(        // hp2
        abf, (long)N_ * AK, AK,
        kT, (long)512 * AK, AK,
        F3, (long)N_ * 512, 512, N_, 512, AK);
    nsoft_k<<<dim3(2, B_), 256, 0, stream>>>(F3, b0);                  // out2 (bf16)

    // 5. GRU input GEMMs via MFMA (bf16 out, layout (t, j, b))
    xrev_k<<<dim3(N_, B_), 128, 0, stream>>>(b0, seq_lens, b1);
    zero_k<<<1, 256, 0, stream>>>((float*)bar, 2048);
    mgemm_k<64, 64, true><<<dim3(24, 1, N_), 256, 0, stream>>>(
        wihb, 0, 512, b0, 512, (long)N_ * 512, gif, 1536 * 64, 64, 1536, 64, 512);
    mgemm_k<64, 64, true><<<dim3(24, 1, N_), 256, 0, stream>>>(
        wihb + 1536 * 512, 0, 512, b1, (long)B_ * 512, 512, gib, 1536 * 64, 64, 1536, 64, 512);

    // 6. recurrence (unchanged) + finalize
    gru_recur4<<<256, 128, 0, stream>>>(gif, gib, gWhh, gbih, gbhh, seq_lens,
                                        hbuf, bar, F1, F2, hfin);
    final_k<<<38656, 256, 0, stream>>>(F1, F2, hfin, seq_lens, out);
}

// Round 10
// 3349.403 us; speedup vs baseline: 1.8010x; 1.1491x over previous
//
#include <hip/hip_runtime.h>
#include <hip/hip_bf16.h>

typedef __hip_bfloat16 bf16;
typedef unsigned long long ull;
typedef __attribute__((ext_vector_type(8))) short s16x8;
typedef __attribute__((ext_vector_type(4))) float f32x4;

#define B_      64
#define NMAX_   299
#define N_      300
#define D_      512
#define H_      512
#define NHEADS_ 8
#define NHID_   64
#define SCLD    304                  // padded leading dim for (n,m) score rows
#define SCSZ    (N_ * SCLD)          // 91,200 floats per batch
#define LDP     48                   // padded LDS row stride (bf16 elems) for mgemm
#define WPAD    536                  // Whh LDS k-stride (shorts)
#define HP      520                  // h LDS row stride (shorts)
#define AK      320                  // padded K (=m) for att/kT MFMA operands

// ---------------------------------------------------------------- utilities

__device__ __forceinline__ float sigmoidf_(float x) { return 1.0f / (1.0f + expf(-x)); }

// ---------------------------------------------------------------- embedding

__global__ void embed_k(const int* __restrict__ tokens, const int* __restrict__ tok_lens,
                        const int* __restrict__ seq_lens, const float* __restrict__ emb,
                        bf16* __restrict__ out)
{
    const int n = blockIdx.x, b = blockIdx.y;
    const int d = threadIdx.x * 4;
    const int nc = seq_lens[b] - 1;
    float4 v;
    if (n < nc) {
        const int tl = tok_lens[b * NMAX_ + n];
        const int* tp = tokens + (b * NMAX_ + n) * 8;
        float4 acc = {0.f, 0.f, 0.f, 0.f};
        for (int t = 0; t < 8; ++t) {
            if (t < tl) {
                const float4 e = *(const float4*)(emb + (long)tp[t] * D_ + d);
                acc.x += e.x; acc.y += e.y; acc.z += e.z; acc.w += e.w;
            }
        }
        const float inv = 1.0f / (float)nc;
        v.x = acc.x * inv; v.y = acc.y * inv; v.z = acc.z * inv; v.w = acc.w * inv;
    } else {
        const int row = (n == nc) ? 2 : 0;
        v = *(const float4*)(emb + row * D_ + d);
    }
    bf16 o[4] = {__float2bfloat16(v.x), __float2bfloat16(v.y),
                 __float2bfloat16(v.z), __float2bfloat16(v.w)};
    *(uint2*)(out + ((long)b * N_ + n) * D_ + d) = *(uint2*)o;
}

// ------------------------------------------------------------------- cond

__global__ void cond_k(const float* __restrict__ adj, unsigned char* __restrict__ cond)
{
    __shared__ float T1[64][65];
    __shared__ float T2[64][65];
    const int b = blockIdx.z;
    const int n0 = blockIdx.x * 64, m0 = blockIdx.y * 64;
    const int jj = threadIdx.x & 63, i0 = threadIdx.x >> 6;
    for (int r = 0; r < 16; ++r) {
        const int i = i0 * 16 + r;
        const int n = n0 + i, m = m0 + jj;
        T1[i][jj] = (n < N_ && m < N_) ? adj[((long)b * N_ + n) * N_ + m] : 0.f;
        const int n2 = m0 + i, m2 = n0 + jj;
        T2[i][jj] = (n2 < N_ && m2 < N_) ? adj[((long)b * N_ + n2) * N_ + m2] : 0.f;
    }
    __syncthreads();
    for (int r = 0; r < 16; ++r) {
        const int i = i0 * 16 + r;
        const int n = n0 + i, m = m0 + jj;
        if (n < N_ && m < N_) {
            const float v = T1[i][jj] + T2[jj][i] + ((n == m) ? 1.f : 0.f);
            cond[((long)b * N_ + n) * N_ + m] = (v > 0.f) ? 1 : 0;
        }
    }
}

// -------------------------------------------------- weight prep (fp32->bf16)

__global__ void wgath_k(const float* __restrict__ W, bf16* __restrict__ out)
{   // (8,512,64) -> (512,512): out[h*64+o][d] = W[h][d][o]
    const int row = blockIdx.x;
    const int d = threadIdx.x;
    const int h = row >> 6, o = row & 63;
    out[row * 512 + d] = __float2bfloat16(W[((long)h * 512 + d) * 64 + o]);
}

__global__ void wtr_k(const float* __restrict__ W, bf16* __restrict__ out)
{   // (512,512) -> transposed: out[o][i] = W[i][o]
    const int o = blockIdx.x;
    const int i = threadIdx.x;
    out[o * 512 + i] = __float2bfloat16(W[(long)i * 512 + o]);
}

__global__ void f2b_k(const float* __restrict__ in, bf16* __restrict__ out, long n)
{
    for (long i = (long)blockIdx.x * 256 + threadIdx.x; i < n; i += (long)gridDim.x * 256)
        out[i] = __float2bfloat16(in[i]);
}

// ---------------------------------------------- bf16 tile transpose (+pad)
// in: [b][300][512] -> out: [b][512][AK], out[f][m] = in[m][f]; m>=300 -> 0

__global__ void tbf_k(const bf16* __restrict__ in, bf16* __restrict__ out)
{
    __shared__ short T[64][65];
    const int b = blockIdx.z;
    const int m0 = blockIdx.x * 64, f0 = blockIdx.y * 64;
    const int jj = threadIdx.x & 63, i0 = threadIdx.x >> 6;
    for (int r = 0; r < 16; ++r) {
        const int i = i0 * 16 + r;
        const int m = m0 + i, f = f0 + jj;
        short v = 0;
        if (m < N_) v = *(const short*)&in[((long)b * N_ + m) * 512 + f];
        T[i][jj] = v;
    }
    __syncthreads();
    for (int r = 0; r < 16; ++r) {
        const int i = i0 * 16 + r;
        const int f = f0 + i, m = m0 + jj;
        ((short*)out)[((long)b * 512 + f) * AK + m] = T[jj][i];
    }
}

// ------------------------------------------------------- bf16 MFMA GEMM
// C[m][n] = sum_k A[m][k] * B[n][k]   (B transposed, row-major [N][K]).

template<int BM, int BN, bool OBF>
__global__ __launch_bounds__(256) void mgemm_k(
    const bf16* __restrict__ A, long sA, int lda,
    const bf16* __restrict__ Bm, long sB, int ldb,
    void* __restrict__ C, long sC, int ldc,
    int M, int N, int K)
{
    __shared__ short As[BM * LDP];
    __shared__ short Bs[BN * LDP];
    const int z = blockIdx.z;
    const bf16* Ab = A + (long)z * sA;
    const bf16* Bb = Bm + (long)z * sB;
    const int m0 = blockIdx.x * BM, n0 = blockIdx.y * BN;
    const int tid = threadIdx.x;
    const int lane = tid & 63;
    const int w = tid >> 6;
    const int wm = (w >> 1) * (BM / 2);
    const int wn = (w & 1) * (BN / 2);
    constexpr int MR = BM / 32;
    constexpr int NR = BN / 32;
    f32x4 acc[MR][NR] = {};

    const int srow = tid >> 2;
    const int sslot = (tid & 3) * 8;

    for (int k0 = 0; k0 < K; k0 += 32) {
        #pragma unroll
        for (int r = 0; r < BM / 64; ++r) {
            const int row = r * 64 + srow;
            uint4 v = {0u, 0u, 0u, 0u};
            if (m0 + row < M)
                v = *(const uint4*)(Ab + (long)(m0 + row) * lda + k0 + sslot);
            *(uint4*)&As[row * LDP + sslot] = v;
        }
        #pragma unroll
        for (int r = 0; r < BN / 64; ++r) {
            const int row = r * 64 + srow;
            uint4 v = {0u, 0u, 0u, 0u};
            if (n0 + row < N)
                v = *(const uint4*)(Bb + (long)(n0 + row) * ldb + k0 + sslot);
            *(uint4*)&Bs[row * LDP + sslot] = v;
        }
        __syncthreads();
        s16x8 aq[MR], bq[NR];
        #pragma unroll
        for (int i = 0; i < MR; ++i)
            aq[i] = *(const s16x8*)&As[(wm + i * 16 + (lane & 15)) * LDP + (lane >> 4) * 8];
        #pragma unroll
        for (int j = 0; j < NR; ++j)
            bq[j] = *(const s16x8*)&Bs[(wn + j * 16 + (lane & 15)) * LDP + (lane >> 4) * 8];
        #pragma unroll
        for (int i = 0; i < MR; ++i)
            #pragma unroll
            for (int j = 0; j < NR; ++j)
                acc[i][j] = __builtin_amdgcn_mfma_f32_16x16x32_bf16(aq[i], bq[j], acc[i][j], 0, 0, 0);
        __syncthreads();
    }

    #pragma unroll
    for (int i = 0; i < MR; ++i) {
        const int mrow = m0 + wm + i * 16 + (lane >> 4) * 4;
        #pragma unroll
        for (int j = 0; j < NR; ++j) {
            const int ncol = n0 + wn + j * 16 + (lane & 15);
            if (ncol < N) {
                #pragma unroll
                for (int e = 0; e < 4; ++e) {
                    const int mm = mrow + e;
                    if (mm < M) {
                        const long idx = (long)z * sC + (long)mm * ldc + ncol;
                        if (OBF) ((bf16*)C)[idx] = __float2bfloat16(acc[i][j][e]);
                        else     ((float*)C)[idx] = acc[i][j][e];
                    }
                }
            }
        }
    }
}

// ------------------------------------------------- softmaxes for GAT layer
// bsoft v2: LDS-tiled single global pass. Block = 64 consecutive idx x all
// 64 batches; coalesced loads into [64][65] tile; max+sum computed from LDS.

__global__ __launch_bounds__(256) void bsoft_k(
    const float* __restrict__ sc, float* __restrict__ mx, float* __restrict__ sm)
{
    __shared__ float T[64][65];
    __shared__ float P[4][64];
    __shared__ float Mv[64];
    const int idx0 = blockIdx.x * 64;
    const int il = threadIdx.x & 63;
    const int bq = threadIdx.x >> 6;       // 0..3

    #pragma unroll
    for (int r = 0; r < 16; ++r) {
        const int b = bq * 16 + r;
        T[b][il] = sc[(long)b * SCSZ + idx0 + il];
    }
    __syncthreads();

    // max over b (4 partials of 16, then combine)
    float pm = -1e30f;
    #pragma unroll
    for (int r = 0; r < 16; ++r) pm = fmaxf(pm, T[bq * 16 + r][il]);
    P[bq][il] = pm;
    __syncthreads();
    if (bq == 0) {
        float m = fmaxf(fmaxf(P[0][il], P[1][il]), fmaxf(P[2][il], P[3][il]));
        Mv[il] = m;
        mx[idx0 + il] = m;
    }
    __syncthreads();

    // sum of exp over b
    const float m = Mv[il];
    float ps = 0.f;
    #pragma unroll
    for (int r = 0; r < 16; ++r) ps += expf(T[bq * 16 + r][il] - m);
    __syncthreads();
    P[bq][il] = ps;
    __syncthreads();
    if (bq == 0)
        sm[idx0 + il] = P[0][il] + P[1][il] + P[2][il] + P[3][il];
}

// colsoft v2: register-resident e-values (<=38 per thread), one sc read
// pass + one abf write pass; cond read once into a bitmask. sc untouched.
#define NSTR 38   // ceil(300/8)

__global__ __launch_bounds__(512) void colsoft_k(
    const float* __restrict__ sc, const float* __restrict__ mx,
    const float* __restrict__ sm, const unsigned char* __restrict__ cond,
    bf16* __restrict__ abf)
{
    __shared__ float red[8][64];
    const int ml = threadIdx.x & 63;
    const int ng = threadIdx.x >> 6;           // 0..7
    const int m = blockIdx.x * 64 + ml;        // 0..319
    const int b = blockIdx.y;
    const float* scb = sc + (long)b * SCSZ;
    const unsigned char* cb = cond + (long)b * (N_ * N_);
    const bool act = m < N_;

    float ev[NSTR];
    ull cmask = 0;
    float vmax = -1e30f;
    #pragma unroll
    for (int i = 0; i < NSTR; ++i) {
        const int n = ng + i * 8;
        float e = 0.f;
        if (n < N_ && act && cb[n * N_ + m]) {
            const int o = n * SCLD + m;
            e = expf(scb[o] - mx[o]) / sm[o];
            cmask |= 1ull << i;
            vmax = fmaxf(vmax, e);
        }
        ev[i] = e;
    }
    red[ng][ml] = vmax;
    __syncthreads();
    vmax = red[0][ml];
    #pragma unroll
    for (int i = 1; i < 8; ++i) vmax = fmaxf(vmax, red[i][ml]);

    float ssum = 0.f;
    #pragma unroll
    for (int i = 0; i < NSTR; ++i)
        if ((cmask >> i) & 1) ssum += expf(ev[i] - vmax);
    __syncthreads();
    red[ng][ml] = ssum;
    __syncthreads();
    ssum = 0.f;
    #pragma unroll
    for (int i = 0; i < 8; ++i) ssum += red[i][ml];
    const float inv = 1.0f / ssum;

    #pragma unroll
    for (int i = 0; i < NSTR; ++i) {
        const int n = ng + i * 8;
        if (n < N_) {
            const float v = ((cmask >> i) & 1) ? expf(ev[i] - vmax) * inv : 0.f;
            abf[(long)b * (N_ * AK) + n * AK + m] = __float2bfloat16(v);
        }
    }
}

__global__ void nsoft_k(const float* __restrict__ hp, bf16* __restrict__ out)
{
    const int f = blockIdx.x * 256 + threadIdx.x;
    const int b = blockIdx.y;
    const float* hb = hp + (long)b * (N_ * 512) + f;
    float vmax = -1e30f;
    for (int n = 0; n < N_; ++n) vmax = fmaxf(vmax, hb[n * 512]);
    float s = 0.f;
    for (int n = 0; n < N_; ++n) s += expf(hb[n * 512] - vmax);
    const float inv = 1.0f / s;
    bf16* ob = out + (long)b * (N_ * 512) + f;
    for (int n = 0; n < N_; ++n) ob[n * 512] = __float2bfloat16(expf(hb[n * 512] - vmax) * inv);
}

// ----------------------------------------------------------------- GRU prep

__global__ void xrev_k(const bf16* __restrict__ out2, const int* __restrict__ seq_lens,
                       bf16* __restrict__ xr)
{
    const int t = blockIdx.x, b = blockIdx.y;
    const int d = threadIdx.x * 4;
    int src = seq_lens[b] - 1 - t;
    if (src < 0) src = 0;
    *(uint2*)(xr + ((long)t * B_ + b) * 512 + d) =
        *(const uint2*)(out2 + ((long)b * N_ + src) * 512 + d);
}

__global__ void zero_k(float* __restrict__ p, long n)
{
    for (long i = (long)blockIdx.x * 256 + threadIdx.x; i < n; i += (long)gridDim.x * 256)
        p[i] = 0.f;
}

// ------------------------------------------------------ GRU recurrence (v4)
// (unchanged — 1.99 ms, exchange/barrier latency-bound)

__device__ __forceinline__ void dbar4(unsigned* __restrict__ gc, unsigned* __restrict__ root,
                                      int step) {
    __syncthreads();
    if (threadIdx.x == 0) {
        const unsigned old =
            __hip_atomic_fetch_add(gc, 1u, __ATOMIC_RELAXED, __HIP_MEMORY_SCOPE_AGENT);
        if (old == (unsigned)(step * 8 + 7))
            __hip_atomic_fetch_add(root, 1u, __ATOMIC_RELAXED, __HIP_MEMORY_SCOPE_AGENT);
        while (__hip_atomic_load(root, __ATOMIC_RELAXED, __HIP_MEMORY_SCOPE_AGENT)
               < (unsigned)((step + 1) * 8)) {
            __builtin_amdgcn_s_sleep(1);
        }
    }
    __syncthreads();
}

__global__ __launch_bounds__(128, 1) void gru_recur4(
    const bf16* __restrict__ gif, const bf16* __restrict__ gib,
    const float* __restrict__ Whh, const float* __restrict__ bih,
    const float* __restrict__ bhh, const int* __restrict__ seq_lens,
    float* __restrict__ hbuf_f, unsigned* __restrict__ bar,
    float* __restrict__ outf, float* __restrict__ outb,
    float* __restrict__ hfin)
{
    __shared__ short wlds[2 * 3 * 8 * WPAD];
    __shared__ short hlds[2 * 32 * HP];
    const int tid = threadIdx.x;
    const int lane = tid & 63;
    const int w = tid >> 6;
    const int ml = lane & 15;
    const int ksl = lane >> 4;
    const int dir = blockIdx.x >> 7;
    const int bl  = blockIdx.x & 127;
    const int ub  = (bl >> 1) * 8;
    const int bh  = bl & 1;
    const int g4  = dir * 2 + bh;
    unsigned* gc   = bar + (g4 * 8 + ((bl >> 1) >> 3)) * 32;
    unsigned* root = bar + 1024 + g4 * 32;
    bf16* hb = (bf16*)hbuf_f;

    {
        const float* Wb = Whh + (long)dir * (1536 * 512);
        for (int idx = tid; idx < 3 * 8 * 512; idx += 128) {
            const int row = idx >> 9;
            const int k = idx & 511;
            const int g = row >> 3, ul = row & 7;
            const float v = Wb[(long)(g * 512 + ub + ul) * 512 + k];
            const bf16 hi = __float2bfloat16(v);
            const bf16 lo = __float2bfloat16(v - __bfloat162float(hi));
            wlds[(0 * 24 + g * 8 + ul) * WPAD + k] = *(const short*)&hi;
            wlds[(1 * 24 + g * 8 + ul) * WPAD + k] = *(const short*)&lo;
        }
    }

    const int bcol = bh * 32 + w * 16 + ml;
    const int ue   = ub + (ksl & 1) * 4;
    const bool owner = (ksl < 2);
    const bf16* gi = dir ? gib : gif;
    float cr[4], cz[4], cn[4], brr[4], bzz[4], bnn[4];
    #pragma unroll
    for (int e = 0; e < 4; ++e) {
        cr[e]  = bih[dir * 1536 + ue + e];
        cz[e]  = bih[dir * 1536 + 512 + ue + e];
        cn[e]  = bih[dir * 1536 + 1024 + ue + e];
        brr[e] = bhh[dir * 1536 + ue + e];
        bzz[e] = bhh[dir * 1536 + 512 + ue + e];
        bnn[e] = bhh[dir * 1536 + 1024 + ue + e];
    }
    const int sl = seq_lens[bcol];
    float hreg[4] = {0.f, 0.f, 0.f, 0.f};
    float owv[4] = {0.f, 0.f, 0.f, 0.f};

    if (owner) {
        const long z0 = (long)((dir * 2 + 0) * 2 + 0) * 32768 + bcol * 512 + ue;
        const long z1 = (long)((dir * 2 + 0) * 2 + 1) * 32768 + bcol * 512 + ue;
        __hip_atomic_store((ull*)(hb + z0), 0ull, __ATOMIC_RELAXED, __HIP_MEMORY_SCOPE_AGENT);
        __hip_atomic_store((ull*)(hb + z1), 0ull, __ATOMIC_RELAXED, __HIP_MEMORY_SCOPE_AGENT);
    }
    dbar4(gc, root, 0);

    for (int t = 0; t < N_; ++t) {
        const int rp = t & 1, wp = rp ^ 1;
        const ull* hu0 = (const ull*)hb + (long)((dir * 2 + rp) * 2 + 0) * 8192 + bh * 4096;
        const ull* hu1 = (const ull*)hb + (long)((dir * 2 + rp) * 2 + 1) * 8192 + bh * 4096;

        ull r0[32], r1[32];
        #pragma unroll
        for (int i = 0; i < 32; ++i)
            r0[i] = __hip_atomic_load(hu0 + i * 128 + tid,
                                      __ATOMIC_RELAXED, __HIP_MEMORY_SCOPE_AGENT);
        #pragma unroll
        for (int i = 0; i < 32; ++i)
            r1[i] = __hip_atomic_load(hu1 + i * 128 + tid,
                                      __ATOMIC_RELAXED, __HIP_MEMORY_SCOPE_AGENT);

        if (t > 0 && owner) {
            const int tp = t - 1;
            if (dir == 0) {
                #pragma unroll
                for (int e = 0; e < 4; ++e)
                    outf[(long)tp * 32768 + (ue + e) * 64 + bcol] = owv[e];
            } else if (tp < sl) {
                #pragma unroll
                for (int e = 0; e < 4; ++e)
                    outb[(long)(sl - 1 - tp) * 32768 + (ue + e) * 64 + bcol] = owv[e];
            }
        }

        float gv[3][4];
        if (owner) {
            #pragma unroll
            for (int g = 0; g < 3; ++g)
                #pragma unroll
                for (int e = 0; e < 4; ++e)
                    gv[g][e] = __bfloat162float(
                        gi[(long)t * 98304 + (g * 512 + ue + e) * 64 + bcol]);
        }

        #pragma unroll
        for (int i = 0; i < 32; ++i) {
            const int q = i * 128 + tid;
            const int bl_ = q >> 7, uo = q & 127;
            *(ull*)&hlds[bl_ * HP + uo * 4] = r0[i];
        }
        #pragma unroll
        for (int i = 0; i < 32; ++i) {
            const int q = i * 128 + tid;
            const int bl_ = q >> 7, uo = q & 127;
            *(ull*)&hlds[32 * HP + bl_ * HP + uo * 4] = r1[i];
        }
        __syncthreads();

        const int brow = (w * 16 + ml) * HP;
        f32x4 acc[3] = {};
        #pragma unroll
        for (int ks = 0; ks < 16; ++ks) {
            const int u0 = ks * 32 + ksl * 8;
            const s16x8 fh = *(const s16x8*)&hlds[brow + u0];
            const s16x8 fl = *(const s16x8*)&hlds[32 * HP + brow + u0];
            const int mr = ml & 7;
            const s16x8 a0h = *(const s16x8*)&wlds[(0 * 24 + 0 * 8 + mr) * WPAD + u0];
            const s16x8 a1h = *(const s16x8*)&wlds[(0 * 24 + 1 * 8 + mr) * WPAD + u0];
            const s16x8 a2h = *(const s16x8*)&wlds[(0 * 24 + 2 * 8 + mr) * WPAD + u0];
            const s16x8 a0l = *(const s16x8*)&wlds[(1 * 24 + 0 * 8 + mr) * WPAD + u0];
            const s16x8 a1l = *(const s16x8*)&wlds[(1 * 24 + 1 * 8 + mr) * WPAD + u0];
            const s16x8 a2l = *(const s16x8*)&wlds[(1 * 24 + 2 * 8 + mr) * WPAD + u0];
            acc[0] = __builtin_amdgcn_mfma_f32_16x16x32_bf16(a0h, fh, acc[0], 0, 0, 0);
            acc[1] = __builtin_amdgcn_mfma_f32_16x16x32_bf16(a1h, fh, acc[1], 0, 0, 0);
            acc[2] = __builtin_amdgcn_mfma_f32_16x16x32_bf16(a2h, fh, acc[2], 0, 0, 0);
            acc[0] = __builtin_amdgcn_mfma_f32_16x16x32_bf16(a0h, fl, acc[0], 0, 0, 0);
            acc[1] = __builtin_amdgcn_mfma_f32_16x16x32_bf16(a1h, fl, acc[1], 0, 0, 0);
            acc[2] = __builtin_amdgcn_mfma_f32_16x16x32_bf16(a2h, fl, acc[2], 0, 0, 0);
            acc[0] = __builtin_amdgcn_mfma_f32_16x16x32_bf16(a0l, fh, acc[0], 0, 0, 0);
            acc[1] = __builtin_amdgcn_mfma_f32_16x16x32_bf16(a1l, fh, acc[1], 0, 0, 0);
            acc[2] = __builtin_amdgcn_mfma_f32_16x16x32_bf16(a2l, fh, acc[2], 0, 0, 0);
        }

        if (owner) {
            ull phi = 0, plo = 0;
            const bool msk = t < sl;
            #pragma unroll
            for (int e = 0; e < 4; ++e) {
                const float rg = sigmoidf_(cr[e] + gv[0][e] + brr[e] + acc[0][e]);
                const float zg = sigmoidf_(cz[e] + gv[1][e] + bzz[e] + acc[1][e]);
                const float ng = tanhf(cn[e] + gv[2][e] + rg * (bnn[e] + acc[2][e]));
                const float hnew = (1.f - zg) * ng + zg * hreg[e];
                owv[e] = (dir == 0) ? (msk ? hnew : 0.f) : hnew;
                hreg[e] = msk ? hnew : hreg[e];
                const bf16 h_hi = __float2bfloat16(hreg[e]);
                const bf16 h_lo = __float2bfloat16(hreg[e] - __bfloat162float(h_hi));
                phi |= (ull)(*(const unsigned short*)&h_hi) << (16 * e);
                plo |= (ull)(*(const unsigned short*)&h_lo) << (16 * e);
            }
            const long wbh = (long)((dir * 2 + wp) * 2 + 0) * 32768 + bcol * 512 + ue;
            const long wbl = (long)((dir * 2 + wp) * 2 + 1) * 32768 + bcol * 512 + ue;
            __hip_atomic_store((ull*)(hb + wbh), phi, __ATOMIC_RELAXED, __HIP_MEMORY_SCOPE_AGENT);
            __hip_atomic_store((ull*)(hb + wbl), plo, __ATOMIC_RELAXED, __HIP_MEMORY_SCOPE_AGENT);
        }

        dbar4(gc, root, t + 1);
    }

    if (owner) {
        const int tp = N_ - 1;
        if (dir == 0) {
            #pragma unroll
            for (int e = 0; e < 4; ++e)
                outf[(long)tp * 32768 + (ue + e) * 64 + bcol] = owv[e];
        } else if (tp < sl) {
            #pragma unroll
            for (int e = 0; e < 4; ++e)
                outb[(long)(sl - 1 - tp) * 32768 + (ue + e) * 64 + bcol] = owv[e];
        }
        #pragma unroll
        for (int e = 0; e < 4; ++e)
            hfin[dir * 32768 + (ue + e) * 64 + bcol] = hreg[e];
    }
}

// --------------------------------------------------------------- finalize

__global__ void final_k(const float* __restrict__ outf, const float* __restrict__ outb,
                        const float* __restrict__ hfin, const int* __restrict__ seq_lens,
                        float* __restrict__ dout)
{
    const long i = (long)blockIdx.x * 256 + threadIdx.x;
    const long NOUT = (long)N_ * B_ * 512;
    if (i < NOUT) {
        const int t = (int)(i >> 15);
        const int b = (int)((i >> 9) & 63);
        const int u = (int)(i & 511);
        const long src = (long)t * 32768 + u * 64 + b;
        dout[i] = (t < seq_lens[b]) ? outf[src] + outb[src] : 0.f;
    } else if (i < NOUT + 2 * B_ * 512) {
        const long j = i - NOUT;
        const int dir = (int)(j >> 15);
        const int b = (int)((j >> 9) & 63);
        const int u = (int)(j & 511);
        dout[i] = hfin[dir * 32768 + u * 64 + b];
    }
}

__global__ void fail_zero_k(float* __restrict__ dout, long n)
{
    for (long i = (long)blockIdx.x * 256 + threadIdx.x; i < n; i += (long)gridDim.x * 256)
        dout[i] = 0.f;
}

// ----------------------------------------------------------------- launch

extern "C" void kernel_launch(void* const* d_in, const int* in_sizes, int n_in,
                              void* d_out, int out_size, void* d_ws, size_t ws_size,
                              hipStream_t stream)
{
    const int*   tokens   = (const int*)d_in[0];
    const int*   tok_lens = (const int*)d_in[1];
    const int*   seq_lens = (const int*)d_in[2];
    const float* adj      = (const float*)d_in[3];
    const float* emb      = (const float*)d_in[4];
    const float* Wq       = (const float*)d_in[5];
    const float* Wk       = (const float*)d_in[6];
    const float* Wq_o     = (const float*)d_in[7];
    const float* Wk_o     = (const float*)d_in[8];
    const float* gWih     = (const float*)d_in[9];
    const float* gWhh     = (const float*)d_in[10];
    const float* gbih     = (const float*)d_in[11];
    const float* gbhh     = (const float*)d_in[12];
    float* out = (float*)d_out;

    const long SZ = (long)B_ * N_ * 512;   // 9,830,400 elements
    float* F1 = (float*)d_ws;              // kT scratch -> outf
    float* F2 = F1 + SZ;                   // att_bf     -> outb
    float* F3 = F2 + SZ;                   // hp1 / hp2 (fp32)
    bf16* b0 = (bf16*)(F3 + SZ);           // embx -> out2
    bf16* b1 = b0 + SZ;                    // x1   -> x_rev
    bf16* b2 = b1 + SZ;                    // q1b  -> q2 -> wih(bf16)
    bf16* b3 = b2 + SZ;                    // k1b  -> k2
    float* sc   = (float*)(b3 + SZ);
    float* mx   = sc + (long)B_ * SCSZ;
    float* smv  = mx + SCSZ;
    unsigned char* cond = (unsigned char*)(smv + SCSZ);
    bf16* gif = (bf16*)(cond + (long)B_ * N_ * N_);
    bf16* gib = gif + (long)N_ * 1536 * B_;
    float* hbuf = (float*)(gib + (long)N_ * 1536 * B_);
    unsigned* bar = (unsigned*)(hbuf + 131072);
    float* hfin = (float*)(bar + 2048);
    const size_t needed = (size_t)((char*)(hfin + 2 * 512 * 64) - (char*)d_ws);
    if (ws_size < needed) {
        fail_zero_k<<<4096, 256, 0, stream>>>(out, out_size);
        return;
    }
    bf16* wq1  = (bf16*)sc;                // dead-region transients
    bf16* wk1  = wq1 + 512 * 512;
    bf16* w2q  = (bf16*)sc;
    bf16* w2k  = w2q + 512 * 512;
    bf16* wihb = b2;
    bf16* kT   = (bf16*)F1;                // [b][512][AK] transposed keys
    bf16* abf  = (bf16*)F2;                // [b][N][AK] bf16 att probs

    // 1. layer-1 weight prep, embedding (bf16), cond
    wgath_k<<<512, 512, 0, stream>>>(Wq, wq1);
    wgath_k<<<512, 512, 0, stream>>>(Wk, wk1);
    embed_k<<<dim3(N_, B_), 128, 0, stream>>>(tokens, tok_lens, seq_lens, emb, b0);
    cond_k<<<dim3(5, 5, B_), 256, 0, stream>>>(adj, cond);

    // 2. layer-1 projections via MFMA (bf16 out): q1 -> b2, k1 -> b3; k1^T
    mgemm_k<128, 128, true><<<dim3(150, 4, 1), 256, 0, stream>>>(
        b0, 0, 512, wq1, 0, 512, b2, 0, 512, B_ * N_, 512, 512);
    mgemm_k<128, 128, true><<<dim3(150, 4, 1), 256, 0, stream>>>(
        b0, 0, 512, wk1, 0, 512, b3, 0, 512, B_ * N_, 512, 512);
    tbf_k<<<dim3(5, 8, B_), 256, 0, stream>>>(b3, kT);

    // 3. per-head attention (all MFMA)
    for (int h = 0; h < NHEADS_; ++h) {
        mgemm_k<64, 64, false><<<dim3(5, 5, B_), 256, 0, stream>>>(    // scores1
            b2 + h * 64, (long)N_ * 512, 512,
            b3 + h * 64, (long)N_ * 512, 512,
            sc, SCSZ, SCLD, N_, N_, 64);
        bsoft_k<<<SCSZ / 64, 256, 0, stream>>>(sc, mx, smv);
        colsoft_k<<<dim3(5, B_), 512, 0, stream>>>(sc, mx, smv, cond, abf);
        mgemm_k<64, 64, false><<<dim3(5, 1, B_), 256, 0, stream>>>(    // hp1
            abf, (long)N_ * AK, AK,
            kT + (long)h * 64 * AK, (long)512 * AK, AK,
            F3 + h * 64, (long)N_ * 512, 512, N_, 64, AK);
    }
    nsoft_k<<<dim3(2, B_), 256, 0, stream>>>(F3, b1);                  // x1 (bf16)

    // 4. layer-2 via MFMA: q2/k2 (bf16), k2^T, scores2, hp2
    wtr_k<<<512, 512, 0, stream>>>(Wq_o, w2q);
    wtr_k<<<512, 512, 0, stream>>>(Wk_o, w2k);
    mgemm_k<128, 128, true><<<dim3(150, 4, 1), 256, 0, stream>>>(
        b1, 0, 512, w2q, 0, 512, b2, 0, 512, B_ * N_, 512, 512);
    mgemm_k<128, 128, true><<<dim3(150, 4, 1), 256, 0, stream>>>(
        b1, 0, 512, w2k, 0, 512, b3, 0, 512, B_ * N_, 512, 512);
    tbf_k<<<dim3(5, 8, B_), 256, 0, stream>>>(b3, kT);
    mgemm_k<64, 64, false><<<dim3(5, 5, B_), 256, 0, stream>>>(        // scores2
        b2, (long)N_ * 512, 512, b3, (long)N_ * 512, 512,
        sc, SCSZ, SCLD, N_, N_, 512);
    f2b_k<<<6144, 256, 0, stream>>>(gWih, wihb, (long)2 * 1536 * 512); // q2 dead
    bsoft_k<<<SCSZ / 64, 256, 0, stream>>>(sc, mx, smv);
    colsoft_k<<<dim3(5, B_), 512, 0, stream>>>(sc, mx, smv, cond, abf);
    mgemm_k<64, 64, false><<<dim3(5, 8, B_), 256, 0, stream>>>(        // hp2
        abf, (long)N_ * AK, AK,
        kT, (long)512 * AK, AK,
        F3, (long)N_ * 512, 512, N_, 512, AK);
    nsoft_k<<<dim3(2, B_), 256, 0, stream>>>(F3, b0);                  // out2 (bf16)

    // 5. GRU input GEMMs via MFMA (bf16 out, layout (t, j, b))
    xrev_k<<<dim3(N_, B_), 128, 0, stream>>>(b0, seq_lens, b1);
    zero_k<<<1, 256, 0, stream>>>((float*)bar, 2048);
    mgemm_k<64, 64, true><<<dim3(24, 1, N_), 256, 0, stream>>>(
        wihb, 0, 512, b0, 512, (long)N_ * 512, gif, 1536 * 64, 64, 1536, 64, 512);
    mgemm_k<64, 64, true><<<dim3(24, 1, N_), 256, 0, stream>>>(
        wihb + 1536 * 512, 0, 512, b1, (long)B_ * 512, 512, gib, 1536 * 64, 64, 1536, 64, 512);

    // 6. recurrence (unchanged) + finalize
    gru_recur4<<<256, 128, 0, stream>>>(gif, gib, gWhh, gbih, gbhh, seq_lens,
                                        hbuf, bar, F1, F2, hfin);
    final_k<<<38656, 256, 0, stream>>>(F1, F2, hfin, seq_lens, out);
}

// Round 11
// 2857.160 us; speedup vs baseline: 2.1113x; 1.1723x over previous
//
#include <hip/hip_runtime.h>
#include <hip/hip_bf16.h>

typedef __hip_bfloat16 bf16;
typedef unsigned long long ull;
typedef __attribute__((ext_vector_type(8))) short s16x8;
typedef __attribute__((ext_vector_type(4))) float f32x4;

#define B_      64
#define NMAX_   299
#define N_      300
#define D_      512
#define H_      512
#define NHEADS_ 8
#define NHID_   64
#define SCLD    304                  // padded leading dim for (n,m) score rows
#define SCSZ    (N_ * SCLD)          // 91,200 floats per batch
#define LDP     48                   // padded LDS row stride (bf16 elems) for mgemm
#define W5P     520                  // Whh LDS k-stride (shorts): 2-way bank alias only
#define HP      520                  // h LDS row stride (shorts)
#define AK      320                  // padded K (=m) for att/kT MFMA operands

// ---------------------------------------------------------------- utilities

__device__ __forceinline__ float sigmoidf_(float x) { return 1.0f / (1.0f + expf(-x)); }

// ---------------------------------------------------------------- embedding

__global__ void embed_k(const int* __restrict__ tokens, const int* __restrict__ tok_lens,
                        const int* __restrict__ seq_lens, const float* __restrict__ emb,
                        bf16* __restrict__ out)
{
    const int n = blockIdx.x, b = blockIdx.y;
    const int d = threadIdx.x * 4;
    const int nc = seq_lens[b] - 1;
    float4 v;
    if (n < nc) {
        const int tl = tok_lens[b * NMAX_ + n];
        const int* tp = tokens + (b * NMAX_ + n) * 8;
        float4 acc = {0.f, 0.f, 0.f, 0.f};
        for (int t = 0; t < 8; ++t) {
            if (t < tl) {
                const float4 e = *(const float4*)(emb + (long)tp[t] * D_ + d);
                acc.x += e.x; acc.y += e.y; acc.z += e.z; acc.w += e.w;
            }
        }
        const float inv = 1.0f / (float)nc;
        v.x = acc.x * inv; v.y = acc.y * inv; v.z = acc.z * inv; v.w = acc.w * inv;
    } else {
        const int row = (n == nc) ? 2 : 0;
        v = *(const float4*)(emb + row * D_ + d);
    }
    bf16 o[4] = {__float2bfloat16(v.x), __float2bfloat16(v.y),
                 __float2bfloat16(v.z), __float2bfloat16(v.w)};
    *(uint2*)(out + ((long)b * N_ + n) * D_ + d) = *(uint2*)o;
}

// ------------------------------------------------------------------- cond

__global__ void cond_k(const float* __restrict__ adj, unsigned char* __restrict__ cond)
{
    __shared__ float T1[64][65];
    __shared__ float T2[64][65];
    const int b = blockIdx.z;
    const int n0 = blockIdx.x * 64, m0 = blockIdx.y * 64;
    const int jj = threadIdx.x & 63, i0 = threadIdx.x >> 6;
    for (int r = 0; r < 16; ++r) {
        const int i = i0 * 16 + r;
        const int n = n0 + i, m = m0 + jj;
        T1[i][jj] = (n < N_ && m < N_) ? adj[((long)b * N_ + n) * N_ + m] : 0.f;
        const int n2 = m0 + i, m2 = n0 + jj;
        T2[i][jj] = (n2 < N_ && m2 < N_) ? adj[((long)b * N_ + n2) * N_ + m2] : 0.f;
    }
    __syncthreads();
    for (int r = 0; r < 16; ++r) {
        const int i = i0 * 16 + r;
        const int n = n0 + i, m = m0 + jj;
        if (n < N_ && m < N_) {
            const float v = T1[i][jj] + T2[jj][i] + ((n == m) ? 1.f : 0.f);
            cond[((long)b * N_ + n) * N_ + m] = (v > 0.f) ? 1 : 0;
        }
    }
}

// -------------------------------------------------- weight prep (fp32->bf16)

__global__ void wgath_k(const float* __restrict__ W, bf16* __restrict__ out)
{   // (8,512,64) -> (512,512): out[h*64+o][d] = W[h][d][o]
    const int row = blockIdx.x;
    const int d = threadIdx.x;
    const int h = row >> 6, o = row & 63;
    out[row * 512 + d] = __float2bfloat16(W[((long)h * 512 + d) * 64 + o]);
}

__global__ void wtr_k(const float* __restrict__ W, bf16* __restrict__ out)
{   // (512,512) -> transposed: out[o][i] = W[i][o]
    const int o = blockIdx.x;
    const int i = threadIdx.x;
    out[o * 512 + i] = __float2bfloat16(W[(long)i * 512 + o]);
}

__global__ void f2b_k(const float* __restrict__ in, bf16* __restrict__ out, long n)
{
    for (long i = (long)blockIdx.x * 256 + threadIdx.x; i < n; i += (long)gridDim.x * 256)
        out[i] = __float2bfloat16(in[i]);
}

// ---------------------------------------------- bf16 tile transpose (+pad)
// in: [b][300][512] -> out: [b][512][AK], out[f][m] = in[m][f]; m>=300 -> 0

__global__ void tbf_k(const bf16* __restrict__ in, bf16* __restrict__ out)
{
    __shared__ short T[64][65];
    const int b = blockIdx.z;
    const int m0 = blockIdx.x * 64, f0 = blockIdx.y * 64;
    const int jj = threadIdx.x & 63, i0 = threadIdx.x >> 6;
    for (int r = 0; r < 16; ++r) {
        const int i = i0 * 16 + r;
        const int m = m0 + i, f = f0 + jj;
        short v = 0;
        if (m < N_) v = *(const short*)&in[((long)b * N_ + m) * 512 + f];
        T[i][jj] = v;
    }
    __syncthreads();
    for (int r = 0; r < 16; ++r) {
        const int i = i0 * 16 + r;
        const int f = f0 + i, m = m0 + jj;
        ((short*)out)[((long)b * 512 + f) * AK + m] = T[jj][i];
    }
}

// ------------------------------------------------------- bf16 MFMA GEMM
// C[m][n] = sum_k A[m][k] * B[n][k]   (B transposed, row-major [N][K]).

template<int BM, int BN, bool OBF>
__global__ __launch_bounds__(256) void mgemm_k(
    const bf16* __restrict__ A, long sA, int lda,
    const bf16* __restrict__ Bm, long sB, int ldb,
    void* __restrict__ C, long sC, int ldc,
    int M, int N, int K)
{
    __shared__ short As[BM * LDP];
    __shared__ short Bs[BN * LDP];
    const int z = blockIdx.z;
    const bf16* Ab = A + (long)z * sA;
    const bf16* Bb = Bm + (long)z * sB;
    const int m0 = blockIdx.x * BM, n0 = blockIdx.y * BN;
    const int tid = threadIdx.x;
    const int lane = tid & 63;
    const int w = tid >> 6;
    const int wm = (w >> 1) * (BM / 2);
    const int wn = (w & 1) * (BN / 2);
    constexpr int MR = BM / 32;
    constexpr int NR = BN / 32;
    f32x4 acc[MR][NR] = {};

    const int srow = tid >> 2;
    const int sslot = (tid & 3) * 8;

    for (int k0 = 0; k0 < K; k0 += 32) {
        #pragma unroll
        for (int r = 0; r < BM / 64; ++r) {
            const int row = r * 64 + srow;
            uint4 v = {0u, 0u, 0u, 0u};
            if (m0 + row < M)
                v = *(const uint4*)(Ab + (long)(m0 + row) * lda + k0 + sslot);
            *(uint4*)&As[row * LDP + sslot] = v;
        }
        #pragma unroll
        for (int r = 0; r < BN / 64; ++r) {
            const int row = r * 64 + srow;
            uint4 v = {0u, 0u, 0u, 0u};
            if (n0 + row < N)
                v = *(const uint4*)(Bb + (long)(n0 + row) * ldb + k0 + sslot);
            *(uint4*)&Bs[row * LDP + sslot] = v;
        }
        __syncthreads();
        s16x8 aq[MR], bq[NR];
        #pragma unroll
        for (int i = 0; i < MR; ++i)
            aq[i] = *(const s16x8*)&As[(wm + i * 16 + (lane & 15)) * LDP + (lane >> 4) * 8];
        #pragma unroll
        for (int j = 0; j < NR; ++j)
            bq[j] = *(const s16x8*)&Bs[(wn + j * 16 + (lane & 15)) * LDP + (lane >> 4) * 8];
        #pragma unroll
        for (int i = 0; i < MR; ++i)
            #pragma unroll
            for (int j = 0; j < NR; ++j)
                acc[i][j] = __builtin_amdgcn_mfma_f32_16x16x32_bf16(aq[i], bq[j], acc[i][j], 0, 0, 0);
        __syncthreads();
    }

    #pragma unroll
    for (int i = 0; i < MR; ++i) {
        const int mrow = m0 + wm + i * 16 + (lane >> 4) * 4;
        #pragma unroll
        for (int j = 0; j < NR; ++j) {
            const int ncol = n0 + wn + j * 16 + (lane & 15);
            if (ncol < N) {
                #pragma unroll
                for (int e = 0; e < 4; ++e) {
                    const int mm = mrow + e;
                    if (mm < M) {
                        const long idx = (long)z * sC + (long)mm * ldc + ncol;
                        if (OBF) ((bf16*)C)[idx] = __float2bfloat16(acc[i][j][e]);
                        else     ((float*)C)[idx] = acc[i][j][e];
                    }
                }
            }
        }
    }
}

// ------------------------------------------------- softmaxes for GAT layer
// bsoft v2: LDS-tiled single global pass.

__global__ __launch_bounds__(256) void bsoft_k(
    const float* __restrict__ sc, float* __restrict__ mx, float* __restrict__ sm)
{
    __shared__ float T[64][65];
    __shared__ float P[4][64];
    __shared__ float Mv[64];
    const int idx0 = blockIdx.x * 64;
    const int il = threadIdx.x & 63;
    const int bq = threadIdx.x >> 6;       // 0..3

    #pragma unroll
    for (int r = 0; r < 16; ++r) {
        const int b = bq * 16 + r;
        T[b][il] = sc[(long)b * SCSZ + idx0 + il];
    }
    __syncthreads();

    float pm = -1e30f;
    #pragma unroll
    for (int r = 0; r < 16; ++r) pm = fmaxf(pm, T[bq * 16 + r][il]);
    P[bq][il] = pm;
    __syncthreads();
    if (bq == 0) {
        float m = fmaxf(fmaxf(P[0][il], P[1][il]), fmaxf(P[2][il], P[3][il]));
        Mv[il] = m;
        mx[idx0 + il] = m;
    }
    __syncthreads();

    const float m = Mv[il];
    float ps = 0.f;
    #pragma unroll
    for (int r = 0; r < 16; ++r) ps += expf(T[bq * 16 + r][il] - m);
    __syncthreads();
    P[bq][il] = ps;
    __syncthreads();
    if (bq == 0)
        sm[idx0 + il] = P[0][il] + P[1][il] + P[2][il] + P[3][il];
}

// colsoft v2: register-resident e-values, one sc read + one abf write.
#define NSTR 38   // ceil(300/8)

__global__ __launch_bounds__(512) void colsoft_k(
    const float* __restrict__ sc, const float* __restrict__ mx,
    const float* __restrict__ sm, const unsigned char* __restrict__ cond,
    bf16* __restrict__ abf)
{
    __shared__ float red[8][64];
    const int ml = threadIdx.x & 63;
    const int ng = threadIdx.x >> 6;           // 0..7
    const int m = blockIdx.x * 64 + ml;        // 0..319
    const int b = blockIdx.y;
    const float* scb = sc + (long)b * SCSZ;
    const unsigned char* cb = cond + (long)b * (N_ * N_);
    const bool act = m < N_;

    float ev[NSTR];
    ull cmask = 0;
    float vmax = -1e30f;
    #pragma unroll
    for (int i = 0; i < NSTR; ++i) {
        const int n = ng + i * 8;
        float e = 0.f;
        if (n < N_ && act && cb[n * N_ + m]) {
            const int o = n * SCLD + m;
            e = expf(scb[o] - mx[o]) / sm[o];
            cmask |= 1ull << i;
            vmax = fmaxf(vmax, e);
        }
        ev[i] = e;
    }
    red[ng][ml] = vmax;
    __syncthreads();
    vmax = red[0][ml];
    #pragma unroll
    for (int i = 1; i < 8; ++i) vmax = fmaxf(vmax, red[i][ml]);

    float ssum = 0.f;
    #pragma unroll
    for (int i = 0; i < NSTR; ++i)
        if ((cmask >> i) & 1) ssum += expf(ev[i] - vmax);
    __syncthreads();
    red[ng][ml] = ssum;
    __syncthreads();
    ssum = 0.f;
    #pragma unroll
    for (int i = 0; i < 8; ++i) ssum += red[i][ml];
    const float inv = 1.0f / ssum;

    #pragma unroll
    for (int i = 0; i < NSTR; ++i) {
        const int n = ng + i * 8;
        if (n < N_) {
            const float v = ((cmask >> i) & 1) ? expf(ev[i] - vmax) * inv : 0.f;
            abf[(long)b * (N_ * AK) + n * AK + m] = __float2bfloat16(v);
        }
    }
}

__global__ void nsoft_k(const float* __restrict__ hp, bf16* __restrict__ out)
{
    const int f = blockIdx.x * 256 + threadIdx.x;
    const int b = blockIdx.y;
    const float* hb = hp + (long)b * (N_ * 512) + f;
    float vmax = -1e30f;
    for (int n = 0; n < N_; ++n) vmax = fmaxf(vmax, hb[n * 512]);
    float s = 0.f;
    for (int n = 0; n < N_; ++n) s += expf(hb[n * 512] - vmax);
    const float inv = 1.0f / s;
    bf16* ob = out + (long)b * (N_ * 512) + f;
    for (int n = 0; n < N_; ++n) ob[n * 512] = __float2bfloat16(expf(hb[n * 512] - vmax) * inv);
}

// ----------------------------------------------------------------- GRU prep

__global__ void xrev_k(const bf16* __restrict__ out2, const int* __restrict__ seq_lens,
                       bf16* __restrict__ xr)
{
    const int t = blockIdx.x, b = blockIdx.y;
    const int d = threadIdx.x * 4;
    int src = seq_lens[b] - 1 - t;
    if (src < 0) src = 0;
    *(uint2*)(xr + ((long)t * B_ + b) * 512 + d) =
        *(const uint2*)(out2 + ((long)b * N_ + src) * 512 + d);
}

__global__ void zero_k(float* __restrict__ p, long n)
{
    for (long i = (long)blockIdx.x * 256 + threadIdx.x; i < n; i += (long)gridDim.x * 256)
        p[i] = 0.f;
}

// ------------------------------------------------------ GRU recurrence (v5)
// 256 blocks = 2 dir x 32 u-slabs(16u) x 4 batch-quarters(16b). 128 thr =
// 2 waves; wave = k-half (0..255 / 256..511), both waves same 16 batches.
// 16-u slab halves the h-exchange read-amplification (16 MB -> 8 MB/step).
// Whh hi/lo (16 u, 97.5 KB) LDS-resident; h staged per-plane sequentially
// through ONE 16-KB buffer (pass A: Whi*hhi + Wlo*hhi; pass B: Whi*hlo —
// same 3 terms as v4). Cross-wave k-reduce via 3-KB LDS scratch; epilogue
// on wave 0. Barrier: 8 groups (dir x bq) x 32 blocks, 4 leaves x 8.

__device__ __forceinline__ void dbar5(unsigned* __restrict__ gc, unsigned* __restrict__ root,
                                      int step) {
    __syncthreads();   // exec barrier + vmcnt drain of this block's stores
    if (threadIdx.x == 0) {
        const unsigned old =
            __hip_atomic_fetch_add(gc, 1u, __ATOMIC_RELAXED, __HIP_MEMORY_SCOPE_AGENT);
        if (old == (unsigned)(step * 8 + 7))
            __hip_atomic_fetch_add(root, 1u, __ATOMIC_RELAXED, __HIP_MEMORY_SCOPE_AGENT);
        while (__hip_atomic_load(root, __ATOMIC_RELAXED, __HIP_MEMORY_SCOPE_AGENT)
               < (unsigned)((step + 1) * 4)) {
            __builtin_amdgcn_s_sleep(1);
        }
    }
    __syncthreads();
}

__global__ __launch_bounds__(128, 1) void gru_recur5(
    const bf16* __restrict__ gif, const bf16* __restrict__ gib,
    const float* __restrict__ Whh, const float* __restrict__ bih,
    const float* __restrict__ bhh, const int* __restrict__ seq_lens,
    float* __restrict__ hbuf_f, unsigned* __restrict__ bar,
    float* __restrict__ outf, float* __restrict__ outb,
    float* __restrict__ hfin)
{
    __shared__ alignas(16) short wlds[2 * 3 * 16 * W5P];   // 97.5 KB Whh hi/lo
    __shared__ alignas(16) short hlds[16 * HP];            // 16.25 KB h staging / scratch
    const int tid = threadIdx.x;               // 0..127
    const int lane = tid & 63;
    const int w = tid >> 6;                    // k-half 0..1
    const int ml = lane & 15;                  // batch-in-block / frag row
    const int ksl = lane >> 4;                 // 0..3
    const int dir = blockIdx.x >> 7;
    const int rem = blockIdx.x & 127;
    const int slab = rem >> 2;                 // 0..31 (16-u slab)
    const int bq   = rem & 3;                  // batch quarter
    const int ub   = slab * 16;
    const int g8   = dir * 4 + bq;             // 8 barrier groups x 32 blocks
    unsigned* gc   = bar + (g8 * 4 + (slab >> 3)) * 32;
    unsigned* root = bar + 1024 + g8 * 32;
    bf16* hb = (bf16*)hbuf_f;

    // one-time: Whh 16-u slab -> LDS hi/lo bf16 (rows: g*16+ul)
    {
        const float* Wb = Whh + (long)dir * (1536 * 512);
        for (int idx = tid; idx < 3 * 16 * 512; idx += 128) {
            const int row = idx >> 9;          // 0..47
            const int k = idx & 511;
            const int g = row >> 4, ul = row & 15;
            const float v = Wb[(long)(g * 512 + ub + ul) * 512 + k];
            const bf16 hi = __float2bfloat16(v);
            const bf16 lo = __float2bfloat16(v - __bfloat162float(hi));
            wlds[(0 * 48 + row) * W5P + k] = *(const short*)&hi;
            wlds[(1 * 48 + row) * W5P + k] = *(const short*)&lo;
        }
    }

    const int bcol = bq * 16 + ml;             // this lane's batch (C col)
    const int ue   = ub + ksl * 4;             // this lane's u-quad (C rows)
    const bf16* gi = dir ? gib : gif;
    float cr[4], cz[4], cn[4], brr[4], bzz[4], bnn[4];
    #pragma unroll
    for (int e = 0; e < 4; ++e) {
        cr[e]  = bih[dir * 1536 + ue + e];
        cz[e]  = bih[dir * 1536 + 512 + ue + e];
        cn[e]  = bih[dir * 1536 + 1024 + ue + e];
        brr[e] = bhh[dir * 1536 + ue + e];
        bzz[e] = bhh[dir * 1536 + 512 + ue + e];
        bnn[e] = bhh[dir * 1536 + 1024 + ue + e];
    }
    const int sl = seq_lens[bcol];
    float hreg[4] = {0.f, 0.f, 0.f, 0.f};
    float owv[4] = {0.f, 0.f, 0.f, 0.f};

    if (w == 0) {   // zero phase-0 h (both planes); each lane owns (bcol, ue..+3)
        const long z0 = (long)((dir * 2 + 0) * 2 + 0) * 32768 + bcol * 512 + ue;
        const long z1 = (long)((dir * 2 + 0) * 2 + 1) * 32768 + bcol * 512 + ue;
        __hip_atomic_store((ull*)(hb + z0), 0ull, __ATOMIC_RELAXED, __HIP_MEMORY_SCOPE_AGENT);
        __hip_atomic_store((ull*)(hb + z1), 0ull, __ATOMIC_RELAXED, __HIP_MEMORY_SCOPE_AGENT);
    }
    dbar5(gc, root, 0);

    for (int t = 0; t < N_; ++t) {
        const int rp = t & 1, wp = rp ^ 1;
        const ull* hu0 = (const ull*)hb + (long)((dir * 2 + rp) * 2 + 0) * 8192 + bq * 2048;
        const ull* hu1 = (const ull*)hb + (long)((dir * 2 + rp) * 2 + 1) * 8192 + bq * 2048;

        // 1. issue ALL coalesced staging loads (16 b x 512 u, both planes)
        ull r0[16], r1[16];
        #pragma unroll
        for (int i = 0; i < 16; ++i)
            r0[i] = __hip_atomic_load(hu0 + i * 128 + tid,
                                      __ATOMIC_RELAXED, __HIP_MEMORY_SCOPE_AGENT);
        #pragma unroll
        for (int i = 0; i < 16; ++i)
            r1[i] = __hip_atomic_load(hu1 + i * 128 + tid,
                                      __ATOMIC_RELAXED, __HIP_MEMORY_SCOPE_AGENT);

        // 2. deferred out-writes of step t-1 (wave 0)
        if (t > 0 && w == 0) {
            const int tp = t - 1;
            if (dir == 0) {
                #pragma unroll
                for (int e = 0; e < 4; ++e)
                    outf[(long)tp * 32768 + (ue + e) * 64 + bcol] = owv[e];
            } else if (tp < sl) {
                #pragma unroll
                for (int e = 0; e < 4; ++e)
                    outb[(long)(sl - 1 - tp) * 32768 + (ue + e) * 64 + bcol] = owv[e];
            }
        }

        // 3. gi for this step (wave 0 consumes)
        float gv[3][4];
        if (w == 0) {
            #pragma unroll
            for (int g = 0; g < 3; ++g)
                #pragma unroll
                for (int e = 0; e < 4; ++e)
                    gv[g][e] = __bfloat162float(
                        gi[(long)t * 98304 + (g * 512 + ue + e) * 64 + bcol]);
        }

        // 4. pass A: stage h_hi, MFMA Whi*hhi + Wlo*hhi over my k-half
        #pragma unroll
        for (int i = 0; i < 16; ++i) {
            const int q = i * 128 + tid;       // 0..2047
            const int bl_ = q >> 7, uo = q & 127;
            *(ull*)&hlds[bl_ * HP + uo * 4] = r0[i];
        }
        __syncthreads();

        const int brow = ml * HP;
        f32x4 acc[3] = {};
        #pragma unroll
        for (int k8 = 0; k8 < 8; ++k8) {
            const int ks = w * 8 + k8;
            const int u0 = ks * 32 + ksl * 8;
            const s16x8 fh = *(const s16x8*)&hlds[brow + u0];
            const s16x8 a0h = *(const s16x8*)&wlds[(0 * 48 + 0 * 16 + ml) * W5P + u0];
            const s16x8 a1h = *(const s16x8*)&wlds[(0 * 48 + 1 * 16 + ml) * W5P + u0];
            const s16x8 a2h = *(const s16x8*)&wlds[(0 * 48 + 2 * 16 + ml) * W5P + u0];
            const s16x8 a0l = *(const s16x8*)&wlds[(1 * 48 + 0 * 16 + ml) * W5P + u0];
            const s16x8 a1l = *(const s16x8*)&wlds[(1 * 48 + 1 * 16 + ml) * W5P + u0];
            const s16x8 a2l = *(const s16x8*)&wlds[(1 * 48 + 2 * 16 + ml) * W5P + u0];
            acc[0] = __builtin_amdgcn_mfma_f32_16x16x32_bf16(a0h, fh, acc[0], 0, 0, 0);
            acc[1] = __builtin_amdgcn_mfma_f32_16x16x32_bf16(a1h, fh, acc[1], 0, 0, 0);
            acc[2] = __builtin_amdgcn_mfma_f32_16x16x32_bf16(a2h, fh, acc[2], 0, 0, 0);
            acc[0] = __builtin_amdgcn_mfma_f32_16x16x32_bf16(a0l, fh, acc[0], 0, 0, 0);
            acc[1] = __builtin_amdgcn_mfma_f32_16x16x32_bf16(a1l, fh, acc[1], 0, 0, 0);
            acc[2] = __builtin_amdgcn_mfma_f32_16x16x32_bf16(a2l, fh, acc[2], 0, 0, 0);
        }
        __syncthreads();

        // 5. pass B: stage h_lo (from regs), MFMA Whi*hlo
        #pragma unroll
        for (int i = 0; i < 16; ++i) {
            const int q = i * 128 + tid;
            const int bl_ = q >> 7, uo = q & 127;
            *(ull*)&hlds[bl_ * HP + uo * 4] = r1[i];
        }
        __syncthreads();
        #pragma unroll
        for (int k8 = 0; k8 < 8; ++k8) {
            const int ks = w * 8 + k8;
            const int u0 = ks * 32 + ksl * 8;
            const s16x8 fl = *(const s16x8*)&hlds[brow + u0];
            const s16x8 a0h = *(const s16x8*)&wlds[(0 * 48 + 0 * 16 + ml) * W5P + u0];
            const s16x8 a1h = *(const s16x8*)&wlds[(0 * 48 + 1 * 16 + ml) * W5P + u0];
            const s16x8 a2h = *(const s16x8*)&wlds[(0 * 48 + 2 * 16 + ml) * W5P + u0];
            acc[0] = __builtin_amdgcn_mfma_f32_16x16x32_bf16(a0h, fl, acc[0], 0, 0, 0);
            acc[1] = __builtin_amdgcn_mfma_f32_16x16x32_bf16(a1h, fl, acc[1], 0, 0, 0);
            acc[2] = __builtin_amdgcn_mfma_f32_16x16x32_bf16(a2h, fl, acc[2], 0, 0, 0);
        }
        __syncthreads();

        // 6. cross-wave k-reduce (wave 1 -> wave 0) via LDS scratch
        float* scr = (float*)hlds;
        if (w == 1) {
            #pragma unroll
            for (int g = 0; g < 3; ++g)
                #pragma unroll
                for (int e = 0; e < 4; ++e)
                    scr[(lane * 3 + g) * 4 + e] = acc[g][e];
        }
        __syncthreads();

        // 7. epilogue on wave 0: gates, h update, stores
        if (w == 0) {
            #pragma unroll
            for (int g = 0; g < 3; ++g)
                #pragma unroll
                for (int e = 0; e < 4; ++e)
                    acc[g][e] += scr[(lane * 3 + g) * 4 + e];

            ull phi = 0, plo = 0;
            const bool msk = t < sl;
            #pragma unroll
            for (int e = 0; e < 4; ++e) {
                const float rg = sigmoidf_(cr[e] + gv[0][e] + brr[e] + acc[0][e]);
                const float zg = sigmoidf_(cz[e] + gv[1][e] + bzz[e] + acc[1][e]);
                const float ng = tanhf(cn[e] + gv[2][e] + rg * (bnn[e] + acc[2][e]));
                const float hnew = (1.f - zg) * ng + zg * hreg[e];
                owv[e] = (dir == 0) ? (msk ? hnew : 0.f) : hnew;
                hreg[e] = msk ? hnew : hreg[e];
                const bf16 h_hi = __float2bfloat16(hreg[e]);
                const bf16 h_lo = __float2bfloat16(hreg[e] - __bfloat162float(h_hi));
                phi |= (ull)(*(const unsigned short*)&h_hi) << (16 * e);
                plo |= (ull)(*(const unsigned short*)&h_lo) << (16 * e);
            }
            const long wbh = (long)((dir * 2 + wp) * 2 + 0) * 32768 + bcol * 512 + ue;
            const long wbl = (long)((dir * 2 + wp) * 2 + 1) * 32768 + bcol * 512 + ue;
            __hip_atomic_store((ull*)(hb + wbh), phi, __ATOMIC_RELAXED, __HIP_MEMORY_SCOPE_AGENT);
            __hip_atomic_store((ull*)(hb + wbl), plo, __ATOMIC_RELAXED, __HIP_MEMORY_SCOPE_AGENT);
        }

        dbar5(gc, root, t + 1);
    }

    // final deferred out-write + final hidden state (wave 0)
    if (w == 0) {
        const int tp = N_ - 1;
        if (dir == 0) {
            #pragma unroll
            for (int e = 0; e < 4; ++e)
                outf[(long)tp * 32768 + (ue + e) * 64 + bcol] = owv[e];
        } else if (tp < sl) {
            #pragma unroll
            for (int e = 0; e < 4; ++e)
                outb[(long)(sl - 1 - tp) * 32768 + (ue + e) * 64 + bcol] = owv[e];
        }
        #pragma unroll
        for (int e = 0; e < 4; ++e)
            hfin[dir * 32768 + (ue + e) * 64 + bcol] = hreg[e];
    }
}

// --------------------------------------------------------------- finalize

__global__ void final_k(const float* __restrict__ outf, const float* __restrict__ outb,
                        const float* __restrict__ hfin, const int* __restrict__ seq_lens,
                        float* __restrict__ dout)
{
    const long i = (long)blockIdx.x * 256 + threadIdx.x;
    const long NOUT = (long)N_ * B_ * 512;
    if (i < NOUT) {
        const int t = (int)(i >> 15);
        const int b = (int)((i >> 9) & 63);
        const int u = (int)(i & 511);
        const long src = (long)t * 32768 + u * 64 + b;
        dout[i] = (t < seq_lens[b]) ? outf[src] + outb[src] : 0.f;
    } else if (i < NOUT + 2 * B_ * 512) {
        const long j = i - NOUT;
        const int dir = (int)(j >> 15);
        const int b = (int)((j >> 9) & 63);
        const int u = (int)(j & 511);
        dout[i] = hfin[dir * 32768 + u * 64 + b];
    }
}

__global__ void fail_zero_k(float* __restrict__ dout, long n)
{
    for (long i = (long)blockIdx.x * 256 + threadIdx.x; i < n; i += (long)gridDim.x * 256)
        dout[i] = 0.f;
}

// ----------------------------------------------------------------- launch

extern "C" void kernel_launch(void* const* d_in, const int* in_sizes, int n_in,
                              void* d_out, int out_size, void* d_ws, size_t ws_size,
                              hipStream_t stream)
{
    const int*   tokens   = (const int*)d_in[0];
    const int*   tok_lens = (const int*)d_in[1];
    const int*   seq_lens = (const int*)d_in[2];
    const float* adj      = (const float*)d_in[3];
    const float* emb      = (const float*)d_in[4];
    const float* Wq       = (const float*)d_in[5];
    const float* Wk       = (const float*)d_in[6];
    const float* Wq_o     = (const float*)d_in[7];
    const float* Wk_o     = (const float*)d_in[8];
    const float* gWih     = (const float*)d_in[9];
    const float* gWhh     = (const float*)d_in[10];
    const float* gbih     = (const float*)d_in[11];
    const float* gbhh     = (const float*)d_in[12];
    float* out = (float*)d_out;

    const long SZ = (long)B_ * N_ * 512;   // 9,830,400 elements
    float* F1 = (float*)d_ws;              // kT scratch -> outf
    float* F2 = F1 + SZ;                   // att_bf     -> outb
    float* F3 = F2 + SZ;                   // hp1 / hp2 (fp32)
    bf16* b0 = (bf16*)(F3 + SZ);           // embx -> out2
    bf16* b1 = b0 + SZ;                    // x1   -> x_rev
    bf16* b2 = b1 + SZ;                    // q1b  -> q2 -> wih(bf16)
    bf16* b3 = b2 + SZ;                    // k1b  -> k2
    float* sc   = (float*)(b3 + SZ);
    float* mx   = sc + (long)B_ * SCSZ;
    float* smv  = mx + SCSZ;
    unsigned char* cond = (unsigned char*)(smv + SCSZ);
    bf16* gif = (bf16*)(cond + (long)B_ * N_ * N_);
    bf16* gib = gif + (long)N_ * 1536 * B_;
    float* hbuf = (float*)(gib + (long)N_ * 1536 * B_);
    unsigned* bar = (unsigned*)(hbuf + 131072);
    float* hfin = (float*)(bar + 2048);
    const size_t needed = (size_t)((char*)(hfin + 2 * 512 * 64) - (char*)d_ws);
    if (ws_size < needed) {
        fail_zero_k<<<4096, 256, 0, stream>>>(out, out_size);
        return;
    }
    bf16* wq1  = (bf16*)sc;                // dead-region transients
    bf16* wk1  = wq1 + 512 * 512;
    bf16* w2q  = (bf16*)sc;
    bf16* w2k  = w2q + 512 * 512;
    bf16* wihb = b2;
    bf16* kT   = (bf16*)F1;                // [b][512][AK] transposed keys
    bf16* abf  = (bf16*)F2;                // [b][N][AK] bf16 att probs

    // 1. layer-1 weight prep, embedding (bf16), cond
    wgath_k<<<512, 512, 0, stream>>>(Wq, wq1);
    wgath_k<<<512, 512, 0, stream>>>(Wk, wk1);
    embed_k<<<dim3(N_, B_), 128, 0, stream>>>(tokens, tok_lens, seq_lens, emb, b0);
    cond_k<<<dim3(5, 5, B_), 256, 0, stream>>>(adj, cond);

    // 2. layer-1 projections via MFMA (bf16 out): q1 -> b2, k1 -> b3; k1^T
    mgemm_k<128, 128, true><<<dim3(150, 4, 1), 256, 0, stream>>>(
        b0, 0, 512, wq1, 0, 512, b2, 0, 512, B_ * N_, 512, 512);
    mgemm_k<128, 128, true><<<dim3(150, 4, 1), 256, 0, stream>>>(
        b0, 0, 512, wk1, 0, 512, b3, 0, 512, B_ * N_, 512, 512);
    tbf_k<<<dim3(5, 8, B_), 256, 0, stream>>>(b3, kT);

    // 3. per-head attention (all MFMA)
    for (int h = 0; h < NHEADS_; ++h) {
        mgemm_k<64, 64, false><<<dim3(5, 5, B_), 256, 0, stream>>>(    // scores1
            b2 + h * 64, (long)N_ * 512, 512,
            b3 + h * 64, (long)N_ * 512, 512,
            sc, SCSZ, SCLD, N_, N_, 64);
        bsoft_k<<<SCSZ / 64, 256, 0, stream>>>(sc, mx, smv);
        colsoft_k<<<dim3(5, B_), 512, 0, stream>>>(sc, mx, smv, cond, abf);
        mgemm_k<64, 64, false><<<dim3(5, 1, B_), 256, 0, stream>>>(    // hp1
            abf, (long)N_ * AK, AK,
            kT + (long)h * 64 * AK, (long)512 * AK, AK,
            F3 + h * 64, (long)N_ * 512, 512, N_, 64, AK);
    }
    nsoft_k<<<dim3(2, B_), 256, 0, stream>>>(F3, b1);                  // x1 (bf16)

    // 4. layer-2 via MFMA: q2/k2 (bf16), k2^T, scores2, hp2
    wtr_k<<<512, 512, 0, stream>>>(Wq_o, w2q);
    wtr_k<<<512, 512, 0, stream>>>(Wk_o, w2k);
    mgemm_k<128, 128, true><<<dim3(150, 4, 1), 256, 0, stream>>>(
        b1, 0, 512, w2q, 0, 512, b2, 0, 512, B_ * N_, 512, 512);
    mgemm_k<128, 128, true><<<dim3(150, 4, 1), 256, 0, stream>>>(
        b1, 0, 512, w2k, 0, 512, b3, 0, 512, B_ * N_, 512, 512);
    tbf_k<<<dim3(5, 8, B_), 256, 0, stream>>>(b3, kT);
    mgemm_k<64, 64, false><<<dim3(5, 5, B_), 256, 0, stream>>>(        // scores2
        b2, (long)N_ * 512, 512, b3, (long)N_ * 512, 512,
        sc, SCSZ, SCLD, N_, N_, 512);
    f2b_k<<<6144, 256, 0, stream>>>(gWih, wihb, (long)2 * 1536 * 512); // q2 dead
    bsoft_k<<<SCSZ / 64, 256, 0, stream>>>(sc, mx, smv);
    colsoft_k<<<dim3(5, B_), 512, 0, stream>>>(sc, mx, smv, cond, abf);
    mgemm_k<64, 64, false><<<dim3(5, 8, B_), 256, 0, stream>>>(        // hp2
        abf, (long)N_ * AK, AK,
        kT, (long)512 * AK, AK,
        F3, (long)N_ * 512, 512, N_, 512, AK);
    nsoft_k<<<dim3(2, B_), 256, 0, stream>>>(F3, b0);                  // out2 (bf16)

    // 5. GRU input GEMMs via MFMA (bf16 out, layout (t, j, b))
    xrev_k<<<dim3(N_, B_), 128, 0, stream>>>(b0, seq_lens, b1);
    zero_k<<<1, 256, 0, stream>>>((float*)bar, 2048);
    mgemm_k<64, 64, true><<<dim3(24, 1, N_), 256, 0, stream>>>(
        wihb, 0, 512, b0, 512, (long)N_ * 512, gif, 1536 * 64, 64, 1536, 64, 512);
    mgemm_k<64, 64, true><<<dim3(24, 1, N_), 256, 0, stream>>>(
        wihb + 1536 * 512, 0, 512, b1, (long)B_ * 512, 512, gib, 1536 * 64, 64, 1536, 64, 512);

    // 6. recurrence (v5: 16-u slabs, 2-pass staging, k-split waves) + finalize
    gru_recur5<<<256, 128, 0, stream>>>(gif, gib, gWhh, gbih, gbhh, seq_lens,
                                        hbuf, bar, F1, F2, hfin);
    final_k<<<38656, 256, 0, stream>>>(F1, F2, hfin, seq_lens, out);
}

// Round 12
// 2664.156 us; speedup vs baseline: 2.2642x; 1.0724x over previous
//
#include <hip/hip_runtime.h>
#include <hip/hip_bf16.h>

typedef __hip_bfloat16 bf16;
typedef unsigned long long ull;
typedef __attribute__((ext_vector_type(8))) short s16x8;
typedef __attribute__((ext_vector_type(4))) float f32x4;

#define B_      64
#define NMAX_   299
#define N_      300
#define D_      512
#define H_      512
#define NHEADS_ 8
#define NHID_   64
#define SCLD    304                  // padded leading dim for (n,m) score rows
#define SCSZ    (N_ * SCLD)          // 91,200 floats per batch
#define LDP     48                   // padded LDS row stride (bf16 elems) for mgemm
#define W5P     520                  // Whh LDS k-stride (shorts): 2-way bank alias only
#define HP      520                  // h LDS row stride (shorts)
#define AK      320                  // padded K (=m) for att/kT MFMA operands

// ---------------------------------------------------------------- utilities

__device__ __forceinline__ float sigmoidf_(float x) { return 1.0f / (1.0f + expf(-x)); }

// ---------------------------------------------------------------- embedding

__global__ void embed_k(const int* __restrict__ tokens, const int* __restrict__ tok_lens,
                        const int* __restrict__ seq_lens, const float* __restrict__ emb,
                        bf16* __restrict__ out)
{
    const int n = blockIdx.x, b = blockIdx.y;
    const int d = threadIdx.x * 4;
    const int nc = seq_lens[b] - 1;
    float4 v;
    if (n < nc) {
        const int tl = tok_lens[b * NMAX_ + n];
        const int* tp = tokens + (b * NMAX_ + n) * 8;
        float4 acc = {0.f, 0.f, 0.f, 0.f};
        for (int t = 0; t < 8; ++t) {
            if (t < tl) {
                const float4 e = *(const float4*)(emb + (long)tp[t] * D_ + d);
                acc.x += e.x; acc.y += e.y; acc.z += e.z; acc.w += e.w;
            }
        }
        const float inv = 1.0f / (float)nc;
        v.x = acc.x * inv; v.y = acc.y * inv; v.z = acc.z * inv; v.w = acc.w * inv;
    } else {
        const int row = (n == nc) ? 2 : 0;
        v = *(const float4*)(emb + row * D_ + d);
    }
    bf16 o[4] = {__float2bfloat16(v.x), __float2bfloat16(v.y),
                 __float2bfloat16(v.z), __float2bfloat16(v.w)};
    *(uint2*)(out + ((long)b * N_ + n) * D_ + d) = *(uint2*)o;
}

// ------------------------------------------------------------------- cond

__global__ void cond_k(const float* __restrict__ adj, unsigned char* __restrict__ cond)
{
    __shared__ float T1[64][65];
    __shared__ float T2[64][65];
    const int b = blockIdx.z;
    const int n0 = blockIdx.x * 64, m0 = blockIdx.y * 64;
    const int jj = threadIdx.x & 63, i0 = threadIdx.x >> 6;
    for (int r = 0; r < 16; ++r) {
        const int i = i0 * 16 + r;
        const int n = n0 + i, m = m0 + jj;
        T1[i][jj] = (n < N_ && m < N_) ? adj[((long)b * N_ + n) * N_ + m] : 0.f;
        const int n2 = m0 + i, m2 = n0 + jj;
        T2[i][jj] = (n2 < N_ && m2 < N_) ? adj[((long)b * N_ + n2) * N_ + m2] : 0.f;
    }
    __syncthreads();
    for (int r = 0; r < 16; ++r) {
        const int i = i0 * 16 + r;
        const int n = n0 + i, m = m0 + jj;
        if (n < N_ && m < N_) {
            const float v = T1[i][jj] + T2[jj][i] + ((n == m) ? 1.f : 0.f);
            cond[((long)b * N_ + n) * N_ + m] = (v > 0.f) ? 1 : 0;
        }
    }
}

// -------------------------------------------------- weight prep (fp32->bf16)

__global__ void wgath_k(const float* __restrict__ W, bf16* __restrict__ out)
{   // (8,512,64) -> (512,512): out[h*64+o][d] = W[h][d][o]
    const int row = blockIdx.x;
    const int d = threadIdx.x;
    const int h = row >> 6, o = row & 63;
    out[row * 512 + d] = __float2bfloat16(W[((long)h * 512 + d) * 64 + o]);
}

__global__ void wtr_k(const float* __restrict__ W, bf16* __restrict__ out)
{   // (512,512) -> transposed: out[o][i] = W[i][o]
    const int o = blockIdx.x;
    const int i = threadIdx.x;
    out[o * 512 + i] = __float2bfloat16(W[(long)i * 512 + o]);
}

__global__ void f2b_k(const float* __restrict__ in, bf16* __restrict__ out, long n)
{
    for (long i = (long)blockIdx.x * 256 + threadIdx.x; i < n; i += (long)gridDim.x * 256)
        out[i] = __float2bfloat16(in[i]);
}

// ---------------------------------------------- bf16 tile transpose (+pad)
// in: [b][300][512] -> out: [b][512][AK], out[f][m] = in[m][f]; m>=300 -> 0

__global__ void tbf_k(const bf16* __restrict__ in, bf16* __restrict__ out)
{
    __shared__ short T[64][65];
    const int b = blockIdx.z;
    const int m0 = blockIdx.x * 64, f0 = blockIdx.y * 64;
    const int jj = threadIdx.x & 63, i0 = threadIdx.x >> 6;
    for (int r = 0; r < 16; ++r) {
        const int i = i0 * 16 + r;
        const int m = m0 + i, f = f0 + jj;
        short v = 0;
        if (m < N_) v = *(const short*)&in[((long)b * N_ + m) * 512 + f];
        T[i][jj] = v;
    }
    __syncthreads();
    for (int r = 0; r < 16; ++r) {
        const int i = i0 * 16 + r;
        const int f = f0 + i, m = m0 + jj;
        ((short*)out)[((long)b * 512 + f) * AK + m] = T[jj][i];
    }
}

// ------------------------------------------------------- bf16 MFMA GEMM
// C[m][n] = sum_k A[m][k] * B[n][k]   (B transposed, row-major [N][K]).

template<int BM, int BN, bool OBF>
__global__ __launch_bounds__(256) void mgemm_k(
    const bf16* __restrict__ A, long sA, int lda,
    const bf16* __restrict__ Bm, long sB, int ldb,
    void* __restrict__ C, long sC, int ldc,
    int M, int N, int K)
{
    __shared__ short As[BM * LDP];
    __shared__ short Bs[BN * LDP];
    const int z = blockIdx.z;
    const bf16* Ab = A + (long)z * sA;
    const bf16* Bb = Bm + (long)z * sB;
    const int m0 = blockIdx.x * BM, n0 = blockIdx.y * BN;
    const int tid = threadIdx.x;
    const int lane = tid & 63;
    const int w = tid >> 6;
    const int wm = (w >> 1) * (BM / 2);
    const int wn = (w & 1) * (BN / 2);
    constexpr int MR = BM / 32;
    constexpr int NR = BN / 32;
    f32x4 acc[MR][NR] = {};

    const int srow = tid >> 2;
    const int sslot = (tid & 3) * 8;

    for (int k0 = 0; k0 < K; k0 += 32) {
        #pragma unroll
        for (int r = 0; r < BM / 64; ++r) {
            const int row = r * 64 + srow;
            uint4 v = {0u, 0u, 0u, 0u};
            if (m0 + row < M)
                v = *(const uint4*)(Ab + (long)(m0 + row) * lda + k0 + sslot);
            *(uint4*)&As[row * LDP + sslot] = v;
        }
        #pragma unroll
        for (int r = 0; r < BN / 64; ++r) {
            const int row = r * 64 + srow;
            uint4 v = {0u, 0u, 0u, 0u};
            if (n0 + row < N)
                v = *(const uint4*)(Bb + (long)(n0 + row) * ldb + k0 + sslot);
            *(uint4*)&Bs[row * LDP + sslot] = v;
        }
        __syncthreads();
        s16x8 aq[MR], bq[NR];
        #pragma unroll
        for (int i = 0; i < MR; ++i)
            aq[i] = *(const s16x8*)&As[(wm + i * 16 + (lane & 15)) * LDP + (lane >> 4) * 8];
        #pragma unroll
        for (int j = 0; j < NR; ++j)
            bq[j] = *(const s16x8*)&Bs[(wn + j * 16 + (lane & 15)) * LDP + (lane >> 4) * 8];
        #pragma unroll
        for (int i = 0; i < MR; ++i)
            #pragma unroll
            for (int j = 0; j < NR; ++j)
                acc[i][j] = __builtin_amdgcn_mfma_f32_16x16x32_bf16(aq[i], bq[j], acc[i][j], 0, 0, 0);
        __syncthreads();
    }

    #pragma unroll
    for (int i = 0; i < MR; ++i) {
        const int mrow = m0 + wm + i * 16 + (lane >> 4) * 4;
        #pragma unroll
        for (int j = 0; j < NR; ++j) {
            const int ncol = n0 + wn + j * 16 + (lane & 15);
            if (ncol < N) {
                #pragma unroll
                for (int e = 0; e < 4; ++e) {
                    const int mm = mrow + e;
                    if (mm < M) {
                        const long idx = (long)z * sC + (long)mm * ldc + ncol;
                        if (OBF) ((bf16*)C)[idx] = __float2bfloat16(acc[i][j][e]);
                        else     ((float*)C)[idx] = acc[i][j][e];
                    }
                }
            }
        }
    }
}

// ------------------------------------------------- softmaxes for GAT layer
// bsoft v2: LDS-tiled single global pass.

__global__ __launch_bounds__(256) void bsoft_k(
    const float* __restrict__ sc, float* __restrict__ mx, float* __restrict__ sm)
{
    __shared__ float T[64][65];
    __shared__ float P[4][64];
    __shared__ float Mv[64];
    const int idx0 = blockIdx.x * 64;
    const int il = threadIdx.x & 63;
    const int bq = threadIdx.x >> 6;       // 0..3

    #pragma unroll
    for (int r = 0; r < 16; ++r) {
        const int b = bq * 16 + r;
        T[b][il] = sc[(long)b * SCSZ + idx0 + il];
    }
    __syncthreads();

    float pm = -1e30f;
    #pragma unroll
    for (int r = 0; r < 16; ++r) pm = fmaxf(pm, T[bq * 16 + r][il]);
    P[bq][il] = pm;
    __syncthreads();
    if (bq == 0) {
        float m = fmaxf(fmaxf(P[0][il], P[1][il]), fmaxf(P[2][il], P[3][il]));
        Mv[il] = m;
        mx[idx0 + il] = m;
    }
    __syncthreads();

    const float m = Mv[il];
    float ps = 0.f;
    #pragma unroll
    for (int r = 0; r < 16; ++r) ps += expf(T[bq * 16 + r][il] - m);
    __syncthreads();
    P[bq][il] = ps;
    __syncthreads();
    if (bq == 0)
        sm[idx0 + il] = P[0][il] + P[1][il] + P[2][il] + P[3][il];
}

// colsoft v3: 32 m x 16 n-strips per block (640 blocks, 2x TLP of v2);
// register-resident e-values, one sc read + one abf write.
#define NSTR3 19   // ceil(300/16)

__global__ __launch_bounds__(512) void colsoft_k(
    const float* __restrict__ sc, const float* __restrict__ mx,
    const float* __restrict__ sm, const unsigned char* __restrict__ cond,
    bf16* __restrict__ abf)
{
    __shared__ float red[16][32];
    const int ml = threadIdx.x & 31;
    const int ng = threadIdx.x >> 5;           // 0..15
    const int m = blockIdx.x * 32 + ml;        // 0..319
    const int b = blockIdx.y;
    const float* scb = sc + (long)b * SCSZ;
    const unsigned char* cb = cond + (long)b * (N_ * N_);
    const bool act = m < N_;

    float ev[NSTR3];
    unsigned cmask = 0;
    float vmax = -1e30f;
    #pragma unroll
    for (int i = 0; i < NSTR3; ++i) {
        const int n = ng + i * 16;
        float e = 0.f;
        if (n < N_ && act && cb[n * N_ + m]) {
            const int o = n * SCLD + m;
            e = expf(scb[o] - mx[o]) / sm[o];
            cmask |= 1u << i;
            vmax = fmaxf(vmax, e);
        }
        ev[i] = e;
    }
    red[ng][ml] = vmax;
    __syncthreads();
    vmax = red[0][ml];
    #pragma unroll
    for (int i = 1; i < 16; ++i) vmax = fmaxf(vmax, red[i][ml]);

    float ssum = 0.f;
    #pragma unroll
    for (int i = 0; i < NSTR3; ++i)
        if ((cmask >> i) & 1) ssum += expf(ev[i] - vmax);
    __syncthreads();
    red[ng][ml] = ssum;
    __syncthreads();
    ssum = 0.f;
    #pragma unroll
    for (int i = 0; i < 16; ++i) ssum += red[i][ml];
    const float inv = 1.0f / ssum;

    #pragma unroll
    for (int i = 0; i < NSTR3; ++i) {
        const int n = ng + i * 16;
        if (n < N_) {
            const float v = ((cmask >> i) & 1) ? expf(ev[i] - vmax) * inv : 0.f;
            abf[(long)b * (N_ * AK) + n * AK + m] = __float2bfloat16(v);
        }
    }
}

__global__ void nsoft_k(const float* __restrict__ hp, bf16* __restrict__ out)
{
    const int f = blockIdx.x * 256 + threadIdx.x;
    const int b = blockIdx.y;
    const float* hb = hp + (long)b * (N_ * 512) + f;
    float vmax = -1e30f;
    for (int n = 0; n < N_; ++n) vmax = fmaxf(vmax, hb[n * 512]);
    float s = 0.f;
    for (int n = 0; n < N_; ++n) s += expf(hb[n * 512] - vmax);
    const float inv = 1.0f / s;
    bf16* ob = out + (long)b * (N_ * 512) + f;
    for (int n = 0; n < N_; ++n) ob[n * 512] = __float2bfloat16(expf(hb[n * 512] - vmax) * inv);
}

// ----------------------------------------------------------------- GRU prep

__global__ void xrev_k(const bf16* __restrict__ out2, const int* __restrict__ seq_lens,
                       bf16* __restrict__ xr)
{
    const int t = blockIdx.x, b = blockIdx.y;
    const int d = threadIdx.x * 4;
    int src = seq_lens[b] - 1 - t;
    if (src < 0) src = 0;
    *(uint2*)(xr + ((long)t * B_ + b) * 512 + d) =
        *(const uint2*)(out2 + ((long)b * N_ + src) * 512 + d);
}

__global__ void zero_k(float* __restrict__ p, long n)
{
    for (long i = (long)blockIdx.x * 256 + threadIdx.x; i < n; i += (long)gridDim.x * 256)
        p[i] = 0.f;
}

// ------------------------------------------------------ GRU recurrence (v6)
// = v5 structure + single-writer FLAG barrier: each block is sole producer
// of its slab's h, so it plain-stores flags[g8][slab]=t+1 after
// __syncthreads() (vmcnt drained -> h visible first, same assumption the
// proven tree barrier used); consumers' lanes 0..31 gang-load the group's
// 32 flags (128-B spaced) and spin until __all(v >= t+1). No RMW chain.

__device__ __forceinline__ void fbar(unsigned* __restrict__ flg, int slab, int step) {
    __syncthreads();   // exec barrier + vmcnt drain of this block's stores
    if (threadIdx.x == 0)
        __hip_atomic_store(flg + slab * 32, (unsigned)(step + 1),
                           __ATOMIC_RELAXED, __HIP_MEMORY_SCOPE_AGENT);
    if (threadIdx.x < 32) {
        for (;;) {
            const unsigned v = __hip_atomic_load(flg + threadIdx.x * 32,
                                   __ATOMIC_RELAXED, __HIP_MEMORY_SCOPE_AGENT);
            if (__all(v >= (unsigned)(step + 1))) break;
            __builtin_amdgcn_s_sleep(1);
        }
    }
    __syncthreads();
}

__global__ __launch_bounds__(128, 1) void gru_recur6(
    const bf16* __restrict__ gif, const bf16* __restrict__ gib,
    const float* __restrict__ Whh, const float* __restrict__ bih,
    const float* __restrict__ bhh, const int* __restrict__ seq_lens,
    float* __restrict__ hbuf_f, unsigned* __restrict__ bar,
    float* __restrict__ outf, float* __restrict__ outb,
    float* __restrict__ hfin)
{
    __shared__ alignas(16) short wlds[2 * 3 * 16 * W5P];   // 97.5 KB Whh hi/lo
    __shared__ alignas(16) short hlds[16 * HP];            // 16.25 KB h staging / scratch
    const int tid = threadIdx.x;               // 0..127
    const int lane = tid & 63;
    const int w = tid >> 6;                    // k-half 0..1
    const int ml = lane & 15;                  // batch-in-block / frag row
    const int ksl = lane >> 4;                 // 0..3
    const int dir = blockIdx.x >> 7;
    const int rem = blockIdx.x & 127;
    const int slab = rem >> 2;                 // 0..31 (16-u slab)
    const int bq   = rem & 3;                  // batch quarter
    const int ub   = slab * 16;
    const int g8   = dir * 4 + bq;             // 8 flag groups x 32 slabs
    unsigned* flg  = bar + g8 * 1024;          // 32 flags, 128-B spaced
    bf16* hb = (bf16*)hbuf_f;

    // one-time: Whh 16-u slab -> LDS hi/lo bf16 (rows: g*16+ul)
    {
        const float* Wb = Whh + (long)dir * (1536 * 512);
        for (int idx = tid; idx < 3 * 16 * 512; idx += 128) {
            const int row = idx >> 9;          // 0..47
            const int k = idx & 511;
            const int g = row >> 4, ul = row & 15;
            const float v = Wb[(long)(g * 512 + ub + ul) * 512 + k];
            const bf16 hi = __float2bfloat16(v);
            const bf16 lo = __float2bfloat16(v - __bfloat162float(hi));
            wlds[(0 * 48 + row) * W5P + k] = *(const short*)&hi;
            wlds[(1 * 48 + row) * W5P + k] = *(const short*)&lo;
        }
    }

    const int bcol = bq * 16 + ml;             // this lane's batch (C col)
    const int ue   = ub + ksl * 4;             // this lane's u-quad (C rows)
    const bf16* gi = dir ? gib : gif;
    float cr[4], cz[4], cn[4], brr[4], bzz[4], bnn[4];
    #pragma unroll
    for (int e = 0; e < 4; ++e) {
        cr[e]  = bih[dir * 1536 + ue + e];
        cz[e]  = bih[dir * 1536 + 512 + ue + e];
        cn[e]  = bih[dir * 1536 + 1024 + ue + e];
        brr[e] = bhh[dir * 1536 + ue + e];
        bzz[e] = bhh[dir * 1536 + 512 + ue + e];
        bnn[e] = bhh[dir * 1536 + 1024 + ue + e];
    }
    const int sl = seq_lens[bcol];
    float hreg[4] = {0.f, 0.f, 0.f, 0.f};
    float owv[4] = {0.f, 0.f, 0.f, 0.f};

    if (w == 0) {   // zero phase-0 h (both planes); each lane owns (bcol, ue..+3)
        const long z0 = (long)((dir * 2 + 0) * 2 + 0) * 32768 + bcol * 512 + ue;
        const long z1 = (long)((dir * 2 + 0) * 2 + 1) * 32768 + bcol * 512 + ue;
        __hip_atomic_store((ull*)(hb + z0), 0ull, __ATOMIC_RELAXED, __HIP_MEMORY_SCOPE_AGENT);
        __hip_atomic_store((ull*)(hb + z1), 0ull, __ATOMIC_RELAXED, __HIP_MEMORY_SCOPE_AGENT);
    }
    fbar(flg, slab, 0);

    for (int t = 0; t < N_; ++t) {
        const int rp = t & 1, wp = rp ^ 1;
        const ull* hu0 = (const ull*)hb + (long)((dir * 2 + rp) * 2 + 0) * 8192 + bq * 2048;
        const ull* hu1 = (const ull*)hb + (long)((dir * 2 + rp) * 2 + 1) * 8192 + bq * 2048;

        // 1. issue ALL coalesced staging loads (16 b x 512 u, both planes)
        ull r0[16], r1[16];
        #pragma unroll
        for (int i = 0; i < 16; ++i)
            r0[i] = __hip_atomic_load(hu0 + i * 128 + tid,
                                      __ATOMIC_RELAXED, __HIP_MEMORY_SCOPE_AGENT);
        #pragma unroll
        for (int i = 0; i < 16; ++i)
            r1[i] = __hip_atomic_load(hu1 + i * 128 + tid,
                                      __ATOMIC_RELAXED, __HIP_MEMORY_SCOPE_AGENT);

        // 2. deferred out-writes of step t-1 (wave 0)
        if (t > 0 && w == 0) {
            const int tp = t - 1;
            if (dir == 0) {
                #pragma unroll
                for (int e = 0; e < 4; ++e)
                    outf[(long)tp * 32768 + (ue + e) * 64 + bcol] = owv[e];
            } else if (tp < sl) {
                #pragma unroll
                for (int e = 0; e < 4; ++e)
                    outb[(long)(sl - 1 - tp) * 32768 + (ue + e) * 64 + bcol] = owv[e];
            }
        }

        // 3. gi for this step (wave 0 consumes)
        float gv[3][4];
        if (w == 0) {
            #pragma unroll
            for (int g = 0; g < 3; ++g)
                #pragma unroll
                for (int e = 0; e < 4; ++e)
                    gv[g][e] = __bfloat162float(
                        gi[(long)t * 98304 + (g * 512 + ue + e) * 64 + bcol]);
        }

        // 4. pass A: stage h_hi, MFMA Whi*hhi + Wlo*hhi over my k-half
        #pragma unroll
        for (int i = 0; i < 16; ++i) {
            const int q = i * 128 + tid;       // 0..2047
            const int bl_ = q >> 7, uo = q & 127;
            *(ull*)&hlds[bl_ * HP + uo * 4] = r0[i];
        }
        __syncthreads();

        const int brow = ml * HP;
        f32x4 acc[3] = {};
        #pragma unroll
        for (int k8 = 0; k8 < 8; ++k8) {
            const int ks = w * 8 + k8;
            const int u0 = ks * 32 + ksl * 8;
            const s16x8 fh = *(const s16x8*)&hlds[brow + u0];
            const s16x8 a0h = *(const s16x8*)&wlds[(0 * 48 + 0 * 16 + ml) * W5P + u0];
            const s16x8 a1h = *(const s16x8*)&wlds[(0 * 48 + 1 * 16 + ml) * W5P + u0];
            const s16x8 a2h = *(const s16x8*)&wlds[(0 * 48 + 2 * 16 + ml) * W5P + u0];
            const s16x8 a0l = *(const s16x8*)&wlds[(1 * 48 + 0 * 16 + ml) * W5P + u0];
            const s16x8 a1l = *(const s16x8*)&wlds[(1 * 48 + 1 * 16 + ml) * W5P + u0];
            const s16x8 a2l = *(const s16x8*)&wlds[(1 * 48 + 2 * 16 + ml) * W5P + u0];
            acc[0] = __builtin_amdgcn_mfma_f32_16x16x32_bf16(a0h, fh, acc[0], 0, 0, 0);
            acc[1] = __builtin_amdgcn_mfma_f32_16x16x32_bf16(a1h, fh, acc[1], 0, 0, 0);
            acc[2] = __builtin_amdgcn_mfma_f32_16x16x32_bf16(a2h, fh, acc[2], 0, 0, 0);
            acc[0] = __builtin_amdgcn_mfma_f32_16x16x32_bf16(a0l, fh, acc[0], 0, 0, 0);
            acc[1] = __builtin_amdgcn_mfma_f32_16x16x32_bf16(a1l, fh, acc[1], 0, 0, 0);
            acc[2] = __builtin_amdgcn_mfma_f32_16x16x32_bf16(a2l, fh, acc[2], 0, 0, 0);
        }
        __syncthreads();

        // 5. pass B: stage h_lo (from regs), MFMA Whi*hlo
        #pragma unroll
        for (int i = 0; i < 16; ++i) {
            const int q = i * 128 + tid;
            const int bl_ = q >> 7, uo = q & 127;
            *(ull*)&hlds[bl_ * HP + uo * 4] = r1[i];
        }
        __syncthreads();
        #pragma unroll
        for (int k8 = 0; k8 < 8; ++k8) {
            const int ks = w * 8 + k8;
            const int u0 = ks * 32 + ksl * 8;
            const s16x8 fl = *(const s16x8*)&hlds[brow + u0];
            const s16x8 a0h = *(const s16x8*)&wlds[(0 * 48 + 0 * 16 + ml) * W5P + u0];
            const s16x8 a1h = *(const s16x8*)&wlds[(0 * 48 + 1 * 16 + ml) * W5P + u0];
            const s16x8 a2h = *(const s16x8*)&wlds[(0 * 48 + 2 * 16 + ml) * W5P + u0];
            acc[0] = __builtin_amdgcn_mfma_f32_16x16x32_bf16(a0h, fl, acc[0], 0, 0, 0);
            acc[1] = __builtin_amdgcn_mfma_f32_16x16x32_bf16(a1h, fl, acc[1], 0, 0, 0);
            acc[2] = __builtin_amdgcn_mfma_f32_16x16x32_bf16(a2h, fl, acc[2], 0, 0, 0);
        }
        __syncthreads();

        // 6. cross-wave k-reduce (wave 1 -> wave 0) via LDS scratch
        float* scr = (float*)hlds;
        if (w == 1) {
            #pragma unroll
            for (int g = 0; g < 3; ++g)
                #pragma unroll
                for (int e = 0; e < 4; ++e)
                    scr[(lane * 3 + g) * 4 + e] = acc[g][e];
        }
        __syncthreads();

        // 7. epilogue on wave 0: gates, h update, stores
        if (w == 0) {
            #pragma unroll
            for (int g = 0; g < 3; ++g)
                #pragma unroll
                for (int e = 0; e < 4; ++e)
                    acc[g][e] += scr[(lane * 3 + g) * 4 + e];

            ull phi = 0, plo = 0;
            const bool msk = t < sl;
            #pragma unroll
            for (int e = 0; e < 4; ++e) {
                const float rg = sigmoidf_(cr[e] + gv[0][e] + brr[e] + acc[0][e]);
                const float zg = sigmoidf_(cz[e] + gv[1][e] + bzz[e] + acc[1][e]);
                const float ng = tanhf(cn[e] + gv[2][e] + rg * (bnn[e] + acc[2][e]));
                const float hnew = (1.f - zg) * ng + zg * hreg[e];
                owv[e] = (dir == 0) ? (msk ? hnew : 0.f) : hnew;
                hreg[e] = msk ? hnew : hreg[e];
                const bf16 h_hi = __float2bfloat16(hreg[e]);
                const bf16 h_lo = __float2bfloat16(hreg[e] - __bfloat162float(h_hi));
                phi |= (ull)(*(const unsigned short*)&h_hi) << (16 * e);
                plo |= (ull)(*(const unsigned short*)&h_lo) << (16 * e);
            }
            const long wbh = (long)((dir * 2 + wp) * 2 + 0) * 32768 + bcol * 512 + ue;
            const long wbl = (long)((dir * 2 + wp) * 2 + 1) * 32768 + bcol * 512 + ue;
            __hip_atomic_store((ull*)(hb + wbh), phi, __ATOMIC_RELAXED, __HIP_MEMORY_SCOPE_AGENT);
            __hip_atomic_store((ull*)(hb + wbl), plo, __ATOMIC_RELAXED, __HIP_MEMORY_SCOPE_AGENT);
        }

        fbar(flg, slab, t + 1);
    }

    // final deferred out-write + final hidden state (wave 0)
    if (w == 0) {
        const int tp = N_ - 1;
        if (dir == 0) {
            #pragma unroll
            for (int e = 0; e < 4; ++e)
                outf[(long)tp * 32768 + (ue + e) * 64 + bcol] = owv[e];
        } else if (tp < sl) {
            #pragma unroll
            for (int e = 0; e < 4; ++e)
                outb[(long)(sl - 1 - tp) * 32768 + (ue + e) * 64 + bcol] = owv[e];
        }
        #pragma unroll
        for (int e = 0; e < 4; ++e)
            hfin[dir * 32768 + (ue + e) * 64 + bcol] = hreg[e];
    }
}

// --------------------------------------------------------------- finalize

__global__ void final_k(const float* __restrict__ outf, const float* __restrict__ outb,
                        const float* __restrict__ hfin, const int* __restrict__ seq_lens,
                        float* __restrict__ dout)
{
    const long i = (long)blockIdx.x * 256 + threadIdx.x;
    const long NOUT = (long)N_ * B_ * 512;
    if (i < NOUT) {
        const int t = (int)(i >> 15);
        const int b = (int)((i >> 9) & 63);
        const int u = (int)(i & 511);
        const long src = (long)t * 32768 + u * 64 + b;
        dout[i] = (t < seq_lens[b]) ? outf[src] + outb[src] : 0.f;
    } else if (i < NOUT + 2 * B_ * 512) {
        const long j = i - NOUT;
        const int dir = (int)(j >> 15);
        const int b = (int)((j >> 9) & 63);
        const int u = (int)(j & 511);
        dout[i] = hfin[dir * 32768 + u * 64 + b];
    }
}

__global__ void fail_zero_k(float* __restrict__ dout, long n)
{
    for (long i = (long)blockIdx.x * 256 + threadIdx.x; i < n; i += (long)gridDim.x * 256)
        dout[i] = 0.f;
}

// ----------------------------------------------------------------- launch

extern "C" void kernel_launch(void* const* d_in, const int* in_sizes, int n_in,
                              void* d_out, int out_size, void* d_ws, size_t ws_size,
                              hipStream_t stream)
{
    const int*   tokens   = (const int*)d_in[0];
    const int*   tok_lens = (const int*)d_in[1];
    const int*   seq_lens = (const int*)d_in[2];
    const float* adj      = (const float*)d_in[3];
    const float* emb      = (const float*)d_in[4];
    const float* Wq       = (const float*)d_in[5];
    const float* Wk       = (const float*)d_in[6];
    const float* Wq_o     = (const float*)d_in[7];
    const float* Wk_o     = (const float*)d_in[8];
    const float* gWih     = (const float*)d_in[9];
    const float* gWhh     = (const float*)d_in[10];
    const float* gbih     = (const float*)d_in[11];
    const float* gbhh     = (const float*)d_in[12];
    float* out = (float*)d_out;

    const long SZ = (long)B_ * N_ * 512;   // 9,830,400 elements
    float* F1 = (float*)d_ws;              // kT scratch -> outf
    float* F2 = F1 + SZ;                   // att_bf     -> outb
    float* F3 = F2 + SZ;                   // hp1 / hp2 (fp32)
    bf16* b0 = (bf16*)(F3 + SZ);           // embx -> out2
    bf16* b1 = b0 + SZ;                    // x1   -> x_rev
    bf16* b2 = b1 + SZ;                    // q1b  -> q2 -> wih(bf16)
    bf16* b3 = b2 + SZ;                    // k1b  -> k2
    float* sc   = (float*)(b3 + SZ);
    float* mx   = sc + (long)B_ * SCSZ;
    float* smv  = mx + SCSZ;
    unsigned char* cond = (unsigned char*)(smv + SCSZ);
    bf16* gif = (bf16*)(cond + (long)B_ * N_ * N_);
    bf16* gib = gif + (long)N_ * 1536 * B_;
    float* hbuf = (float*)(gib + (long)N_ * 1536 * B_);
    unsigned* bar = (unsigned*)(hbuf + 131072);          // 8 groups x 32 flags x 32 pad
    float* hfin = (float*)(bar + 8192);
    const size_t needed = (size_t)((char*)(hfin + 2 * 512 * 64) - (char*)d_ws);
    if (ws_size < needed) {
        fail_zero_k<<<4096, 256, 0, stream>>>(out, out_size);
        return;
    }
    bf16* wq1  = (bf16*)sc;                // dead-region transients
    bf16* wk1  = wq1 + 512 * 512;
    bf16* w2q  = (bf16*)sc;
    bf16* w2k  = w2q + 512 * 512;
    bf16* wihb = b2;
    bf16* kT   = (bf16*)F1;                // [b][512][AK] transposed keys
    bf16* abf  = (bf16*)F2;                // [b][N][AK] bf16 att probs

    // 1. layer-1 weight prep, embedding (bf16), cond
    wgath_k<<<512, 512, 0, stream>>>(Wq, wq1);
    wgath_k<<<512, 512, 0, stream>>>(Wk, wk1);
    embed_k<<<dim3(N_, B_), 128, 0, stream>>>(tokens, tok_lens, seq_lens, emb, b0);
    cond_k<<<dim3(5, 5, B_), 256, 0, stream>>>(adj, cond);

    // 2. layer-1 projections via MFMA (bf16 out): q1 -> b2, k1 -> b3; k1^T
    mgemm_k<128, 128, true><<<dim3(150, 4, 1), 256, 0, stream>>>(
        b0, 0, 512, wq1, 0, 512, b2, 0, 512, B_ * N_, 512, 512);
    mgemm_k<128, 128, true><<<dim3(150, 4, 1), 256, 0, stream>>>(
        b0, 0, 512, wk1, 0, 512, b3, 0, 512, B_ * N_, 512, 512);
    tbf_k<<<dim3(5, 8, B_), 256, 0, stream>>>(b3, kT);

    // 3. per-head attention (all MFMA)
    for (int h = 0; h < NHEADS_; ++h) {
        mgemm_k<64, 64, false><<<dim3(5, 5, B_), 256, 0, stream>>>(    // scores1
            b2 + h * 64, (long)N_ * 512, 512,
            b3 + h * 64, (long)N_ * 512, 512,
            sc, SCSZ, SCLD, N_, N_, 64);
        bsoft_k<<<SCSZ / 64, 256, 0, stream>>>(sc, mx, smv);
        colsoft_k<<<dim3(10, B_), 512, 0, stream>>>(sc, mx, smv, cond, abf);
        mgemm_k<64, 64, false><<<dim3(5, 1, B_), 256, 0, stream>>>(    // hp1
            abf, (long)N_ * AK, AK,
            kT + (long)h * 64 * AK, (long)512 * AK, AK,
            F3 + h * 64, (long)N_ * 512, 512, N_, 64, AK);
    }
    nsoft_k<<<dim3(2, B_), 256, 0, stream>>>(F3, b1);                  // x1 (bf16)

    // 4. layer-2 via MFMA: q2/k2 (bf16), k2^T, scores2, hp2
    wtr_k<<<512, 512, 0, stream>>>(Wq_o, w2q);
    wtr_k<<<512, 512, 0, stream>>>(Wk_o, w2k);
    mgemm_k<128, 128, true><<<dim3(150, 4, 1), 256, 0, stream>>>(
        b1, 0, 512, w2q, 0, 512, b2, 0, 512, B_ * N_, 512, 512);
    mgemm_k<128, 128, true><<<dim3(150, 4, 1), 256, 0, stream>>>(
        b1, 0, 512, w2k, 0, 512, b3, 0, 512, B_ * N_, 512, 512);
    tbf_k<<<dim3(5, 8, B_), 256, 0, stream>>>(b3, kT);
    mgemm_k<64, 64, false><<<dim3(5, 5, B_), 256, 0, stream>>>(        // scores2
        b2, (long)N_ * 512, 512, b3, (long)N_ * 512, 512,
        sc, SCSZ, SCLD, N_, N_, 512);
    f2b_k<<<6144, 256, 0, stream>>>(gWih, wihb, (long)2 * 1536 * 512); // q2 dead
    bsoft_k<<<SCSZ / 64, 256, 0, stream>>>(sc, mx, smv);
    colsoft_k<<<dim3(10, B_), 512, 0, stream>>>(sc, mx, smv, cond, abf);
    mgemm_k<64, 64, false><<<dim3(5, 8, B_), 256, 0, stream>>>(        // hp2
        abf, (long)N_ * AK, AK,
        kT, (long)512 * AK, AK,
        F3, (long)N_ * 512, 512, N_, 512, AK);
    nsoft_k<<<dim3(2, B_), 256, 0, stream>>>(F3, b0);                  // out2 (bf16)

    // 5. GRU input GEMMs via MFMA (bf16 out, layout (t, j, b)); 128-row tiles
    xrev_k<<<dim3(N_, B_), 128, 0, stream>>>(b0, seq_lens, b1);
    zero_k<<<1, 256, 0, stream>>>((float*)bar, 8192);
    mgemm_k<128, 64, true><<<dim3(12, 1, N_), 256, 0, stream>>>(
        wihb, 0, 512, b0, 512, (long)N_ * 512, gif, 1536 * 64, 64, 1536, 64, 512);
    mgemm_k<128, 64, true><<<dim3(12, 1, N_), 256, 0, stream>>>(
        wihb + 1536 * 512, 0, 512, b1, (long)B_ * 512, 512, gib, 1536 * 64, 64, 1536, 64, 512);

    // 6. recurrence (v6: flag-array sync) + finalize
    gru_recur6<<<256, 128, 0, stream>>>(gif, gib, gWhh, gbih, gbhh, seq_lens,
                                        hbuf, bar, F1, F2, hfin);
    final_k<<<38656, 256, 0, stream>>>(F1, F2, hfin, seq_lens, out);
}

// Round 13
// 2571.796 us; speedup vs baseline: 2.3456x; 1.0359x over previous
//
#include <hip/hip_runtime.h>
#include <hip/hip_bf16.h>

typedef __hip_bfloat16 bf16;
typedef unsigned long long ull;
typedef __attribute__((ext_vector_type(8))) short s16x8;
typedef __attribute__((ext_vector_type(4))) float f32x4;

#define B_      64
#define NMAX_   299
#define N_      300
#define D_      512
#define H_      512
#define NHEADS_ 8
#define NHID_   64
#define SCLD    304                  // padded leading dim for (n,m) score rows
#define SCSZ    (N_ * SCLD)          // 91,200 floats per batch
#define LDP     48                   // padded LDS row stride (bf16 elems) for mgemm
#define W5P     520                  // Whh LDS k-stride (shorts): 2-way bank alias only
#define HP      520                  // h LDS row stride (shorts)
#define AK      320                  // padded K (=m) for att/kT MFMA operands

// ---------------------------------------------------------------- utilities

__device__ __forceinline__ float sigmoidf_(float x) { return 1.0f / (1.0f + expf(-x)); }

// ---------------------------------------------------------------- embedding

__global__ void embed_k(const int* __restrict__ tokens, const int* __restrict__ tok_lens,
                        const int* __restrict__ seq_lens, const float* __restrict__ emb,
                        bf16* __restrict__ out)
{
    const int n = blockIdx.x, b = blockIdx.y;
    const int d = threadIdx.x * 4;
    const int nc = seq_lens[b] - 1;
    float4 v;
    if (n < nc) {
        const int tl = tok_lens[b * NMAX_ + n];
        const int* tp = tokens + (b * NMAX_ + n) * 8;
        float4 acc = {0.f, 0.f, 0.f, 0.f};
        for (int t = 0; t < 8; ++t) {
            if (t < tl) {
                const float4 e = *(const float4*)(emb + (long)tp[t] * D_ + d);
                acc.x += e.x; acc.y += e.y; acc.z += e.z; acc.w += e.w;
            }
        }
        const float inv = 1.0f / (float)nc;
        v.x = acc.x * inv; v.y = acc.y * inv; v.z = acc.z * inv; v.w = acc.w * inv;
    } else {
        const int row = (n == nc) ? 2 : 0;
        v = *(const float4*)(emb + row * D_ + d);
    }
    bf16 o[4] = {__float2bfloat16(v.x), __float2bfloat16(v.y),
                 __float2bfloat16(v.z), __float2bfloat16(v.w)};
    *(uint2*)(out + ((long)b * N_ + n) * D_ + d) = *(uint2*)o;
}

// ------------------------------------------------------------------- cond

__global__ void cond_k(const float* __restrict__ adj, unsigned char* __restrict__ cond)
{
    __shared__ float T1[64][65];
    __shared__ float T2[64][65];
    const int b = blockIdx.z;
    const int n0 = blockIdx.x * 64, m0 = blockIdx.y * 64;
    const int jj = threadIdx.x & 63, i0 = threadIdx.x >> 6;
    for (int r = 0; r < 16; ++r) {
        const int i = i0 * 16 + r;
        const int n = n0 + i, m = m0 + jj;
        T1[i][jj] = (n < N_ && m < N_) ? adj[((long)b * N_ + n) * N_ + m] : 0.f;
        const int n2 = m0 + i, m2 = n0 + jj;
        T2[i][jj] = (n2 < N_ && m2 < N_) ? adj[((long)b * N_ + n2) * N_ + m2] : 0.f;
    }
    __syncthreads();
    for (int r = 0; r < 16; ++r) {
        const int i = i0 * 16 + r;
        const int n = n0 + i, m = m0 + jj;
        if (n < N_ && m < N_) {
            const float v = T1[i][jj] + T2[jj][i] + ((n == m) ? 1.f : 0.f);
            cond[((long)b * N_ + n) * N_ + m] = (v > 0.f) ? 1 : 0;
        }
    }
}

// -------------------------------------------------- weight prep (fp32->bf16)

__global__ void wgath_k(const float* __restrict__ W, bf16* __restrict__ out)
{   // (8,512,64) -> (512,512): out[h*64+o][d] = W[h][d][o]
    const int row = blockIdx.x;
    const int d = threadIdx.x;
    const int h = row >> 6, o = row & 63;
    out[row * 512 + d] = __float2bfloat16(W[((long)h * 512 + d) * 64 + o]);
}

__global__ void wtr_k(const float* __restrict__ W, bf16* __restrict__ out)
{   // (512,512) -> transposed: out[o][i] = W[i][o]
    const int o = blockIdx.x;
    const int i = threadIdx.x;
    out[o * 512 + i] = __float2bfloat16(W[(long)i * 512 + o]);
}

__global__ void f2b_k(const float* __restrict__ in, bf16* __restrict__ out, long n)
{
    for (long i = (long)blockIdx.x * 256 + threadIdx.x; i < n; i += (long)gridDim.x * 256)
        out[i] = __float2bfloat16(in[i]);
}

// ---------------------------------------------- bf16 tile transpose (+pad)
// in: [b][300][512] -> out: [b][512][AK], out[f][m] = in[m][f]; m>=300 -> 0

__global__ void tbf_k(const bf16* __restrict__ in, bf16* __restrict__ out)
{
    __shared__ short T[64][65];
    const int b = blockIdx.z;
    const int m0 = blockIdx.x * 64, f0 = blockIdx.y * 64;
    const int jj = threadIdx.x & 63, i0 = threadIdx.x >> 6;
    for (int r = 0; r < 16; ++r) {
        const int i = i0 * 16 + r;
        const int m = m0 + i, f = f0 + jj;
        short v = 0;
        if (m < N_) v = *(const short*)&in[((long)b * N_ + m) * 512 + f];
        T[i][jj] = v;
    }
    __syncthreads();
    for (int r = 0; r < 16; ++r) {
        const int i = i0 * 16 + r;
        const int f = f0 + i, m = m0 + jj;
        ((short*)out)[((long)b * 512 + f) * AK + m] = T[jj][i];
    }
}

// ------------------------------------------------------- bf16 MFMA GEMM
// C[m][n] = sum_k A[m][k] * B[n][k]   (B transposed, row-major [N][K]).

template<int BM, int BN, bool OBF>
__global__ __launch_bounds__(256) void mgemm_k(
    const bf16* __restrict__ A, long sA, int lda,
    const bf16* __restrict__ Bm, long sB, int ldb,
    void* __restrict__ C, long sC, int ldc,
    int M, int N, int K)
{
    __shared__ short As[BM * LDP];
    __shared__ short Bs[BN * LDP];
    const int z = blockIdx.z;
    const bf16* Ab = A + (long)z * sA;
    const bf16* Bb = Bm + (long)z * sB;
    const int m0 = blockIdx.x * BM, n0 = blockIdx.y * BN;
    const int tid = threadIdx.x;
    const int lane = tid & 63;
    const int w = tid >> 6;
    const int wm = (w >> 1) * (BM / 2);
    const int wn = (w & 1) * (BN / 2);
    constexpr int MR = BM / 32;
    constexpr int NR = BN / 32;
    f32x4 acc[MR][NR] = {};

    const int srow = tid >> 2;
    const int sslot = (tid & 3) * 8;

    for (int k0 = 0; k0 < K; k0 += 32) {
        #pragma unroll
        for (int r = 0; r < BM / 64; ++r) {
            const int row = r * 64 + srow;
            uint4 v = {0u, 0u, 0u, 0u};
            if (m0 + row < M)
                v = *(const uint4*)(Ab + (long)(m0 + row) * lda + k0 + sslot);
            *(uint4*)&As[row * LDP + sslot] = v;
        }
        #pragma unroll
        for (int r = 0; r < BN / 64; ++r) {
            const int row = r * 64 + srow;
            uint4 v = {0u, 0u, 0u, 0u};
            if (n0 + row < N)
                v = *(const uint4*)(Bb + (long)(n0 + row) * ldb + k0 + sslot);
            *(uint4*)&Bs[row * LDP + sslot] = v;
        }
        __syncthreads();
        s16x8 aq[MR], bq[NR];
        #pragma unroll
        for (int i = 0; i < MR; ++i)
            aq[i] = *(const s16x8*)&As[(wm + i * 16 + (lane & 15)) * LDP + (lane >> 4) * 8];
        #pragma unroll
        for (int j = 0; j < NR; ++j)
            bq[j] = *(const s16x8*)&Bs[(wn + j * 16 + (lane & 15)) * LDP + (lane >> 4) * 8];
        #pragma unroll
        for (int i = 0; i < MR; ++i)
            #pragma unroll
            for (int j = 0; j < NR; ++j)
                acc[i][j] = __builtin_amdgcn_mfma_f32_16x16x32_bf16(aq[i], bq[j], acc[i][j], 0, 0, 0);
        __syncthreads();
    }

    #pragma unroll
    for (int i = 0; i < MR; ++i) {
        const int mrow = m0 + wm + i * 16 + (lane >> 4) * 4;
        #pragma unroll
        for (int j = 0; j < NR; ++j) {
            const int ncol = n0 + wn + j * 16 + (lane & 15);
            if (ncol < N) {
                #pragma unroll
                for (int e = 0; e < 4; ++e) {
                    const int mm = mrow + e;
                    if (mm < M) {
                        const long idx = (long)z * sC + (long)mm * ldc + ncol;
                        if (OBF) ((bf16*)C)[idx] = __float2bfloat16(acc[i][j][e]);
                        else     ((float*)C)[idx] = acc[i][j][e];
                    }
                }
            }
        }
    }
}

// ------------------------------------------------- softmaxes for GAT layer
// bsoft v2: LDS-tiled single global pass.

__global__ __launch_bounds__(256) void bsoft_k(
    const float* __restrict__ sc, float* __restrict__ mx, float* __restrict__ sm)
{
    __shared__ float T[64][65];
    __shared__ float P[4][64];
    __shared__ float Mv[64];
    const int idx0 = blockIdx.x * 64;
    const int il = threadIdx.x & 63;
    const int bq = threadIdx.x >> 6;       // 0..3

    #pragma unroll
    for (int r = 0; r < 16; ++r) {
        const int b = bq * 16 + r;
        T[b][il] = sc[(long)b * SCSZ + idx0 + il];
    }
    __syncthreads();

    float pm = -1e30f;
    #pragma unroll
    for (int r = 0; r < 16; ++r) pm = fmaxf(pm, T[bq * 16 + r][il]);
    P[bq][il] = pm;
    __syncthreads();
    if (bq == 0) {
        float m = fmaxf(fmaxf(P[0][il], P[1][il]), fmaxf(P[2][il], P[3][il]));
        Mv[il] = m;
        mx[idx0 + il] = m;
    }
    __syncthreads();

    const float m = Mv[il];
    float ps = 0.f;
    #pragma unroll
    for (int r = 0; r < 16; ++r) ps += expf(T[bq * 16 + r][il] - m);
    __syncthreads();
    P[bq][il] = ps;
    __syncthreads();
    if (bq == 0)
        sm[idx0 + il] = P[0][il] + P[1][il] + P[2][il] + P[3][il];
}

// colsoft v3: 32 m x 16 n-strips per block (640 blocks);
// register-resident e-values, one sc read + one abf write.
#define NSTR3 19   // ceil(300/16)

__global__ __launch_bounds__(512) void colsoft_k(
    const float* __restrict__ sc, const float* __restrict__ mx,
    const float* __restrict__ sm, const unsigned char* __restrict__ cond,
    bf16* __restrict__ abf)
{
    __shared__ float red[16][32];
    const int ml = threadIdx.x & 31;
    const int ng = threadIdx.x >> 5;           // 0..15
    const int m = blockIdx.x * 32 + ml;        // 0..319
    const int b = blockIdx.y;
    const float* scb = sc + (long)b * SCSZ;
    const unsigned char* cb = cond + (long)b * (N_ * N_);
    const bool act = m < N_;

    float ev[NSTR3];
    unsigned cmask = 0;
    float vmax = -1e30f;
    #pragma unroll
    for (int i = 0; i < NSTR3; ++i) {
        const int n = ng + i * 16;
        float e = 0.f;
        if (n < N_ && act && cb[n * N_ + m]) {
            const int o = n * SCLD + m;
            e = expf(scb[o] - mx[o]) / sm[o];
            cmask |= 1u << i;
            vmax = fmaxf(vmax, e);
        }
        ev[i] = e;
    }
    red[ng][ml] = vmax;
    __syncthreads();
    vmax = red[0][ml];
    #pragma unroll
    for (int i = 1; i < 16; ++i) vmax = fmaxf(vmax, red[i][ml]);

    float ssum = 0.f;
    #pragma unroll
    for (int i = 0; i < NSTR3; ++i)
        if ((cmask >> i) & 1) ssum += expf(ev[i] - vmax);
    __syncthreads();
    red[ng][ml] = ssum;
    __syncthreads();
    ssum = 0.f;
    #pragma unroll
    for (int i = 0; i < 16; ++i) ssum += red[i][ml];
    const float inv = 1.0f / ssum;

    #pragma unroll
    for (int i = 0; i < NSTR3; ++i) {
        const int n = ng + i * 16;
        if (n < N_) {
            const float v = ((cmask >> i) & 1) ? expf(ev[i] - vmax) * inv : 0.f;
            abf[(long)b * (N_ * AK) + n * AK + m] = __float2bfloat16(v);
        }
    }
}

__global__ void nsoft_k(const float* __restrict__ hp, bf16* __restrict__ out)
{
    const int f = blockIdx.x * 256 + threadIdx.x;
    const int b = blockIdx.y;
    const float* hb = hp + (long)b * (N_ * 512) + f;
    float vmax = -1e30f;
    for (int n = 0; n < N_; ++n) vmax = fmaxf(vmax, hb[n * 512]);
    float s = 0.f;
    for (int n = 0; n < N_; ++n) s += expf(hb[n * 512] - vmax);
    const float inv = 1.0f / s;
    bf16* ob = out + (long)b * (N_ * 512) + f;
    for (int n = 0; n < N_; ++n) ob[n * 512] = __float2bfloat16(expf(hb[n * 512] - vmax) * inv);
}

// ----------------------------------------------------------------- GRU prep

__global__ void xrev_k(const bf16* __restrict__ out2, const int* __restrict__ seq_lens,
                       bf16* __restrict__ xr)
{
    const int t = blockIdx.x, b = blockIdx.y;
    const int d = threadIdx.x * 4;
    int src = seq_lens[b] - 1 - t;
    if (src < 0) src = 0;
    *(uint2*)(xr + ((long)t * B_ + b) * 512 + d) =
        *(const uint2*)(out2 + ((long)b * N_ + src) * 512 + d);
}

__global__ void zero_k(float* __restrict__ p, long n)
{
    for (long i = (long)blockIdx.x * 256 + threadIdx.x; i < n; i += (long)gridDim.x * 256)
        p[i] = 0.f;
}

// ------------------------------------------------------ GRU recurrence (v7)
// = v6 + single-pass h staging: BOTH hi/lo planes resident in LDS at once
// (wlds 97.5 KB + hlds 32.5 KB = 130 KB < 160 KB/CU). Removes one staging
// phase and 2 syncthreads per step; restores v4's 9-MFMA-per-ks order.
// Flag-array barrier unchanged.

__device__ __forceinline__ void fbar(unsigned* __restrict__ flg, int slab, int step) {
    __syncthreads();   // exec barrier + vmcnt drain of this block's stores
    if (threadIdx.x == 0)
        __hip_atomic_store(flg + slab * 32, (unsigned)(step + 1),
                           __ATOMIC_RELAXED, __HIP_MEMORY_SCOPE_AGENT);
    if (threadIdx.x < 32) {
        for (;;) {
            const unsigned v = __hip_atomic_load(flg + threadIdx.x * 32,
                                   __ATOMIC_RELAXED, __HIP_MEMORY_SCOPE_AGENT);
            if (__all(v >= (unsigned)(step + 1))) break;
            __builtin_amdgcn_s_sleep(1);
        }
    }
    __syncthreads();
}

__global__ __launch_bounds__(128, 1) void gru_recur7(
    const bf16* __restrict__ gif, const bf16* __restrict__ gib,
    const float* __restrict__ Whh, const float* __restrict__ bih,
    const float* __restrict__ bhh, const int* __restrict__ seq_lens,
    float* __restrict__ hbuf_f, unsigned* __restrict__ bar,
    float* __restrict__ outf, float* __restrict__ outb,
    float* __restrict__ hfin)
{
    __shared__ alignas(16) short wlds[2 * 3 * 16 * W5P];   // 97.5 KB Whh hi/lo
    __shared__ alignas(16) short hlds[2 * 16 * HP];        // 32.5 KB both h planes
    const int tid = threadIdx.x;               // 0..127
    const int lane = tid & 63;
    const int w = tid >> 6;                    // k-half 0..1
    const int ml = lane & 15;                  // batch-in-block / frag row
    const int ksl = lane >> 4;                 // 0..3
    const int dir = blockIdx.x >> 7;
    const int rem = blockIdx.x & 127;
    const int slab = rem >> 2;                 // 0..31 (16-u slab)
    const int bq   = rem & 3;                  // batch quarter
    const int ub   = slab * 16;
    const int g8   = dir * 4 + bq;             // 8 flag groups x 32 slabs
    unsigned* flg  = bar + g8 * 1024;          // 32 flags, 128-B spaced
    bf16* hb = (bf16*)hbuf_f;

    // one-time: Whh 16-u slab -> LDS hi/lo bf16 (rows: g*16+ul)
    {
        const float* Wb = Whh + (long)dir * (1536 * 512);
        for (int idx = tid; idx < 3 * 16 * 512; idx += 128) {
            const int row = idx >> 9;          // 0..47
            const int k = idx & 511;
            const int g = row >> 4, ul = row & 15;
            const float v = Wb[(long)(g * 512 + ub + ul) * 512 + k];
            const bf16 hi = __float2bfloat16(v);
            const bf16 lo = __float2bfloat16(v - __bfloat162float(hi));
            wlds[(0 * 48 + row) * W5P + k] = *(const short*)&hi;
            wlds[(1 * 48 + row) * W5P + k] = *(const short*)&lo;
        }
    }

    const int bcol = bq * 16 + ml;             // this lane's batch (C col)
    const int ue   = ub + ksl * 4;             // this lane's u-quad (C rows)
    const bf16* gi = dir ? gib : gif;
    float cr[4], cz[4], cn[4], brr[4], bzz[4], bnn[4];
    #pragma unroll
    for (int e = 0; e < 4; ++e) {
        cr[e]  = bih[dir * 1536 + ue + e];
        cz[e]  = bih[dir * 1536 + 512 + ue + e];
        cn[e]  = bih[dir * 1536 + 1024 + ue + e];
        brr[e] = bhh[dir * 1536 + ue + e];
        bzz[e] = bhh[dir * 1536 + 512 + ue + e];
        bnn[e] = bhh[dir * 1536 + 1024 + ue + e];
    }
    const int sl = seq_lens[bcol];
    float hreg[4] = {0.f, 0.f, 0.f, 0.f};
    float owv[4] = {0.f, 0.f, 0.f, 0.f};

    if (w == 0) {   // zero phase-0 h (both planes)
        const long z0 = (long)((dir * 2 + 0) * 2 + 0) * 32768 + bcol * 512 + ue;
        const long z1 = (long)((dir * 2 + 0) * 2 + 1) * 32768 + bcol * 512 + ue;
        __hip_atomic_store((ull*)(hb + z0), 0ull, __ATOMIC_RELAXED, __HIP_MEMORY_SCOPE_AGENT);
        __hip_atomic_store((ull*)(hb + z1), 0ull, __ATOMIC_RELAXED, __HIP_MEMORY_SCOPE_AGENT);
    }
    fbar(flg, slab, 0);

    for (int t = 0; t < N_; ++t) {
        const int rp = t & 1, wp = rp ^ 1;
        const ull* hu0 = (const ull*)hb + (long)((dir * 2 + rp) * 2 + 0) * 8192 + bq * 2048;
        const ull* hu1 = (const ull*)hb + (long)((dir * 2 + rp) * 2 + 1) * 8192 + bq * 2048;

        // 1. issue ALL coalesced staging loads (16 b x 512 u, both planes)
        ull r0[16], r1[16];
        #pragma unroll
        for (int i = 0; i < 16; ++i)
            r0[i] = __hip_atomic_load(hu0 + i * 128 + tid,
                                      __ATOMIC_RELAXED, __HIP_MEMORY_SCOPE_AGENT);
        #pragma unroll
        for (int i = 0; i < 16; ++i)
            r1[i] = __hip_atomic_load(hu1 + i * 128 + tid,
                                      __ATOMIC_RELAXED, __HIP_MEMORY_SCOPE_AGENT);

        // 2. deferred out-writes of step t-1 (wave 0)
        if (t > 0 && w == 0) {
            const int tp = t - 1;
            if (dir == 0) {
                #pragma unroll
                for (int e = 0; e < 4; ++e)
                    outf[(long)tp * 32768 + (ue + e) * 64 + bcol] = owv[e];
            } else if (tp < sl) {
                #pragma unroll
                for (int e = 0; e < 4; ++e)
                    outb[(long)(sl - 1 - tp) * 32768 + (ue + e) * 64 + bcol] = owv[e];
            }
        }

        // 3. gi for this step (wave 0 consumes)
        float gv[3][4];
        if (w == 0) {
            #pragma unroll
            for (int g = 0; g < 3; ++g)
                #pragma unroll
                for (int e = 0; e < 4; ++e)
                    gv[g][e] = __bfloat162float(
                        gi[(long)t * 98304 + (g * 512 + ue + e) * 64 + bcol]);
        }

        // 4. single-pass staging: both planes into LDS
        #pragma unroll
        for (int i = 0; i < 16; ++i) {
            const int q = i * 128 + tid;       // 0..2047
            const int bl_ = q >> 7, uo = q & 127;
            *(ull*)&hlds[bl_ * HP + uo * 4] = r0[i];
        }
        #pragma unroll
        for (int i = 0; i < 16; ++i) {
            const int q = i * 128 + tid;
            const int bl_ = q >> 7, uo = q & 127;
            *(ull*)&hlds[16 * HP + bl_ * HP + uo * 4] = r1[i];
        }
        __syncthreads();

        // 5. MFMA over my k-half: 9 terms per ks (v4 order)
        const int brow = ml * HP;
        f32x4 acc[3] = {};
        #pragma unroll
        for (int k8 = 0; k8 < 8; ++k8) {
            const int ks = w * 8 + k8;
            const int u0 = ks * 32 + ksl * 8;
            const s16x8 fh = *(const s16x8*)&hlds[brow + u0];
            const s16x8 fl = *(const s16x8*)&hlds[16 * HP + brow + u0];
            const s16x8 a0h = *(const s16x8*)&wlds[(0 * 48 + 0 * 16 + ml) * W5P + u0];
            const s16x8 a1h = *(const s16x8*)&wlds[(0 * 48 + 1 * 16 + ml) * W5P + u0];
            const s16x8 a2h = *(const s16x8*)&wlds[(0 * 48 + 2 * 16 + ml) * W5P + u0];
            const s16x8 a0l = *(const s16x8*)&wlds[(1 * 48 + 0 * 16 + ml) * W5P + u0];
            const s16x8 a1l = *(const s16x8*)&wlds[(1 * 48 + 1 * 16 + ml) * W5P + u0];
            const s16x8 a2l = *(const s16x8*)&wlds[(1 * 48 + 2 * 16 + ml) * W5P + u0];
            acc[0] = __builtin_amdgcn_mfma_f32_16x16x32_bf16(a0h, fh, acc[0], 0, 0, 0);
            acc[1] = __builtin_amdgcn_mfma_f32_16x16x32_bf16(a1h, fh, acc[1], 0, 0, 0);
            acc[2] = __builtin_amdgcn_mfma_f32_16x16x32_bf16(a2h, fh, acc[2], 0, 0, 0);
            acc[0] = __builtin_amdgcn_mfma_f32_16x16x32_bf16(a0h, fl, acc[0], 0, 0, 0);
            acc[1] = __builtin_amdgcn_mfma_f32_16x16x32_bf16(a1h, fl, acc[1], 0, 0, 0);
            acc[2] = __builtin_amdgcn_mfma_f32_16x16x32_bf16(a2h, fl, acc[2], 0, 0, 0);
            acc[0] = __builtin_amdgcn_mfma_f32_16x16x32_bf16(a0l, fh, acc[0], 0, 0, 0);
            acc[1] = __builtin_amdgcn_mfma_f32_16x16x32_bf16(a1l, fh, acc[1], 0, 0, 0);
            acc[2] = __builtin_amdgcn_mfma_f32_16x16x32_bf16(a2l, fh, acc[2], 0, 0, 0);
        }
        __syncthreads();

        // 6. cross-wave k-reduce (wave 1 -> wave 0) via LDS scratch
        float* scr = (float*)hlds;
        if (w == 1) {
            #pragma unroll
            for (int g = 0; g < 3; ++g)
                #pragma unroll
                for (int e = 0; e < 4; ++e)
                    scr[(lane * 3 + g) * 4 + e] = acc[g][e];
        }
        __syncthreads();

        // 7. epilogue on wave 0: gates, h update, stores
        if (w == 0) {
            #pragma unroll
            for (int g = 0; g < 3; ++g)
                #pragma unroll
                for (int e = 0; e < 4; ++e)
                    acc[g][e] += scr[(lane * 3 + g) * 4 + e];

            ull phi = 0, plo = 0;
            const bool msk = t < sl;
            #pragma unroll
            for (int e = 0; e < 4; ++e) {
                const float rg = sigmoidf_(cr[e] + gv[0][e] + brr[e] + acc[0][e]);
                const float zg = sigmoidf_(cz[e] + gv[1][e] + bzz[e] + acc[1][e]);
                const float ng = tanhf(cn[e] + gv[2][e] + rg * (bnn[e] + acc[2][e]));
                const float hnew = (1.f - zg) * ng + zg * hreg[e];
                owv[e] = (dir == 0) ? (msk ? hnew : 0.f) : hnew;
                hreg[e] = msk ? hnew : hreg[e];
                const bf16 h_hi = __float2bfloat16(hreg[e]);
                const bf16 h_lo = __float2bfloat16(hreg[e] - __bfloat162float(h_hi));
                phi |= (ull)(*(const unsigned short*)&h_hi) << (16 * e);
                plo |= (ull)(*(const unsigned short*)&h_lo) << (16 * e);
            }
            const long wbh = (long)((dir * 2 + wp) * 2 + 0) * 32768 + bcol * 512 + ue;
            const long wbl = (long)((dir * 2 + wp) * 2 + 1) * 32768 + bcol * 512 + ue;
            __hip_atomic_store((ull*)(hb + wbh), phi, __ATOMIC_RELAXED, __HIP_MEMORY_SCOPE_AGENT);
            __hip_atomic_store((ull*)(hb + wbl), plo, __ATOMIC_RELAXED, __HIP_MEMORY_SCOPE_AGENT);
        }

        fbar(flg, slab, t + 1);
    }

    // final deferred out-write + final hidden state (wave 0)
    if (w == 0) {
        const int tp = N_ - 1;
        if (dir == 0) {
            #pragma unroll
            for (int e = 0; e < 4; ++e)
                outf[(long)tp * 32768 + (ue + e) * 64 + bcol] = owv[e];
        } else if (tp < sl) {
            #pragma unroll
            for (int e = 0; e < 4; ++e)
                outb[(long)(sl - 1 - tp) * 32768 + (ue + e) * 64 + bcol] = owv[e];
        }
        #pragma unroll
        for (int e = 0; e < 4; ++e)
            hfin[dir * 32768 + (ue + e) * 64 + bcol] = hreg[e];
    }
}

// --------------------------------------------------------------- finalize

__global__ void final_k(const float* __restrict__ outf, const float* __restrict__ outb,
                        const float* __restrict__ hfin, const int* __restrict__ seq_lens,
                        float* __restrict__ dout)
{
    const long i = (long)blockIdx.x * 256 + threadIdx.x;
    const long NOUT = (long)N_ * B_ * 512;
    if (i < NOUT) {
        const int t = (int)(i >> 15);
        const int b = (int)((i >> 9) & 63);
        const int u = (int)(i & 511);
        const long src = (long)t * 32768 + u * 64 + b;
        dout[i] = (t < seq_lens[b]) ? outf[src] + outb[src] : 0.f;
    } else if (i < NOUT + 2 * B_ * 512) {
        const long j = i - NOUT;
        const int dir = (int)(j >> 15);
        const int b = (int)((j >> 9) & 63);
        const int u = (int)(j & 511);
        dout[i] = hfin[dir * 32768 + u * 64 + b];
    }
}

__global__ void fail_zero_k(float* __restrict__ dout, long n)
{
    for (long i = (long)blockIdx.x * 256 + threadIdx.x; i < n; i += (long)gridDim.x * 256)
        dout[i] = 0.f;
}

// ----------------------------------------------------------------- launch

extern "C" void kernel_launch(void* const* d_in, const int* in_sizes, int n_in,
                              void* d_out, int out_size, void* d_ws, size_t ws_size,
                              hipStream_t stream)
{
    const int*   tokens   = (const int*)d_in[0];
    const int*   tok_lens = (const int*)d_in[1];
    const int*   seq_lens = (const int*)d_in[2];
    const float* adj      = (const float*)d_in[3];
    const float* emb      = (const float*)d_in[4];
    const float* Wq       = (const float*)d_in[5];
    const float* Wk       = (const float*)d_in[6];
    const float* Wq_o     = (const float*)d_in[7];
    const float* Wk_o     = (const float*)d_in[8];
    const float* gWih     = (const float*)d_in[9];
    const float* gWhh     = (const float*)d_in[10];
    const float* gbih     = (const float*)d_in[11];
    const float* gbhh     = (const float*)d_in[12];
    float* out = (float*)d_out;

    const long SZ = (long)B_ * N_ * 512;   // 9,830,400 elements
    float* F1 = (float*)d_ws;              // kT scratch -> outf
    float* F2 = F1 + SZ;                   // att_bf     -> outb
    float* F3 = F2 + SZ;                   // hp1 / hp2 (fp32)
    bf16* b0 = (bf16*)(F3 + SZ);           // embx -> out2
    bf16* b1 = b0 + SZ;                    // x1   -> x_rev
    bf16* b2 = b1 + SZ;                    // q1b  -> q2 -> wih(bf16)
    bf16* b3 = b2 + SZ;                    // k1b  -> k2
    float* sc   = (float*)(b3 + SZ);
    float* mx   = sc + (long)B_ * SCSZ;
    float* smv  = mx + SCSZ;
    unsigned char* cond = (unsigned char*)(smv + SCSZ);
    bf16* gif = (bf16*)(cond + (long)B_ * N_ * N_);
    bf16* gib = gif + (long)N_ * 1536 * B_;
    float* hbuf = (float*)(gib + (long)N_ * 1536 * B_);
    unsigned* bar = (unsigned*)(hbuf + 131072);          // 8 groups x 32 flags x 32 pad
    float* hfin = (float*)(bar + 8192);
    const size_t needed = (size_t)((char*)(hfin + 2 * 512 * 64) - (char*)d_ws);
    if (ws_size < needed) {
        fail_zero_k<<<4096, 256, 0, stream>>>(out, out_size);
        return;
    }
    bf16* wq1  = (bf16*)sc;                // dead-region transients
    bf16* wk1  = wq1 + 512 * 512;
    bf16* w2q  = (bf16*)sc;
    bf16* w2k  = w2q + 512 * 512;
    bf16* wihb = b2;
    bf16* kT   = (bf16*)F1;                // [b][512][AK] transposed keys
    bf16* abf  = (bf16*)F2;                // [b][N][AK] bf16 att probs

    // 1. layer-1 weight prep, embedding (bf16), cond
    wgath_k<<<512, 512, 0, stream>>>(Wq, wq1);
    wgath_k<<<512, 512, 0, stream>>>(Wk, wk1);
    embed_k<<<dim3(N_, B_), 128, 0, stream>>>(tokens, tok_lens, seq_lens, emb, b0);
    cond_k<<<dim3(5, 5, B_), 256, 0, stream>>>(adj, cond);

    // 2. layer-1 projections via MFMA (bf16 out): q1 -> b2, k1 -> b3; k1^T
    mgemm_k<128, 128, true><<<dim3(150, 4, 1), 256, 0, stream>>>(
        b0, 0, 512, wq1, 0, 512, b2, 0, 512, B_ * N_, 512, 512);
    mgemm_k<128, 128, true><<<dim3(150, 4, 1), 256, 0, stream>>>(
        b0, 0, 512, wk1, 0, 512, b3, 0, 512, B_ * N_, 512, 512);
    tbf_k<<<dim3(5, 8, B_), 256, 0, stream>>>(b3, kT);

    // 3. per-head attention (all MFMA; 128^2 score tiles)
    for (int h = 0; h < NHEADS_; ++h) {
        mgemm_k<128, 128, false><<<dim3(3, 3, B_), 256, 0, stream>>>(  // scores1
            b2 + h * 64, (long)N_ * 512, 512,
            b3 + h * 64, (long)N_ * 512, 512,
            sc, SCSZ, SCLD, N_, N_, 64);
        bsoft_k<<<SCSZ / 64, 256, 0, stream>>>(sc, mx, smv);
        colsoft_k<<<dim3(10, B_), 512, 0, stream>>>(sc, mx, smv, cond, abf);
        mgemm_k<64, 64, false><<<dim3(5, 1, B_), 256, 0, stream>>>(    // hp1
            abf, (long)N_ * AK, AK,
            kT + (long)h * 64 * AK, (long)512 * AK, AK,
            F3 + h * 64, (long)N_ * 512, 512, N_, 64, AK);
    }
    nsoft_k<<<dim3(2, B_), 256, 0, stream>>>(F3, b1);                  // x1 (bf16)

    // 4. layer-2 via MFMA: q2/k2 (bf16), k2^T, scores2, hp2 (128^2 tiles)
    wtr_k<<<512, 512, 0, stream>>>(Wq_o, w2q);
    wtr_k<<<512, 512, 0, stream>>>(Wk_o, w2k);
    mgemm_k<128, 128, true><<<dim3(150, 4, 1), 256, 0, stream>>>(
        b1, 0, 512, w2q, 0, 512, b2, 0, 512, B_ * N_, 512, 512);
    mgemm_k<128, 128, true><<<dim3(150, 4, 1), 256, 0, stream>>>(
        b1, 0, 512, w2k, 0, 512, b3, 0, 512, B_ * N_, 512, 512);
    tbf_k<<<dim3(5, 8, B_), 256, 0, stream>>>(b3, kT);
    mgemm_k<128, 128, false><<<dim3(3, 3, B_), 256, 0, stream>>>(      // scores2
        b2, (long)N_ * 512, 512, b3, (long)N_ * 512, 512,
        sc, SCSZ, SCLD, N_, N_, 512);
    f2b_k<<<6144, 256, 0, stream>>>(gWih, wihb, (long)2 * 1536 * 512); // q2 dead
    bsoft_k<<<SCSZ / 64, 256, 0, stream>>>(sc, mx, smv);
    colsoft_k<<<dim3(10, B_), 512, 0, stream>>>(sc, mx, smv, cond, abf);
    mgemm_k<128, 128, false><<<dim3(3, 4, B_), 256, 0, stream>>>(      // hp2
        abf, (long)N_ * AK, AK,
        kT, (long)512 * AK, AK,
        F3, (long)N_ * 512, 512, N_, 512, AK);
    nsoft_k<<<dim3(2, B_), 256, 0, stream>>>(F3, b0);                  // out2 (bf16)

    // 5. GRU input GEMMs via MFMA (bf16 out, layout (t, j, b)); 128-row tiles
    xrev_k<<<dim3(N_, B_), 128, 0, stream>>>(b0, seq_lens, b1);
    zero_k<<<1, 256, 0, stream>>>((float*)bar, 8192);
    mgemm_k<128, 64, true><<<dim3(12, 1, N_), 256, 0, stream>>>(
        wihb, 0, 512, b0, 512, (long)N_ * 512, gif, 1536 * 64, 64, 1536, 64, 512);
    mgemm_k<128, 64, true><<<dim3(12, 1, N_), 256, 0, stream>>>(
        wihb + 1536 * 512, 0, 512, b1, (long)B_ * 512, 512, gib, 1536 * 64, 64, 1536, 64, 512);

    // 6. recurrence (v7: single-pass LDS staging, flag sync) + finalize
    gru_recur7<<<256, 128, 0, stream>>>(gif, gib, gWhh, gbih, gbhh, seq_lens,
                                        hbuf, bar, F1, F2, hfin);
    final_k<<<38656, 256, 0, stream>>>(F1, F2, hfin, seq_lens, out);
}